// Round 11
// baseline (336.560 us; speedup 1.0000x reference)
//
#include <hip/hip_runtime.h>

#define H 128
#define RNUM 8
#define TNUM 2
#define PNUM 1000
#define MNUM 223
#define BNODES 64           // nodes per dst-bucket (power of 2)
#define NBUCK 782           // padN / 64
#define BCAP 2304           // per-bucket capacity (mean 2048, +5.7 sigma)
#define EPB 8192            // edges per partition block

typedef __attribute__((ext_vector_type(8))) short bf16x8;
typedef __attribute__((ext_vector_type(4))) float f32x4;

__device__ __forceinline__ float fsig(float z) {
    return 1.0f / (1.0f + __expf(-z));
}
__device__ __forceinline__ float fsig_fast(float z) {
    return __builtin_amdgcn_rcpf(1.0f + __expf(-z));
}

__device__ __forceinline__ float wave_reduce(float v) {
#pragma unroll
    for (int off = 32; off > 0; off >>= 1) v += __shfl_down(v, off, 64);
    return v;
}

__device__ __forceinline__ unsigned short f2bf(float f) {
    unsigned int u = __float_as_uint(f);
    u += 0x7fffu + ((u >> 16) & 1u);   // RNE
    return (unsigned short)(u >> 16);
}

// ---------------------------------------------------------------------------
// K1: fused G+C precompute. Block tr = t*8+r (16 blocks, 128 threads).
// ---------------------------------------------------------------------------
__global__ void precompute_CG(const float* __restrict__ fc_w, const float* __restrict__ fc_b,
                              const float* __restrict__ w_nt, const float* __restrict__ w_rel,
                              float* __restrict__ C) {
    __shared__ float G[3][H];
    int tr = blockIdx.x;
    int t = tr >> 3, r = tr & 7;
    int i = threadIdx.x;
    float a0 = 0.f, a1 = 0.f, a2 = 0.f;
#pragma unroll 8
    for (int j = 0; j < H; ++j) {
        float w = w_nt[((size_t)t * H + j) * H + i];
        a0 += fc_w[j] * w;
        a1 += fc_w[H + j] * w;
        a2 += fc_b[j] * w;
    }
    G[0][i] = a0; G[1][i] = a1; G[2][i] = a2;
    __syncthreads();
    float c0 = 0.f, c1 = 0.f, c2 = 0.f;
#pragma unroll 8
    for (int k = 0; k < H; ++k) {
        float w = w_rel[((size_t)r * H + k) * H + i];
        c0 += G[0][k] * w;
        c1 += G[1][k] * w;
        c2 += G[2][k] * w;
    }
    C[((size_t)tr * 3 + 0) * H + i] = c0;
    C[((size_t)tr * 3 + 1) * H + i] = c1;
    C[((size_t)tr * 3 + 2) * H + i] = c2;
}

// ---------------------------------------------------------------------------
// K1c: wt[p][k] = bf16(fl3_w[k][p]) (p zero-padded to 1024); biasws[p] padded
// with -1e4 so sigmoid of pad columns is exactly 0.
// ---------------------------------------------------------------------------
__global__ void wt_kernel(const float* __restrict__ w, const float* __restrict__ fl3_b,
                          unsigned short* __restrict__ wt, float* __restrict__ biasws) {
    int p = blockIdx.x;   // 0..1023
    int k = threadIdx.x;  // 0..127
    float v = (p < PNUM) ? w[(size_t)k * PNUM + p] : 0.0f;
    wt[(size_t)p * H + k] = f2bf(v);
    if (k == 0) biasws[p] = (p < PNUM) ? fl3_b[p] : -1.0e4f;
}

// ---------------------------------------------------------------------------
// K2: partition edges into 64-node dst buckets. FAT payload (16B):
//   .x = src | (local<<18) | (r<<24) | (t<<27)
//   .y = bits(norm*ntc0[s]), .z = bits(norm*ntc1[s]), .w = bits(norm)
// ---------------------------------------------------------------------------
__global__ __launch_bounds__(1024) void partition_kernel(
        const int* __restrict__ src, const int* __restrict__ dst,
        const int* __restrict__ etype, const float* __restrict__ norm,
        const int* __restrict__ node_type, const float* __restrict__ ntc,
        int* __restrict__ cursor, uint4* __restrict__ buck, int E) {
    __shared__ int lh[NBUCK];
    __shared__ int gb[NBUCK];
    int tid = threadIdx.x;
    for (int i = tid; i < NBUCK; i += 1024) lh[i] = 0;
    __syncthreads();
    int base = blockIdx.x * EPB;
    uint4 pl[8]; int bb[8]; int rk[8];
#pragma unroll
    for (int c = 0; c < 8; ++c) {
        int e = base + c * 1024 + tid;
        bb[c] = -1;
        if (e < E) {
            int s = src[e];
            int d = dst[e];
            int r = etype[e];
            float nm = norm[e];
            int t = node_type[s];
            float2 cc = ((const float2*)ntc)[s];
            int b = d >> 6;
            int local = d & 63;
            pl[c].x = (unsigned)s | ((unsigned)local << 18) | ((unsigned)r << 24) | ((unsigned)t << 27);
            pl[c].y = __float_as_uint(nm * cc.x);
            pl[c].z = __float_as_uint(nm * cc.y);
            pl[c].w = __float_as_uint(nm);
            bb[c] = b;
            rk[c] = atomicAdd(&lh[b], 1);
        }
    }
    __syncthreads();
    for (int i = tid; i < NBUCK; i += 1024) {
        if (lh[i] > 0) {
            int g = atomicAdd(&cursor[i], lh[i]);
            gb[i] = (g < 0) ? 0 : (g > BCAP ? BCAP : g);
        }
    }
    __syncthreads();
#pragma unroll
    for (int c = 0; c < 8; ++c) {
        if (bb[c] >= 0) {
            int pos = gb[bb[c]] + rk[c];
            if (pos < BCAP) buck[(size_t)bb[c] * BCAP + pos] = pl[c];
        }
    }
}

// ---------------------------------------------------------------------------
// K3: replay ONLY: payload stream -> LDS S[64][49] atomics -> coalesced
// plain store to Sg[padN][48]. 12.5KB LDS -> many blocks/CU. Pad-node rows
// store zeros (S initialized 0), so Sg needs no memset.
// ---------------------------------------------------------------------------
__global__ __launch_bounds__(256) void replay_kernel(
        const uint4* __restrict__ buck, const int* __restrict__ cursor,
        float* __restrict__ Sg) {
    __shared__ float S[64 * 49];
    int tid = threadIdx.x;
    int bkt = blockIdx.x;
    for (int i = tid; i < 64 * 49; i += 256) S[i] = 0.0f;
    __syncthreads();
    int cnt = cursor[bkt];
    if (cnt > BCAP) cnt = BCAP;
    if (cnt < 0) cnt = 0;
    const uint4* bp = buck + (size_t)bkt * BCAP;
    for (int i = tid; i < cnt; i += 256) {
        uint4 pl = bp[i];
        int local = (pl.x >> 18) & 63;
        int tr = ((pl.x >> 24) & 7) + (((pl.x >> 27) & 1) << 3);
        float* p = &S[local * 49 + tr * 3];
        atomicAdd(p, __uint_as_float(pl.y));
        atomicAdd(p + 1, __uint_as_float(pl.z));
        atomicAdd(p + 2, __uint_as_float(pl.w));
    }
    __syncthreads();
    // unpad 49 -> 48 and store
    float* dst = Sg + (size_t)bkt * (64 * 48);
    for (int i = tid; i < 64 * 48; i += 256) {
        int row = i / 48, c = i - row * 48;
        dst[i] = S[row * 49 + c];
    }
}

// ---------------------------------------------------------------------------
// K4: FUSED node-GEMV + prob3-MFMA. Grid (nb128, 2), 256 thr.
// Phase 1: h = relu(Sg@C) fp32 (C/Sg direct from global; C is L1-hot since
// identical across blocks), bf16 h -> LDS A-tile; pred/gsum (y==0 only).
// Then A-frags -> registers; SAME LDS buffer rebound as Bsh; 4-p-tile MFMA
// with maskless sigmoid epilogue (pad rows corrected in tail). LDS 34.8KB.
// ---------------------------------------------------------------------------
__global__ __launch_bounds__(256) void node_prob3(
        const float* __restrict__ Sg, const float* __restrict__ C,
        const float* __restrict__ fc2_w, const float* __restrict__ fc2_b,
        const unsigned short* __restrict__ wt, const float* __restrict__ biasws,
        float* __restrict__ pred, float* __restrict__ gpart,
        float* __restrict__ psum, int N, int nb128) {
    __shared__ unsigned short ABsh[128 * 136];   // Ash in phase 1/2a, Bsh in 2b
    __shared__ float gloc[128];
    __shared__ float wsum[4];
    int tid = threadIdx.x;
    int n0 = blockIdx.x * 128;
    bool writer = (blockIdx.y == 0);
    if (tid < 128) gloc[tid] = 0.0f;
    __syncthreads();

    // ---- phase 1: 4 passes x 32 nodes; sub covers 16 cols (4xf4 at q*32+sub*4)
    int sub = tid & 7, vl = tid >> 3;   // vl 0..31
    const float4* w4 = (const float4*)fc2_w;
    for (int ps = 0; ps < 4; ++ps) {
        int ln = ps * 32 + vl;          // node within tile
        int v = n0 + ln;
        const float* Srow = Sg + (size_t)v * 48;
        float4 hv[4];
#pragma unroll
        for (int q = 0; q < 4; ++q) hv[q] = make_float4(0.f, 0.f, 0.f, 0.f);
#pragma unroll 4
        for (int k = 0; k < 48; ++k) {
            float sv = Srow[k];
            const float4* Cr = (const float4*)(C + k * 128);
#pragma unroll
            for (int q = 0; q < 4; ++q) {
                float4 c = Cr[q * 8 + sub];
                hv[q].x += sv * c.x; hv[q].y += sv * c.y;
                hv[q].z += sv * c.z; hv[q].w += sv * c.w;
            }
        }
#pragma unroll
        for (int q = 0; q < 4; ++q) {
            hv[q].x = fmaxf(hv[q].x, 0.f); hv[q].y = fmaxf(hv[q].y, 0.f);
            hv[q].z = fmaxf(hv[q].z, 0.f); hv[q].w = fmaxf(hv[q].w, 0.f);
        }
        // write bf16 h into A-tile (pad rows write zeros - Sg pad rows are 0)
        float pd = 0.f;
#pragma unroll
        for (int q = 0; q < 4; ++q) {
            unsigned int u0 = ((unsigned int)f2bf(hv[q].y) << 16) | f2bf(hv[q].x);
            unsigned int u1 = ((unsigned int)f2bf(hv[q].w) << 16) | f2bf(hv[q].z);
            *(uint2*)(ABsh + ln * 136 + q * 32 + sub * 4) = make_uint2(u0, u1);
            float4 w = w4[q * 8 + sub];
            pd += hv[q].x * w.x + hv[q].y * w.y + hv[q].z * w.z + hv[q].w * w.w;
        }
#pragma unroll
        for (int off = 4; off > 0; off >>= 1) pd += __shfl_down(pd, off, 8);
        if (sub == 0 && v < N && writer) {
            float z = pd + fc2_b[0];
            pred[v] = fminf(fmaxf(fsig(z), 1e-7f), 1e10f);
        }
        if (writer) {
#pragma unroll
            for (int q = 0; q < 4; ++q) {
                float4 x = (v < N) ? hv[q] : make_float4(0.f, 0.f, 0.f, 0.f);
#pragma unroll
                for (int d = 8; d < 64; d <<= 1) {
                    x.x += __shfl_down(x.x, d, 64); x.y += __shfl_down(x.y, d, 64);
                    x.z += __shfl_down(x.z, d, 64); x.w += __shfl_down(x.w, d, 64);
                }
                if ((tid & 63) < 8) {
                    int o = q * 32 + sub * 4;
                    atomicAdd(&gloc[o], x.x); atomicAdd(&gloc[o + 1], x.y);
                    atomicAdd(&gloc[o + 2], x.z); atomicAdd(&gloc[o + 3], x.w);
                }
            }
        }
    }
    __syncthreads();

    // ---- phase 2a: A-frags -> registers
    int lane = tid & 63, wid = tid >> 6;
    int wy = wid >> 1, wx = wid & 1;
    int lrow = lane & 15, quad = lane >> 4;
    bf16x8 a[4][4];
#pragma unroll
    for (int tm = 0; tm < 4; ++tm) {
        const unsigned short* arow = ABsh + (wy * 64 + tm * 16 + lrow) * 136 + quad * 8;
#pragma unroll
        for (int ks = 0; ks < 4; ++ks)
            a[tm][ks] = *(const bf16x8*)(arow + ks * 32);
    }
    __syncthreads();   // A reads done; buffer may be rebound as Bsh

    // ---- phase 2b: p-tile loop
    float lsum = 0.f;
    for (int pi = 0; pi < 4; ++pi) {
        int pt = blockIdx.y * 4 + pi;
        if (pi) __syncthreads();
        {
            int c = tid & 15;
            int r0 = tid >> 4;
#pragma unroll
            for (int it = 0; it < 8; ++it) {
                int row = r0 + it * 16;
                uint4 bv = *(const uint4*)(wt + (size_t)(pt * 128 + row) * H + c * 8);
                *(uint4*)(ABsh + row * 136 + c * 8) = bv;
            }
        }
        __syncthreads();

        f32x4 acc[4][4];
#pragma unroll
        for (int tm = 0; tm < 4; ++tm)
#pragma unroll
            for (int tn = 0; tn < 4; ++tn)
                acc[tm][tn] = (f32x4){0.f, 0.f, 0.f, 0.f};

        const unsigned short* Bbase = ABsh + (wx * 64 + lrow) * 136 + quad * 8;
#pragma unroll
        for (int ks = 0; ks < 4; ++ks) {
            bf16x8 b[4];
#pragma unroll
            for (int tn = 0; tn < 4; ++tn)
                b[tn] = *(const bf16x8*)(Bbase + tn * 16 * 136 + ks * 32);
#pragma unroll
            for (int tm = 0; tm < 4; ++tm)
#pragma unroll
                for (int tn = 0; tn < 4; ++tn)
                    acc[tm][tn] = __builtin_amdgcn_mfma_f32_16x16x32_bf16(a[tm][ks], b[tn], acc[tm][tn], 0, 0, 0);
        }

#pragma unroll
        for (int tn = 0; tn < 4; ++tn) {
            float bv = biasws[pt * 128 + wx * 64 + tn * 16 + lrow];
#pragma unroll
            for (int tm = 0; tm < 4; ++tm) {
#pragma unroll
                for (int r = 0; r < 4; ++r)
                    lsum += fsig_fast(acc[tm][tn][r] + bv);
            }
        }
    }
    lsum = wave_reduce(lsum);
    if (lane == 0) wsum[wid] = lsum;
    __syncthreads();
    if (tid == 0)
        psum[blockIdx.y * nb128 + blockIdx.x] = wsum[0] + wsum[1] + wsum[2] + wsum[3];
    if (tid < 128 && writer) gpart[(size_t)blockIdx.x * 128 + tid] = gloc[tid];
}

// ---------------------------------------------------------------------------
// K5: per-bucket agg[dst] += pred[src] in LDS; out_cost partial plain-stored.
// ---------------------------------------------------------------------------
__global__ __launch_bounds__(512) void agg_outcost(
        const uint4* __restrict__ buck, const int* __restrict__ cursor,
        const float* __restrict__ pred, const float* __restrict__ sc,
        float* __restrict__ ocpart, int N) {
    __shared__ float agg[BNODES];
    int tid = threadIdx.x;
    int bkt = blockIdx.x;
    if (tid < BNODES) agg[tid] = 0.0f;
    __syncthreads();
    int cnt = cursor[bkt];
    if (cnt > BCAP) cnt = BCAP;
    if (cnt < 0) cnt = 0;
    const uint4* bp = buck + (size_t)bkt * BCAP;
    for (int i = tid; i < cnt; i += 512) {
        unsigned x = bp[i].x;
        int s = x & 0x3FFFF;
        int local = (x >> 18) & 63;
        atomicAdd(&agg[local], pred[s]);
    }
    __syncthreads();
    if (tid < 64) {
        float v = 0.f;
        int node = bkt * BNODES + tid;
        if (node < N) {
            float d = agg[tid] - 1.0f;
            v = d * d * sc[node];
        }
        v = wave_reduce(v);
        if (tid == 0) ocpart[bkt] = v;
    }
}

// K6: rs (blocks 0..222) and cs (blocks 223..445), plain stores, no atomics.
__global__ void rowcol_kernel(const float* __restrict__ pred, float* __restrict__ rs,
                              float* __restrict__ cs) {
    __shared__ float red[4];
    int blk = blockIdx.x, tid = threadIdx.x;
    float p = 0.f;
    if (blk < MNUM) {
        if (tid < MNUM) p = pred[blk * MNUM + tid];
    } else {
        int j = blk - MNUM;
        if (tid < MNUM) p = pred[tid * MNUM + j];
    }
    p = wave_reduce(p);
    if ((tid & 63) == 0) red[tid >> 6] = p;
    __syncthreads();
    if (tid == 0) {
        float s = red[0] + red[1] + red[2] + red[3];
        if (blk < MNUM) rs[blk] = s; else cs[blk - MNUM] = s;
    }
}

// K7: blocks 0..222: per-row ce/l2 plain stores. blocks 223..350: gsum dim
// reduction from gpart (plain stores).
__global__ void losses_kernel(const float* __restrict__ pred, const float* __restrict__ gt,
                              const float* __restrict__ rs, const float* __restrict__ cs,
                              const float* __restrict__ gpart, float* __restrict__ lce,
                              float* __restrict__ ll2, float* __restrict__ gsum, int nbuck) {
    __shared__ float redc[4], redl[4];
    int blk = blockIdx.x, tid = threadIdx.x;
    if (blk < MNUM) {
        float ce = 0.f, l2 = 0.f;
        if (tid < MNUM) {
            float p = pred[blk * MNUM + tid];
            ce = -gt[blk * MNUM + tid] * __log2f(p);
            l2 = p * (rs[blk] + cs[tid] - 2.0f * p);
        }
        ce = wave_reduce(ce);
        l2 = wave_reduce(l2);
        if ((tid & 63) == 0) { redc[tid >> 6] = ce; redl[tid >> 6] = l2; }
        __syncthreads();
        if (tid == 0) {
            lce[blk] = redc[0] + redc[1] + redc[2] + redc[3];
            ll2[blk] = redl[0] + redl[1] + redl[2] + redl[3];
        }
    } else {
        int dim = blk - MNUM;  // 0..127
        float s = 0.f;
        for (int b = tid; b < nbuck; b += 256) s += gpart[(size_t)b * 128 + dim];
        s = wave_reduce(s);
        if ((tid & 63) == 0) redc[tid >> 6] = s;
        __syncthreads();
        if (tid == 0) gsum[dim] = redc[0] + redc[1] + redc[2] + redc[3];
    }
}

// K8: single-block tail: all six outputs via plain stores.
__global__ void tail_kernel(const float* __restrict__ rs, const float* __restrict__ cs,
                            const float* __restrict__ lce, const float* __restrict__ ll2,
                            const float* __restrict__ psum, int npsum,
                            const float* __restrict__ ocpart, int nbuck,
                            const float* __restrict__ gsum, const float* __restrict__ fc3_w,
                            const float* __restrict__ fc3_b, const float* __restrict__ fl3_b,
                            float* __restrict__ out, int N, int padrows) {
    __shared__ float red[4];
    int tid = threadIdx.x;
    // sumone
    float v = 0.f;
    if (tid < MNUM) {
        float a = rs[tid] - 1.0f, b = cs[tid] - 1.0f;
        v = a * a + b * b;
    }
    v = wave_reduce(v);
    if ((tid & 63) == 0) red[tid >> 6] = v;
    __syncthreads();
    if (tid == 0) out[1] = red[0] + red[1] + red[2] + red[3];
    __syncthreads();
    // ce
    float ce = (tid < MNUM) ? lce[tid] : 0.f;
    ce = wave_reduce(ce);
    if ((tid & 63) == 0) red[tid >> 6] = ce;
    __syncthreads();
    if (tid == 0) out[3] = red[0] + red[1] + red[2] + red[3];
    __syncthreads();
    // loss2
    float l2 = (tid < MNUM) ? ll2[tid] : 0.f;
    l2 = wave_reduce(l2);
    if ((tid & 63) == 0) red[tid >> 6] = l2;
    __syncthreads();
    if (tid == 0) out[2] = red[0] + red[1] + red[2] + red[3];
    __syncthreads();
    // prob3_sum
    float ps = 0.f;
    for (int i = tid; i < npsum; i += 256) ps += psum[i];
    float ss = 0.f;
    for (int p = tid; p < PNUM; p += 256) ss += fsig_fast(fl3_b[p]);
    float comb = ps - (float)padrows * ss;
    comb = wave_reduce(comb);
    if ((tid & 63) == 0) red[tid >> 6] = comb;
    __syncthreads();
    if (tid == 0) out[5] = red[0] + red[1] + red[2] + red[3];
    __syncthreads();
    // out_cost
    float oc = 0.f;
    for (int b = tid; b < nbuck; b += 256) oc += ocpart[b];
    oc = wave_reduce(oc);
    if ((tid & 63) == 0) red[tid >> 6] = oc;
    __syncthreads();
    if (tid == 0) out[4] = red[0] + red[1] + red[2] + red[3];
    __syncthreads();
    // pred_obj
    float pv = 0.f;
    if (tid < 128) pv = gsum[tid] * (1.0f / (float)N) * fc3_w[tid];
    pv = wave_reduce(pv);
    if ((tid & 63) == 0) red[tid >> 6] = pv;
    __syncthreads();
    if (tid == 0) out[0] = red[0] + red[1] + fc3_b[0];
}

extern "C" void kernel_launch(void* const* d_in, const int* in_sizes, int n_in,
                              void* d_out, int out_size, void* d_ws, size_t ws_size,
                              hipStream_t stream) {
    const float* ntc   = (const float*)d_in[0];
    const float* norm  = (const float*)d_in[1];
    const float* sc    = (const float*)d_in[2];
    const float* gt    = (const float*)d_in[3];
    const float* fc_w  = (const float*)d_in[4];
    const float* fc_b  = (const float*)d_in[5];
    const float* w_nt  = (const float*)d_in[6];
    const float* w_rel = (const float*)d_in[7];
    const float* fc2_w = (const float*)d_in[8];
    const float* fc2_b = (const float*)d_in[9];
    const float* fc3_w = (const float*)d_in[10];
    const float* fc3_b = (const float*)d_in[11];
    const float* fl3_w = (const float*)d_in[12];
    const float* fl3_b = (const float*)d_in[13];
    const int* node_type = (const int*)d_in[14];
    const int* src   = (const int*)d_in[15];
    const int* dst   = (const int*)d_in[16];
    const int* etype = (const int*)d_in[17];
    int N = in_sizes[2];
    int E = in_sizes[1];
    int nb128 = (N + 127) / 128;             // 391
    int padN  = nb128 * 128;                 // 50048
    int nbuck = padN / BNODES;               // 782
    int npsum = nb128 * 2;                   // 782

    // ---- workspace layout (float offsets) ----
    float* ws   = (float*)d_ws;
    float* C    = ws;                        // 0..6144
    unsigned short* wt = (unsigned short*)(ws + 6144);   // ..71680
    float* biasws = ws + 71680;              // ..72704
    float* gsum = ws + 72704;                // ..72832
    float* rs   = ws + 72832;                // ..73088
    float* cs   = ws + 73088;                // ..73344
    int*  cursor = (int*)(ws + 73344);       // ..74128 (784 ints)
    float* psum = ws + 74128;                // ..75152
    float* lce  = ws + 75152;                // ..75408
    float* ll2  = ws + 75408;                // ..75664
    float* ocpart = ws + 75664;              // ..76688
    float* gpart  = ws + 76688;              // ..176784 (782*128)
    float* pred = ws + 176784;               // ..+N
    float* Sg   = pred + N;                  // padN*48 floats (9.6 MB)
    uint4* buck = (uint4*)(Sg + (size_t)padN * 48);      // nbuck*BCAP*16B
    float* out  = (float*)d_out;

    hipMemsetAsync(d_out, 0, 6 * sizeof(float), stream);
    hipMemsetAsync(cursor, 0, 784 * sizeof(int), stream);

    wt_kernel<<<1024, 128, 0, stream>>>(fl3_w, fl3_b, wt, biasws);
    precompute_CG<<<16, 128, 0, stream>>>(fc_w, fc_b, w_nt, w_rel, C);
    partition_kernel<<<(E + EPB - 1) / EPB, 1024, 0, stream>>>(src, dst, etype, norm,
                                                               node_type, ntc, cursor, buck, E);
    replay_kernel<<<nbuck, 256, 0, stream>>>(buck, cursor, Sg);
    node_prob3<<<dim3(nb128, 2), 256, 0, stream>>>(Sg, C, fc2_w, fc2_b, wt, biasws,
                                                   pred, gpart, psum, N, nb128);
    agg_outcost<<<nbuck, 512, 0, stream>>>(buck, cursor, pred, sc, ocpart, N);
    rowcol_kernel<<<2 * MNUM, 256, 0, stream>>>(pred, rs, cs);
    losses_kernel<<<MNUM + 128, 256, 0, stream>>>(pred, gt, rs, cs, gpart, lce, ll2, gsum, nbuck);
    tail_kernel<<<1, 256, 0, stream>>>(rs, cs, lce, ll2, psum, npsum, ocpart, nbuck,
                                       gsum, fc3_w, fc3_b, fl3_b, out, N, padN - N);
}

// Round 12
// 251.185 us; speedup vs baseline: 1.3399x; 1.3399x over previous
//
#include <hip/hip_runtime.h>

#define H 128
#define RNUM 8
#define TNUM 2
#define PNUM 1000
#define MNUM 223
#define BNODES 64           // nodes per dst-bucket (power of 2)
#define NBUCK 782           // padN / 64
#define BCAP 2304           // per-bucket capacity (mean 2048, +5.7 sigma)
#define EPB 8192            // edges per partition block

typedef __attribute__((ext_vector_type(8))) short bf16x8;
typedef __attribute__((ext_vector_type(4))) float f32x4;

__device__ __forceinline__ float fsig(float z) {
    return 1.0f / (1.0f + __expf(-z));
}
__device__ __forceinline__ float fsig_fast(float z) {
    return __builtin_amdgcn_rcpf(1.0f + __expf(-z));
}

__device__ __forceinline__ float wave_reduce(float v) {
#pragma unroll
    for (int off = 32; off > 0; off >>= 1) v += __shfl_down(v, off, 64);
    return v;
}

__device__ __forceinline__ unsigned short f2bf(float f) {
    unsigned int u = __float_as_uint(f);
    u += 0x7fffu + ((u >> 16) & 1u);   // RNE
    return (unsigned short)(u >> 16);
}

// ---------------------------------------------------------------------------
// K1 (fused setup): blocks 0..1023 -> wt/bias transpose+pad; blocks
// 1024..1039 -> C precompute (tr = blk-1024). 128 threads each.
// ---------------------------------------------------------------------------
__global__ void setup_kernel(const float* __restrict__ fl3_w, const float* __restrict__ fl3_b,
                             unsigned short* __restrict__ wt, float* __restrict__ biasws,
                             const float* __restrict__ fc_w, const float* __restrict__ fc_b,
                             const float* __restrict__ w_nt, const float* __restrict__ w_rel,
                             float* __restrict__ C) {
    __shared__ float G[3][H];
    int blk = blockIdx.x;
    int i = threadIdx.x;
    if (blk < 1024) {
        int p = blk;
        float v = (p < PNUM) ? fl3_w[(size_t)i * PNUM + p] : 0.0f;
        wt[(size_t)p * H + i] = f2bf(v);
        if (i == 0) biasws[p] = (p < PNUM) ? fl3_b[p] : -1.0e4f;
        return;
    }
    int tr = blk - 1024;            // t*8+r
    int t = tr >> 3, r = tr & 7;
    float a0 = 0.f, a1 = 0.f, a2 = 0.f;
#pragma unroll 8
    for (int j = 0; j < H; ++j) {
        float w = w_nt[((size_t)t * H + j) * H + i];
        a0 += fc_w[j] * w;
        a1 += fc_w[H + j] * w;
        a2 += fc_b[j] * w;
    }
    G[0][i] = a0; G[1][i] = a1; G[2][i] = a2;
    __syncthreads();
    float c0 = 0.f, c1 = 0.f, c2 = 0.f;
#pragma unroll 8
    for (int k = 0; k < H; ++k) {
        float w = w_rel[((size_t)r * H + k) * H + i];
        c0 += G[0][k] * w;
        c1 += G[1][k] * w;
        c2 += G[2][k] * w;
    }
    C[((size_t)tr * 3 + 0) * H + i] = c0;
    C[((size_t)tr * 3 + 1) * H + i] = c1;
    C[((size_t)tr * 3 + 2) * H + i] = c2;
}

// ---------------------------------------------------------------------------
// K2: partition edges into 64-node dst buckets. Payload 8B:
//   .x = src | (local<<18) | (r<<24) | (t<<27); .y = bits(norm)
// ---------------------------------------------------------------------------
__global__ __launch_bounds__(1024) void partition_kernel(
        const int* __restrict__ src, const int* __restrict__ dst,
        const int* __restrict__ etype, const float* __restrict__ norm,
        const int* __restrict__ node_type, int* __restrict__ cursor,
        uint2* __restrict__ buck, int E) {
    __shared__ int lh[NBUCK];
    __shared__ int gb[NBUCK];
    int tid = threadIdx.x;
    for (int i = tid; i < NBUCK; i += 1024) lh[i] = 0;
    __syncthreads();
    int base = blockIdx.x * EPB;
    uint2 pl[8]; int bb[8]; int rk[8];
#pragma unroll
    for (int c = 0; c < 8; ++c) {
        int e = base + c * 1024 + tid;
        bb[c] = -1;
        if (e < E) {
            int s = src[e];
            int d = dst[e];
            int r = etype[e];
            float nm = norm[e];
            int t = node_type[s];
            int b = d >> 6;
            int local = d & 63;
            pl[c].x = (unsigned)s | ((unsigned)local << 18) | ((unsigned)r << 24) | ((unsigned)t << 27);
            pl[c].y = __float_as_uint(nm);
            bb[c] = b;
            rk[c] = atomicAdd(&lh[b], 1);
        }
    }
    __syncthreads();
    for (int i = tid; i < NBUCK; i += 1024) {
        if (lh[i] > 0) {
            int g = atomicAdd(&cursor[i], lh[i]);
            gb[i] = (g < 0) ? 0 : (g > BCAP ? BCAP : g);
        }
    }
    __syncthreads();
#pragma unroll
    for (int c = 0; c < 8; ++c) {
        if (bb[c] >= 0) {
            int pos = gb[bb[c]] + rk[c];
            if (pos < BCAP) buck[(size_t)bb[c] * BCAP + pos] = pl[c];
        }
    }
}

// ---------------------------------------------------------------------------
// K3: per-bucket replay -> S[64][49] LDS, then h = relu(S@C).
// 256 threads, 2 nodes/thread: per wave per k the 4 C-frag b128 reads are
// shared by 16 nodes (6 ds-instr/16 nodes vs 5/8 single-pass) -> 1.67x less
// LDS-pipe pressure, same total VALU. Pad nodes write zero hb rows (no memset).
// ---------------------------------------------------------------------------
__global__ __launch_bounds__(256) void bucket_node(
        const uint2* __restrict__ buck, const int* __restrict__ cursor,
        const float* __restrict__ ntc, const float* __restrict__ C,
        const float* __restrict__ fc2_w, const float* __restrict__ fc2_b,
        unsigned short* __restrict__ hb, float* __restrict__ pred,
        float* __restrict__ gpart, int N) {
    __shared__ float S[64 * 49];     // 12.5KB
    __shared__ float Csh[48 * 128];  // 24.6KB
    __shared__ float gloc[128];
    int tid = threadIdx.x;
    int bkt = blockIdx.x;
    for (int i = tid; i < 64 * 49; i += 256) S[i] = 0.0f;
    for (int i = tid; i < 48 * 128; i += 256) Csh[i] = C[i];
    if (tid < 128) gloc[tid] = 0.0f;
    __syncthreads();

    int cnt = cursor[bkt];
    if (cnt > BCAP) cnt = BCAP;
    if (cnt < 0) cnt = 0;
    const uint2* bp = buck + (size_t)bkt * BCAP;
    for (int i = tid; i < cnt; i += 256) {
        uint2 pl = bp[i];
        int s = pl.x & 0x3FFFF;
        int local = (pl.x >> 18) & 63;
        int tr = ((pl.x >> 24) & 7) + (((pl.x >> 27) & 1) << 3);
        float nm = __uint_as_float(pl.y);
        float2 c = ((const float2*)ntc)[s];
        float* p = &S[local * 49 + tr * 3];
        atomicAdd(p, nm * c.x);
        atomicAdd(p + 1, nm * c.y);
        atomicAdd(p + 2, nm);
    }
    __syncthreads();

    int sub = tid & 7, vl = tid >> 3;   // vl = 0..31; this thread: nodes vl, vl+32
    float4 hv[2][4];
#pragma unroll
    for (int ps = 0; ps < 2; ++ps)
#pragma unroll
        for (int q = 0; q < 4; ++q) hv[ps][q] = make_float4(0.f, 0.f, 0.f, 0.f);

#pragma unroll 4
    for (int k = 0; k < 48; ++k) {
        float4 c[4];
        const float4* Cr = (const float4*)(Csh + k * 128);
#pragma unroll
        for (int q = 0; q < 4; ++q) c[q] = Cr[q * 8 + sub];
        float sv0 = S[vl * 49 + k];
        float sv1 = S[(vl + 32) * 49 + k];
#pragma unroll
        for (int q = 0; q < 4; ++q) {
            hv[0][q].x += sv0 * c[q].x; hv[0][q].y += sv0 * c[q].y;
            hv[0][q].z += sv0 * c[q].z; hv[0][q].w += sv0 * c[q].w;
            hv[1][q].x += sv1 * c[q].x; hv[1][q].y += sv1 * c[q].y;
            hv[1][q].z += sv1 * c[q].z; hv[1][q].w += sv1 * c[q].w;
        }
    }

    const float4* w4 = (const float4*)fc2_w;
#pragma unroll
    for (int ps = 0; ps < 2; ++ps) {
        int ln = vl + 32 * ps;
        int v = bkt * BNODES + ln;
        bool act = (v < N);
#pragma unroll
        for (int q = 0; q < 4; ++q) {
            hv[ps][q].x = fmaxf(hv[ps][q].x, 0.f); hv[ps][q].y = fmaxf(hv[ps][q].y, 0.f);
            hv[ps][q].z = fmaxf(hv[ps][q].z, 0.f); hv[ps][q].w = fmaxf(hv[ps][q].w, 0.f);
        }
        // hb written unconditionally: pad rows are exactly zero (S rows zero)
        unsigned short* hrow = hb + (size_t)v * H;
        float pd = 0.f;
#pragma unroll
        for (int q = 0; q < 4; ++q) {
            unsigned int u0 = ((unsigned int)f2bf(hv[ps][q].y) << 16) | f2bf(hv[ps][q].x);
            unsigned int u1 = ((unsigned int)f2bf(hv[ps][q].w) << 16) | f2bf(hv[ps][q].z);
            *(uint2*)(hrow + q * 32 + sub * 4) = make_uint2(u0, u1);
            float4 w = w4[q * 8 + sub];
            pd += hv[ps][q].x * w.x + hv[ps][q].y * w.y + hv[ps][q].z * w.z + hv[ps][q].w * w.w;
        }
#pragma unroll
        for (int off = 4; off > 0; off >>= 1) pd += __shfl_down(pd, off, 8);
        if (sub == 0 && act) {
            float z = pd + fc2_b[0];
            pred[v] = fminf(fmaxf(fsig(z), 1e-7f), 1e10f);
        }
#pragma unroll
        for (int q = 0; q < 4; ++q) {
            float4 x = act ? hv[ps][q] : make_float4(0.f, 0.f, 0.f, 0.f);
#pragma unroll
            for (int d = 8; d < 64; d <<= 1) {
                x.x += __shfl_down(x.x, d, 64); x.y += __shfl_down(x.y, d, 64);
                x.z += __shfl_down(x.z, d, 64); x.w += __shfl_down(x.w, d, 64);
            }
            if ((tid & 63) < 8) {
                int o = q * 32 + sub * 4;
                atomicAdd(&gloc[o], x.x); atomicAdd(&gloc[o + 1], x.y);
                atomicAdd(&gloc[o + 2], x.z); atomicAdd(&gloc[o + 3], x.w);
            }
        }
    }
    __syncthreads();
    if (tid < 128) gpart[(size_t)bkt * 128 + tid] = gloc[tid];
}

// ---------------------------------------------------------------------------
// K4: prob3 via bf16 MFMA, maskless; per-block plain store to psum.
// ---------------------------------------------------------------------------
__global__ __launch_bounds__(256, 2) void prob3_mfma(const unsigned short* __restrict__ hb,
                                                     const unsigned short* __restrict__ wt,
                                                     const float* __restrict__ biasws,
                                                     float* __restrict__ psum, int nb128) {
    __shared__ unsigned short Bsh[128 * 136];
    __shared__ float wsum[4];
    int tid = threadIdx.x;
    int n0 = blockIdx.x * 128;
    int pt0 = blockIdx.y * 4;

    int lane = tid & 63, wid = tid >> 6;
    int wy = wid >> 1, wx = wid & 1;
    int lrow = lane & 15, quad = lane >> 4;

    bf16x8 a[4][4];
#pragma unroll
    for (int tm = 0; tm < 4; ++tm) {
        const unsigned short* arow = hb + (size_t)(n0 + wy * 64 + tm * 16 + lrow) * H + quad * 8;
#pragma unroll
        for (int ks = 0; ks < 4; ++ks)
            a[tm][ks] = *(const bf16x8*)(arow + ks * 32);
    }

    float lsum = 0.f;
    for (int pi = 0; pi < 4; ++pi) {
        int pt = pt0 + pi;
        __syncthreads();
        {
            int c = tid & 15;
            int r0 = tid >> 4;
#pragma unroll
            for (int it = 0; it < 8; ++it) {
                int row = r0 + it * 16;
                uint4 bv = *(const uint4*)(wt + (size_t)(pt * 128 + row) * H + c * 8);
                *(uint4*)(Bsh + row * 136 + c * 8) = bv;
            }
        }
        __syncthreads();

        f32x4 acc[4][4];
#pragma unroll
        for (int tm = 0; tm < 4; ++tm)
#pragma unroll
            for (int tn = 0; tn < 4; ++tn)
                acc[tm][tn] = (f32x4){0.f, 0.f, 0.f, 0.f};

        const unsigned short* Bbase = Bsh + (wx * 64 + lrow) * 136 + quad * 8;
#pragma unroll
        for (int ks = 0; ks < 4; ++ks) {
            bf16x8 b[4];
#pragma unroll
            for (int tn = 0; tn < 4; ++tn)
                b[tn] = *(const bf16x8*)(Bbase + tn * 16 * 136 + ks * 32);
#pragma unroll
            for (int tm = 0; tm < 4; ++tm)
#pragma unroll
                for (int tn = 0; tn < 4; ++tn)
                    acc[tm][tn] = __builtin_amdgcn_mfma_f32_16x16x32_bf16(a[tm][ks], b[tn], acc[tm][tn], 0, 0, 0);
        }

#pragma unroll
        for (int tn = 0; tn < 4; ++tn) {
            float bv = biasws[pt * 128 + wx * 64 + tn * 16 + lrow];
#pragma unroll
            for (int tm = 0; tm < 4; ++tm) {
#pragma unroll
                for (int r = 0; r < 4; ++r)
                    lsum += fsig_fast(acc[tm][tn][r] + bv);
            }
        }
    }
    lsum = wave_reduce(lsum);
    if (lane == 0) wsum[wid] = lsum;
    __syncthreads();
    if (tid == 0)
        psum[blockIdx.y * nb128 + blockIdx.x] = wsum[0] + wsum[1] + wsum[2] + wsum[3];
}

// ---------------------------------------------------------------------------
// K5: per-bucket agg[dst] += pred[src] in LDS; out_cost partial plain-stored.
// ---------------------------------------------------------------------------
__global__ __launch_bounds__(512) void agg_outcost(
        const uint2* __restrict__ buck, const int* __restrict__ cursor,
        const float* __restrict__ pred, const float* __restrict__ sc,
        float* __restrict__ ocpart, int N) {
    __shared__ float agg[BNODES];
    int tid = threadIdx.x;
    int bkt = blockIdx.x;
    if (tid < BNODES) agg[tid] = 0.0f;
    __syncthreads();
    int cnt = cursor[bkt];
    if (cnt > BCAP) cnt = BCAP;
    if (cnt < 0) cnt = 0;
    const uint2* bp = buck + (size_t)bkt * BCAP;
    for (int i = tid; i < cnt; i += 512) {
        unsigned x = bp[i].x;
        int s = x & 0x3FFFF;
        int local = (x >> 18) & 63;
        atomicAdd(&agg[local], pred[s]);
    }
    __syncthreads();
    if (tid < 64) {
        float v = 0.f;
        int node = bkt * BNODES + tid;
        if (node < N) {
            float d = agg[tid] - 1.0f;
            v = d * d * sc[node];
        }
        v = wave_reduce(v);
        if (tid == 0) ocpart[bkt] = v;
    }
}

// K6: rs (blocks 0..222) and cs (blocks 223..445), plain stores, no atomics.
__global__ void rowcol_kernel(const float* __restrict__ pred, float* __restrict__ rs,
                              float* __restrict__ cs) {
    __shared__ float red[4];
    int blk = blockIdx.x, tid = threadIdx.x;
    float p = 0.f;
    if (blk < MNUM) {
        if (tid < MNUM) p = pred[blk * MNUM + tid];
    } else {
        int j = blk - MNUM;
        if (tid < MNUM) p = pred[tid * MNUM + j];
    }
    p = wave_reduce(p);
    if ((tid & 63) == 0) red[tid >> 6] = p;
    __syncthreads();
    if (tid == 0) {
        float s = red[0] + red[1] + red[2] + red[3];
        if (blk < MNUM) rs[blk] = s; else cs[blk - MNUM] = s;
    }
}

// K7: blocks 0..222: per-row ce/l2 plain stores. blocks 223..350: gsum dim
// reduction from gpart (plain stores).
__global__ void losses_kernel(const float* __restrict__ pred, const float* __restrict__ gt,
                              const float* __restrict__ rs, const float* __restrict__ cs,
                              const float* __restrict__ gpart, float* __restrict__ lce,
                              float* __restrict__ ll2, float* __restrict__ gsum, int nbuck) {
    __shared__ float redc[4], redl[4];
    int blk = blockIdx.x, tid = threadIdx.x;
    if (blk < MNUM) {
        float ce = 0.f, l2 = 0.f;
        if (tid < MNUM) {
            float p = pred[blk * MNUM + tid];
            ce = -gt[blk * MNUM + tid] * __log2f(p);
            l2 = p * (rs[blk] + cs[tid] - 2.0f * p);
        }
        ce = wave_reduce(ce);
        l2 = wave_reduce(l2);
        if ((tid & 63) == 0) { redc[tid >> 6] = ce; redl[tid >> 6] = l2; }
        __syncthreads();
        if (tid == 0) {
            lce[blk] = redc[0] + redc[1] + redc[2] + redc[3];
            ll2[blk] = redl[0] + redl[1] + redl[2] + redl[3];
        }
    } else {
        int dim = blk - MNUM;  // 0..127
        float s = 0.f;
        for (int b = tid; b < nbuck; b += 256) s += gpart[(size_t)b * 128 + dim];
        s = wave_reduce(s);
        if ((tid & 63) == 0) redc[tid >> 6] = s;
        __syncthreads();
        if (tid == 0) gsum[dim] = redc[0] + redc[1] + redc[2] + redc[3];
    }
}

// K8: single-block tail: all six outputs via plain stores.
__global__ void tail_kernel(const float* __restrict__ rs, const float* __restrict__ cs,
                            const float* __restrict__ lce, const float* __restrict__ ll2,
                            const float* __restrict__ psum, int npsum,
                            const float* __restrict__ ocpart, int nbuck,
                            const float* __restrict__ gsum, const float* __restrict__ fc3_w,
                            const float* __restrict__ fc3_b, const float* __restrict__ fl3_b,
                            float* __restrict__ out, int N, int padrows) {
    __shared__ float red[4];
    int tid = threadIdx.x;
    // sumone
    float v = 0.f;
    if (tid < MNUM) {
        float a = rs[tid] - 1.0f, b = cs[tid] - 1.0f;
        v = a * a + b * b;
    }
    v = wave_reduce(v);
    if ((tid & 63) == 0) red[tid >> 6] = v;
    __syncthreads();
    if (tid == 0) out[1] = red[0] + red[1] + red[2] + red[3];
    __syncthreads();
    // ce
    float ce = (tid < MNUM) ? lce[tid] : 0.f;
    ce = wave_reduce(ce);
    if ((tid & 63) == 0) red[tid >> 6] = ce;
    __syncthreads();
    if (tid == 0) out[3] = red[0] + red[1] + red[2] + red[3];
    __syncthreads();
    // loss2
    float l2 = (tid < MNUM) ? ll2[tid] : 0.f;
    l2 = wave_reduce(l2);
    if ((tid & 63) == 0) red[tid >> 6] = l2;
    __syncthreads();
    if (tid == 0) out[2] = red[0] + red[1] + red[2] + red[3];
    __syncthreads();
    // prob3_sum
    float ps = 0.f;
    for (int i = tid; i < npsum; i += 256) ps += psum[i];
    float ss = 0.f;
    for (int p = tid; p < PNUM; p += 256) ss += fsig_fast(fl3_b[p]);
    float comb = ps - (float)padrows * ss;
    comb = wave_reduce(comb);
    if ((tid & 63) == 0) red[tid >> 6] = comb;
    __syncthreads();
    if (tid == 0) out[5] = red[0] + red[1] + red[2] + red[3];
    __syncthreads();
    // out_cost
    float oc = 0.f;
    for (int b = tid; b < nbuck; b += 256) oc += ocpart[b];
    oc = wave_reduce(oc);
    if ((tid & 63) == 0) red[tid >> 6] = oc;
    __syncthreads();
    if (tid == 0) out[4] = red[0] + red[1] + red[2] + red[3];
    __syncthreads();
    // pred_obj
    float pv = 0.f;
    if (tid < 128) pv = gsum[tid] * (1.0f / (float)N) * fc3_w[tid];
    pv = wave_reduce(pv);
    if ((tid & 63) == 0) red[tid >> 6] = pv;
    __syncthreads();
    if (tid == 0) out[0] = red[0] + red[1] + fc3_b[0];
}

extern "C" void kernel_launch(void* const* d_in, const int* in_sizes, int n_in,
                              void* d_out, int out_size, void* d_ws, size_t ws_size,
                              hipStream_t stream) {
    const float* ntc   = (const float*)d_in[0];
    const float* norm  = (const float*)d_in[1];
    const float* sc    = (const float*)d_in[2];
    const float* gt    = (const float*)d_in[3];
    const float* fc_w  = (const float*)d_in[4];
    const float* fc_b  = (const float*)d_in[5];
    const float* w_nt  = (const float*)d_in[6];
    const float* w_rel = (const float*)d_in[7];
    const float* fc2_w = (const float*)d_in[8];
    const float* fc2_b = (const float*)d_in[9];
    const float* fc3_w = (const float*)d_in[10];
    const float* fc3_b = (const float*)d_in[11];
    const float* fl3_w = (const float*)d_in[12];
    const float* fl3_b = (const float*)d_in[13];
    const int* node_type = (const int*)d_in[14];
    const int* src   = (const int*)d_in[15];
    const int* dst   = (const int*)d_in[16];
    const int* etype = (const int*)d_in[17];
    int N = in_sizes[2];
    int E = in_sizes[1];
    int nb128 = (N + 127) / 128;             // 391
    int padN  = nb128 * 128;                 // 50048
    int nbuck = padN / BNODES;               // 782
    int npsum = nb128 * 2;                   // 782

    // ---- workspace layout (float offsets) ----
    float* ws   = (float*)d_ws;
    float* C    = ws;                        // 0..6144
    unsigned short* wt = (unsigned short*)(ws + 6144);   // ..71680
    float* biasws = ws + 71680;              // ..72704
    float* gsum = ws + 72704;                // ..72832
    float* rs   = ws + 72832;                // ..73088
    float* cs   = ws + 73088;                // ..73344
    int*  cursor = (int*)(ws + 73344);       // ..74128 (784 ints)
    float* psum = ws + 74128;                // ..75152
    float* lce  = ws + 75152;                // ..75408
    float* ll2  = ws + 75408;                // ..75664
    float* ocpart = ws + 75664;              // ..76688
    float* gpart  = ws + 76688;              // ..176784 (782*128)
    float* pred = ws + 176784;               // ..+N
    unsigned short* hb = (unsigned short*)(pred + N);    // padN*128 bf16
    uint2* buck = (uint2*)(hb + (size_t)padN * H);       // nbuck*BCAP*8B
    float* out  = (float*)d_out;

    hipMemsetAsync(d_out, 0, 6 * sizeof(float), stream);
    hipMemsetAsync(cursor, 0, 784 * sizeof(int), stream);

    setup_kernel<<<1040, 128, 0, stream>>>(fl3_w, fl3_b, wt, biasws,
                                           fc_w, fc_b, w_nt, w_rel, C);
    partition_kernel<<<(E + EPB - 1) / EPB, 1024, 0, stream>>>(src, dst, etype, norm,
                                                               node_type, cursor, buck, E);
    bucket_node<<<nbuck, 256, 0, stream>>>(buck, cursor, ntc, C, fc2_w, fc2_b,
                                           hb, pred, gpart, N);
    prob3_mfma<<<dim3(nb128, 2), 256, 0, stream>>>(hb, wt, biasws, psum, nb128);
    agg_outcost<<<nbuck, 512, 0, stream>>>(buck, cursor, pred, sc, ocpart, N);
    rowcol_kernel<<<2 * MNUM, 256, 0, stream>>>(pred, rs, cs);
    losses_kernel<<<MNUM + 128, 256, 0, stream>>>(pred, gt, rs, cs, gpart, lce, ll2, gsum, nbuck);
    tail_kernel<<<1, 256, 0, stream>>>(rs, cs, lce, ll2, psum, npsum, ocpart, nbuck,
                                       gsum, fc3_w, fc3_b, fl3_b, out, N, padN - N);
}

// Round 13
// 244.324 us; speedup vs baseline: 1.3775x; 1.0281x over previous
//
#include <hip/hip_runtime.h>

#define H 128
#define RNUM 8
#define TNUM 2
#define PNUM 1000
#define MNUM 223
#define BNODES 64           // nodes per dst-bucket (power of 2)
#define NBUCK 782           // padN / 64
#define BCAP 2304           // per-bucket capacity (mean 2048, +5.7 sigma)
#define EPB 8192            // edges per partition block

typedef __attribute__((ext_vector_type(8))) short bf16x8;
typedef __attribute__((ext_vector_type(4))) float f32x4;

__device__ __forceinline__ float fsig(float z) {
    return 1.0f / (1.0f + __expf(-z));
}
__device__ __forceinline__ float fsig_fast(float z) {
    return __builtin_amdgcn_rcpf(1.0f + __expf(-z));
}

__device__ __forceinline__ float wave_reduce(float v) {
#pragma unroll
    for (int off = 32; off > 0; off >>= 1) v += __shfl_down(v, off, 64);
    return v;
}

__device__ __forceinline__ unsigned short f2bf(float f) {
    unsigned int u = __float_as_uint(f);
    u += 0x7fffu + ((u >> 16) & 1u);   // RNE
    return (unsigned short)(u >> 16);
}

// ---------------------------------------------------------------------------
// K1 (fused setup): blocks 0..1023 -> wt/bias transpose+pad; blocks
// 1024..1039 -> C precompute (tr = blk-1024). 128 threads each.
// ---------------------------------------------------------------------------
__global__ void setup_kernel(const float* __restrict__ fl3_w, const float* __restrict__ fl3_b,
                             unsigned short* __restrict__ wt, float* __restrict__ biasws,
                             const float* __restrict__ fc_w, const float* __restrict__ fc_b,
                             const float* __restrict__ w_nt, const float* __restrict__ w_rel,
                             float* __restrict__ C) {
    __shared__ float G[3][H];
    int blk = blockIdx.x;
    int i = threadIdx.x;
    if (blk < 1024) {
        int p = blk;
        float v = (p < PNUM) ? fl3_w[(size_t)i * PNUM + p] : 0.0f;
        wt[(size_t)p * H + i] = f2bf(v);
        if (i == 0) biasws[p] = (p < PNUM) ? fl3_b[p] : -1.0e4f;
        return;
    }
    int tr = blk - 1024;            // t*8+r
    int t = tr >> 3, r = tr & 7;
    float a0 = 0.f, a1 = 0.f, a2 = 0.f;
#pragma unroll 8
    for (int j = 0; j < H; ++j) {
        float w = w_nt[((size_t)t * H + j) * H + i];
        a0 += fc_w[j] * w;
        a1 += fc_w[H + j] * w;
        a2 += fc_b[j] * w;
    }
    G[0][i] = a0; G[1][i] = a1; G[2][i] = a2;
    __syncthreads();
    float c0 = 0.f, c1 = 0.f, c2 = 0.f;
#pragma unroll 8
    for (int k = 0; k < H; ++k) {
        float w = w_rel[((size_t)r * H + k) * H + i];
        c0 += G[0][k] * w;
        c1 += G[1][k] * w;
        c2 += G[2][k] * w;
    }
    C[((size_t)tr * 3 + 0) * H + i] = c0;
    C[((size_t)tr * 3 + 1) * H + i] = c1;
    C[((size_t)tr * 3 + 2) * H + i] = c2;
}

// K1b: CbT[o][k] = bf16(C[k][o]), k padded 48->64 with zeros. 128 blocks x 64.
__global__ void cbt_kernel(const float* __restrict__ C, unsigned short* __restrict__ CbT) {
    int o = blockIdx.x;
    int k = threadIdx.x;
    CbT[o * 64 + k] = (k < 48) ? f2bf(C[k * 128 + o]) : (unsigned short)0;
}

// ---------------------------------------------------------------------------
// K2: partition edges into 64-node dst buckets. Payload 8B:
//   .x = src | (local<<18) | (r<<24) | (t<<27); .y = bits(norm)
// ---------------------------------------------------------------------------
__global__ __launch_bounds__(1024) void partition_kernel(
        const int* __restrict__ src, const int* __restrict__ dst,
        const int* __restrict__ etype, const float* __restrict__ norm,
        const int* __restrict__ node_type, int* __restrict__ cursor,
        uint2* __restrict__ buck, int E) {
    __shared__ int lh[NBUCK];
    __shared__ int gb[NBUCK];
    int tid = threadIdx.x;
    for (int i = tid; i < NBUCK; i += 1024) lh[i] = 0;
    __syncthreads();
    int base = blockIdx.x * EPB;
    uint2 pl[8]; int bb[8]; int rk[8];
#pragma unroll
    for (int c = 0; c < 8; ++c) {
        int e = base + c * 1024 + tid;
        bb[c] = -1;
        if (e < E) {
            int s = src[e];
            int d = dst[e];
            int r = etype[e];
            float nm = norm[e];
            int t = node_type[s];
            int b = d >> 6;
            int local = d & 63;
            pl[c].x = (unsigned)s | ((unsigned)local << 18) | ((unsigned)r << 24) | ((unsigned)t << 27);
            pl[c].y = __float_as_uint(nm);
            bb[c] = b;
            rk[c] = atomicAdd(&lh[b], 1);
        }
    }
    __syncthreads();
    for (int i = tid; i < NBUCK; i += 1024) {
        if (lh[i] > 0) {
            int g = atomicAdd(&cursor[i], lh[i]);
            gb[i] = (g < 0) ? 0 : (g > BCAP ? BCAP : g);
        }
    }
    __syncthreads();
#pragma unroll
    for (int c = 0; c < 8; ++c) {
        if (bb[c] >= 0) {
            int pos = gb[bb[c]] + rk[c];
            if (pos < BCAP) buck[(size_t)bb[c] * BCAP + pos] = pl[c];
        }
    }
}

// ---------------------------------------------------------------------------
// K3: per-bucket replay (4-deep pipelined) -> S[64][68] fp32 LDS, then
// h = relu(S@C) via bf16 MFMA (layouts verified in prob3_mfma since R5):
// A[m=lane&15][k=ks*32+quad*8+j] from S rows; B[n][k] from CbT rows;
// D col=lane&15, row=quad*4+reg. Epilogue: hb bf16, pred, gsum partial.
// LDS: S 17.4KB + Cb 18.4KB + gloc 0.5KB = 36.4KB -> 4 blocks/CU.
// ---------------------------------------------------------------------------
__global__ __launch_bounds__(256) void bucket_node(
        const uint2* __restrict__ buck, const int* __restrict__ cursor,
        const float* __restrict__ ntc, const unsigned short* __restrict__ CbT,
        const float* __restrict__ fc2_w, const float* __restrict__ fc2_b,
        unsigned short* __restrict__ hb, float* __restrict__ pred,
        float* __restrict__ gpart, int N) {
    __shared__ float S[64 * 68];            // rows padded to 68 (bank spread)
    __shared__ unsigned short Cb[128 * 72]; // CbT rows padded to 72 shorts
    __shared__ float gloc[128];
    int tid = threadIdx.x;
    int bkt = blockIdx.x;
    for (int i = tid; i < 64 * 68; i += 256) S[i] = 0.0f;
    for (int g = tid; g < 1024; g += 256) {   // stage CbT: 1024 uint4
        int row = g >> 3, c = g & 7;
        uint4 v = ((const uint4*)CbT)[g];
        *(uint4*)(Cb + row * 72 + c * 8) = v;
    }
    if (tid < 128) gloc[tid] = 0.0f;
    __syncthreads();

    int cnt = cursor[bkt];
    if (cnt > BCAP) cnt = BCAP;
    if (cnt < 0) cnt = 0;
    const uint2* bp = buck + (size_t)bkt * BCAP;
    for (int base = 0; base < cnt; base += 1024) {
        uint2 pl[4]; float2 cc[4]; int ii[4];
#pragma unroll
        for (int j = 0; j < 4; ++j) {
            ii[j] = base + j * 256 + tid;
            pl[j] = (ii[j] < cnt) ? bp[ii[j]] : make_uint2(0u, 0u);
        }
#pragma unroll
        for (int j = 0; j < 4; ++j)
            cc[j] = (ii[j] < cnt) ? ((const float2*)ntc)[pl[j].x & 0x3FFFF]
                                  : make_float2(0.f, 0.f);
#pragma unroll
        for (int j = 0; j < 4; ++j) {
            if (ii[j] < cnt) {
                int local = (pl[j].x >> 18) & 63;
                int tr = ((pl[j].x >> 24) & 7) + (((pl[j].x >> 27) & 1) << 3);
                float nm = __uint_as_float(pl[j].y);
                float* p = &S[local * 68 + tr * 3];
                atomicAdd(p, nm * cc[j].x);
                atomicAdd(p + 1, nm * cc[j].y);
                atomicAdd(p + 2, nm);
            }
        }
    }
    __syncthreads();

    int lane = tid & 63, w = tid >> 6;
    int lrow = lane & 15, quad = lane >> 4;

    // A-frags: rows w*16+lrow of S (fp32 -> bf16)
    bf16x8 a[2];
#pragma unroll
    for (int ks = 0; ks < 2; ++ks) {
        const float* sp = S + (w * 16 + lrow) * 68 + ks * 32 + quad * 8;
        float4 f0 = *(const float4*)sp;
        float4 f1 = *(const float4*)(sp + 4);
        bf16x8 t;
        t[0] = (short)f2bf(f0.x); t[1] = (short)f2bf(f0.y);
        t[2] = (short)f2bf(f0.z); t[3] = (short)f2bf(f0.w);
        t[4] = (short)f2bf(f1.x); t[5] = (short)f2bf(f1.y);
        t[6] = (short)f2bf(f1.z); t[7] = (short)f2bf(f1.w);
        a[ks] = t;
    }

    f32x4 acc[8];
#pragma unroll
    for (int tn = 0; tn < 8; ++tn) acc[tn] = (f32x4){0.f, 0.f, 0.f, 0.f};
#pragma unroll
    for (int ks = 0; ks < 2; ++ks) {
#pragma unroll
        for (int tn = 0; tn < 8; ++tn) {
            bf16x8 b = *(const bf16x8*)(Cb + (tn * 16 + lrow) * 72 + ks * 32 + quad * 8);
            acc[tn] = __builtin_amdgcn_mfma_f32_16x16x32_bf16(a[ks], b, acc[tn], 0, 0, 0);
        }
    }

    // relu
#pragma unroll
    for (int tn = 0; tn < 8; ++tn)
#pragma unroll
        for (int r = 0; r < 4; ++r) acc[tn][r] = fmaxf(acc[tn][r], 0.f);

    int vbase = bkt * BNODES + w * 16 + quad * 4;
    // hb stores (pad rows write zeros; D row=quad*4+r, col=lane&15)
#pragma unroll
    for (int r = 0; r < 4; ++r) {
        unsigned short* hrow = hb + (size_t)(vbase + r) * H + lrow;
#pragma unroll
        for (int tn = 0; tn < 8; ++tn) hrow[tn * 16] = f2bf(acc[tn][r]);
    }
    // pred: dot over 128 cols = reduce over 16 lanes of the quad
    float pd[4];
#pragma unroll
    for (int r = 0; r < 4; ++r) {
        float s = 0.f;
#pragma unroll
        for (int tn = 0; tn < 8; ++tn) s += acc[tn][r] * fc2_w[tn * 16 + lrow];
        pd[r] = s;
    }
#pragma unroll
    for (int mask = 1; mask < 16; mask <<= 1)
#pragma unroll
        for (int r = 0; r < 4; ++r) pd[r] += __shfl_xor(pd[r], mask, 64);
    if (lrow == 0) {
#pragma unroll
        for (int r = 0; r < 4; ++r) {
            int v = vbase + r;
            if (v < N) {
                float z = pd[r] + fc2_b[0];
                pred[v] = fminf(fmaxf(fsig(z), 1e-7f), 1e10f);
            }
        }
    }
    // gsum partial: column sums over this wave's 16 rows
    float csum[8];
#pragma unroll
    for (int tn = 0; tn < 8; ++tn)
        csum[tn] = acc[tn][0] + acc[tn][1] + acc[tn][2] + acc[tn][3];
#pragma unroll
    for (int mask = 16; mask < 64; mask <<= 1)
#pragma unroll
        for (int tn = 0; tn < 8; ++tn) csum[tn] += __shfl_xor(csum[tn], mask, 64);
    if (lane < 16) {
#pragma unroll
        for (int tn = 0; tn < 8; ++tn) atomicAdd(&gloc[tn * 16 + lrow], csum[tn]);
    }
    __syncthreads();
    if (tid < 128) gpart[(size_t)bkt * 128 + tid] = gloc[tid];
}

// ---------------------------------------------------------------------------
// K4: prob3 via bf16 MFMA, maskless; per-block plain store to psum.
// ---------------------------------------------------------------------------
__global__ __launch_bounds__(256, 2) void prob3_mfma(const unsigned short* __restrict__ hb,
                                                     const unsigned short* __restrict__ wt,
                                                     const float* __restrict__ biasws,
                                                     float* __restrict__ psum, int nb128) {
    __shared__ unsigned short Bsh[128 * 136];
    __shared__ float wsum[4];
    int tid = threadIdx.x;
    int n0 = blockIdx.x * 128;
    int pt0 = blockIdx.y * 4;

    int lane = tid & 63, wid = tid >> 6;
    int wy = wid >> 1, wx = wid & 1;
    int lrow = lane & 15, quad = lane >> 4;

    bf16x8 a[4][4];
#pragma unroll
    for (int tm = 0; tm < 4; ++tm) {
        const unsigned short* arow = hb + (size_t)(n0 + wy * 64 + tm * 16 + lrow) * H + quad * 8;
#pragma unroll
        for (int ks = 0; ks < 4; ++ks)
            a[tm][ks] = *(const bf16x8*)(arow + ks * 32);
    }

    float lsum = 0.f;
    for (int pi = 0; pi < 4; ++pi) {
        int pt = pt0 + pi;
        __syncthreads();
        {
            int c = tid & 15;
            int r0 = tid >> 4;
#pragma unroll
            for (int it = 0; it < 8; ++it) {
                int row = r0 + it * 16;
                uint4 bv = *(const uint4*)(wt + (size_t)(pt * 128 + row) * H + c * 8);
                *(uint4*)(Bsh + row * 136 + c * 8) = bv;
            }
        }
        __syncthreads();

        f32x4 acc[4][4];
#pragma unroll
        for (int tm = 0; tm < 4; ++tm)
#pragma unroll
            for (int tn = 0; tn < 4; ++tn)
                acc[tm][tn] = (f32x4){0.f, 0.f, 0.f, 0.f};

        const unsigned short* Bbase = Bsh + (wx * 64 + lrow) * 136 + quad * 8;
#pragma unroll
        for (int ks = 0; ks < 4; ++ks) {
            bf16x8 b[4];
#pragma unroll
            for (int tn = 0; tn < 4; ++tn)
                b[tn] = *(const bf16x8*)(Bbase + tn * 16 * 136 + ks * 32);
#pragma unroll
            for (int tm = 0; tm < 4; ++tm)
#pragma unroll
                for (int tn = 0; tn < 4; ++tn)
                    acc[tm][tn] = __builtin_amdgcn_mfma_f32_16x16x32_bf16(a[tm][ks], b[tn], acc[tm][tn], 0, 0, 0);
        }

#pragma unroll
        for (int tn = 0; tn < 4; ++tn) {
            float bv = biasws[pt * 128 + wx * 64 + tn * 16 + lrow];
#pragma unroll
            for (int tm = 0; tm < 4; ++tm) {
#pragma unroll
                for (int r = 0; r < 4; ++r)
                    lsum += fsig_fast(acc[tm][tn][r] + bv);
            }
        }
    }
    lsum = wave_reduce(lsum);
    if (lane == 0) wsum[wid] = lsum;
    __syncthreads();
    if (tid == 0)
        psum[blockIdx.y * nb128 + blockIdx.x] = wsum[0] + wsum[1] + wsum[2] + wsum[3];
}

// ---------------------------------------------------------------------------
// K5: per-bucket agg[dst] += pred[src] in LDS (4-deep pipelined gathers);
// out_cost partial plain-stored.
// ---------------------------------------------------------------------------
__global__ __launch_bounds__(512) void agg_outcost(
        const uint2* __restrict__ buck, const int* __restrict__ cursor,
        const float* __restrict__ pred, const float* __restrict__ sc,
        float* __restrict__ ocpart, int N) {
    __shared__ float agg[BNODES];
    int tid = threadIdx.x;
    int bkt = blockIdx.x;
    if (tid < BNODES) agg[tid] = 0.0f;
    __syncthreads();
    int cnt = cursor[bkt];
    if (cnt > BCAP) cnt = BCAP;
    if (cnt < 0) cnt = 0;
    const uint2* bp = buck + (size_t)bkt * BCAP;
    for (int base = 0; base < cnt; base += 2048) {
        unsigned x[4]; float pv[4]; int ii[4];
#pragma unroll
        for (int j = 0; j < 4; ++j) {
            ii[j] = base + j * 512 + tid;
            x[j] = (ii[j] < cnt) ? bp[ii[j]].x : 0u;
        }
#pragma unroll
        for (int j = 0; j < 4; ++j)
            pv[j] = (ii[j] < cnt) ? pred[x[j] & 0x3FFFF] : 0.f;
#pragma unroll
        for (int j = 0; j < 4; ++j)
            if (ii[j] < cnt) atomicAdd(&agg[(x[j] >> 18) & 63], pv[j]);
    }
    __syncthreads();
    if (tid < 64) {
        float v = 0.f;
        int node = bkt * BNODES + tid;
        if (node < N) {
            float d = agg[tid] - 1.0f;
            v = d * d * sc[node];
        }
        v = wave_reduce(v);
        if (tid == 0) ocpart[bkt] = v;
    }
}

// K6: rs (blocks 0..222) and cs (blocks 223..445), plain stores, no atomics.
__global__ void rowcol_kernel(const float* __restrict__ pred, float* __restrict__ rs,
                              float* __restrict__ cs) {
    __shared__ float red[4];
    int blk = blockIdx.x, tid = threadIdx.x;
    float p = 0.f;
    if (blk < MNUM) {
        if (tid < MNUM) p = pred[blk * MNUM + tid];
    } else {
        int j = blk - MNUM;
        if (tid < MNUM) p = pred[tid * MNUM + j];
    }
    p = wave_reduce(p);
    if ((tid & 63) == 0) red[tid >> 6] = p;
    __syncthreads();
    if (tid == 0) {
        float s = red[0] + red[1] + red[2] + red[3];
        if (blk < MNUM) rs[blk] = s; else cs[blk - MNUM] = s;
    }
}

// K7: blocks 0..222: per-row ce/l2 plain stores. blocks 223..350: gsum dim
// reduction from gpart (plain stores).
__global__ void losses_kernel(const float* __restrict__ pred, const float* __restrict__ gt,
                              const float* __restrict__ rs, const float* __restrict__ cs,
                              const float* __restrict__ gpart, float* __restrict__ lce,
                              float* __restrict__ ll2, float* __restrict__ gsum, int nbuck) {
    __shared__ float redc[4], redl[4];
    int blk = blockIdx.x, tid = threadIdx.x;
    if (blk < MNUM) {
        float ce = 0.f, l2 = 0.f;
        if (tid < MNUM) {
            float p = pred[blk * MNUM + tid];
            ce = -gt[blk * MNUM + tid] * __log2f(p);
            l2 = p * (rs[blk] + cs[tid] - 2.0f * p);
        }
        ce = wave_reduce(ce);
        l2 = wave_reduce(l2);
        if ((tid & 63) == 0) { redc[tid >> 6] = ce; redl[tid >> 6] = l2; }
        __syncthreads();
        if (tid == 0) {
            lce[blk] = redc[0] + redc[1] + redc[2] + redc[3];
            ll2[blk] = redl[0] + redl[1] + redl[2] + redl[3];
        }
    } else {
        int dim = blk - MNUM;  // 0..127
        float s = 0.f;
        for (int b = tid; b < nbuck; b += 256) s += gpart[(size_t)b * 128 + dim];
        s = wave_reduce(s);
        if ((tid & 63) == 0) redc[tid >> 6] = s;
        __syncthreads();
        if (tid == 0) gsum[dim] = redc[0] + redc[1] + redc[2] + redc[3];
    }
}

// K8: single-block tail: all six outputs via plain stores.
__global__ void tail_kernel(const float* __restrict__ rs, const float* __restrict__ cs,
                            const float* __restrict__ lce, const float* __restrict__ ll2,
                            const float* __restrict__ psum, int npsum,
                            const float* __restrict__ ocpart, int nbuck,
                            const float* __restrict__ gsum, const float* __restrict__ fc3_w,
                            const float* __restrict__ fc3_b, const float* __restrict__ fl3_b,
                            float* __restrict__ out, int N, int padrows) {
    __shared__ float red[4];
    int tid = threadIdx.x;
    // sumone
    float v = 0.f;
    if (tid < MNUM) {
        float a = rs[tid] - 1.0f, b = cs[tid] - 1.0f;
        v = a * a + b * b;
    }
    v = wave_reduce(v);
    if ((tid & 63) == 0) red[tid >> 6] = v;
    __syncthreads();
    if (tid == 0) out[1] = red[0] + red[1] + red[2] + red[3];
    __syncthreads();
    // ce
    float ce = (tid < MNUM) ? lce[tid] : 0.f;
    ce = wave_reduce(ce);
    if ((tid & 63) == 0) red[tid >> 6] = ce;
    __syncthreads();
    if (tid == 0) out[3] = red[0] + red[1] + red[2] + red[3];
    __syncthreads();
    // loss2
    float l2 = (tid < MNUM) ? ll2[tid] : 0.f;
    l2 = wave_reduce(l2);
    if ((tid & 63) == 0) red[tid >> 6] = l2;
    __syncthreads();
    if (tid == 0) out[2] = red[0] + red[1] + red[2] + red[3];
    __syncthreads();
    // prob3_sum
    float ps = 0.f;
    for (int i = tid; i < npsum; i += 256) ps += psum[i];
    float ss = 0.f;
    for (int p = tid; p < PNUM; p += 256) ss += fsig_fast(fl3_b[p]);
    float comb = ps - (float)padrows * ss;
    comb = wave_reduce(comb);
    if ((tid & 63) == 0) red[tid >> 6] = comb;
    __syncthreads();
    if (tid == 0) out[5] = red[0] + red[1] + red[2] + red[3];
    __syncthreads();
    // out_cost
    float oc = 0.f;
    for (int b = tid; b < nbuck; b += 256) oc += ocpart[b];
    oc = wave_reduce(oc);
    if ((tid & 63) == 0) red[tid >> 6] = oc;
    __syncthreads();
    if (tid == 0) out[4] = red[0] + red[1] + red[2] + red[3];
    __syncthreads();
    // pred_obj
    float pv = 0.f;
    if (tid < 128) pv = gsum[tid] * (1.0f / (float)N) * fc3_w[tid];
    pv = wave_reduce(pv);
    if ((tid & 63) == 0) red[tid >> 6] = pv;
    __syncthreads();
    if (tid == 0) out[0] = red[0] + red[1] + fc3_b[0];
}

extern "C" void kernel_launch(void* const* d_in, const int* in_sizes, int n_in,
                              void* d_out, int out_size, void* d_ws, size_t ws_size,
                              hipStream_t stream) {
    const float* ntc   = (const float*)d_in[0];
    const float* norm  = (const float*)d_in[1];
    const float* sc    = (const float*)d_in[2];
    const float* gt    = (const float*)d_in[3];
    const float* fc_w  = (const float*)d_in[4];
    const float* fc_b  = (const float*)d_in[5];
    const float* w_nt  = (const float*)d_in[6];
    const float* w_rel = (const float*)d_in[7];
    const float* fc2_w = (const float*)d_in[8];
    const float* fc2_b = (const float*)d_in[9];
    const float* fc3_w = (const float*)d_in[10];
    const float* fc3_b = (const float*)d_in[11];
    const float* fl3_w = (const float*)d_in[12];
    const float* fl3_b = (const float*)d_in[13];
    const int* node_type = (const int*)d_in[14];
    const int* src   = (const int*)d_in[15];
    const int* dst   = (const int*)d_in[16];
    const int* etype = (const int*)d_in[17];
    int N = in_sizes[2];
    int E = in_sizes[1];
    int nb128 = (N + 127) / 128;             // 391
    int padN  = nb128 * 128;                 // 50048
    int nbuck = padN / BNODES;               // 782
    int npsum = nb128 * 2;                   // 782

    // ---- workspace layout (float offsets) ----
    float* ws   = (float*)d_ws;
    float* C    = ws;                        // 0..6144
    unsigned short* wt = (unsigned short*)(ws + 6144);   // ..71680
    float* biasws = ws + 71680;              // ..72704
    float* gsum = ws + 72704;                // ..72832
    float* rs   = ws + 72832;                // ..73088
    float* cs   = ws + 73088;                // ..73344
    int*  cursor = (int*)(ws + 73344);       // ..74128 (784 ints)
    float* psum = ws + 74128;                // ..75152
    float* lce  = ws + 75152;                // ..75408
    float* ll2  = ws + 75408;                // ..75664
    float* ocpart = ws + 75664;              // ..76688
    unsigned short* CbT = (unsigned short*)(ws + 76688); // 128*64 shorts = ..80784
    float* gpart  = ws + 80784;              // ..180880 (782*128)
    float* pred = ws + 180880;               // ..+N
    unsigned short* hb = (unsigned short*)(pred + N);    // padN*128 bf16
    uint2* buck = (uint2*)(hb + (size_t)padN * H);       // nbuck*BCAP*8B
    float* out  = (float*)d_out;

    hipMemsetAsync(d_out, 0, 6 * sizeof(float), stream);
    hipMemsetAsync(cursor, 0, 784 * sizeof(int), stream);

    setup_kernel<<<1040, 128, 0, stream>>>(fl3_w, fl3_b, wt, biasws,
                                           fc_w, fc_b, w_nt, w_rel, C);
    cbt_kernel<<<128, 64, 0, stream>>>(C, CbT);
    partition_kernel<<<(E + EPB - 1) / EPB, 1024, 0, stream>>>(src, dst, etype, norm,
                                                               node_type, cursor, buck, E);
    bucket_node<<<nbuck, 256, 0, stream>>>(buck, cursor, ntc, CbT, fc2_w, fc2_b,
                                           hb, pred, gpart, N);
    prob3_mfma<<<dim3(nb128, 2), 256, 0, stream>>>(hb, wt, biasws, psum, nb128);
    agg_outcost<<<nbuck, 512, 0, stream>>>(buck, cursor, pred, sc, ocpart, N);
    rowcol_kernel<<<2 * MNUM, 256, 0, stream>>>(pred, rs, cs);
    losses_kernel<<<MNUM + 128, 256, 0, stream>>>(pred, gt, rs, cs, gpart, lce, ll2, gsum, nbuck);
    tail_kernel<<<1, 256, 0, stream>>>(rs, cs, lce, ll2, psum, npsum, ocpart, nbuck,
                                       gsum, fc3_w, fc3_b, fl3_b, out, N, padN - N);
}

// Round 14
// 238.568 us; speedup vs baseline: 1.4108x; 1.0241x over previous
//
#include <hip/hip_runtime.h>

#define H 128
#define RNUM 8
#define TNUM 2
#define PNUM 1000
#define MNUM 223
#define BNODES 64           // nodes per dst-bucket (power of 2)
#define NBUCK 782           // padN / 64
#define BCAP 2304           // per-bucket capacity (mean 2048, +5.7 sigma)
#define EPB 8192            // edges per partition block

typedef __attribute__((ext_vector_type(8))) short bf16x8;
typedef __attribute__((ext_vector_type(4))) float f32x4;

__device__ __forceinline__ float fsig(float z) {
    return 1.0f / (1.0f + __expf(-z));
}
__device__ __forceinline__ float fsig_fast(float z) {
    return __builtin_amdgcn_rcpf(1.0f + __expf(-z));
}

__device__ __forceinline__ float wave_reduce(float v) {
#pragma unroll
    for (int off = 32; off > 0; off >>= 1) v += __shfl_down(v, off, 64);
    return v;
}

__device__ __forceinline__ unsigned short f2bf(float f) {
    unsigned int u = __float_as_uint(f);
    u += 0x7fffu + ((u >> 16) & 1u);   // RNE
    return (unsigned short)(u >> 16);
}

// ---------------------------------------------------------------------------
// K1 (fused setup): blocks 0..1023 -> wt/bias transpose+pad; blocks
// 1024..1039 -> C precompute (tr = blk-1024). 128 threads each.
// ---------------------------------------------------------------------------
__global__ void setup_kernel(const float* __restrict__ fl3_w, const float* __restrict__ fl3_b,
                             unsigned short* __restrict__ wt, float* __restrict__ biasws,
                             const float* __restrict__ fc_w, const float* __restrict__ fc_b,
                             const float* __restrict__ w_nt, const float* __restrict__ w_rel,
                             float* __restrict__ C) {
    __shared__ float G[3][H];
    int blk = blockIdx.x;
    int i = threadIdx.x;
    if (blk < 1024) {
        int p = blk;
        float v = (p < PNUM) ? fl3_w[(size_t)i * PNUM + p] : 0.0f;
        wt[(size_t)p * H + i] = f2bf(v);
        if (i == 0) biasws[p] = (p < PNUM) ? fl3_b[p] : -1.0e4f;
        return;
    }
    int tr = blk - 1024;            // t*8+r
    int t = tr >> 3, r = tr & 7;
    float a0 = 0.f, a1 = 0.f, a2 = 0.f;
#pragma unroll 8
    for (int j = 0; j < H; ++j) {
        float w = w_nt[((size_t)t * H + j) * H + i];
        a0 += fc_w[j] * w;
        a1 += fc_w[H + j] * w;
        a2 += fc_b[j] * w;
    }
    G[0][i] = a0; G[1][i] = a1; G[2][i] = a2;
    __syncthreads();
    float c0 = 0.f, c1 = 0.f, c2 = 0.f;
#pragma unroll 8
    for (int k = 0; k < H; ++k) {
        float w = w_rel[((size_t)r * H + k) * H + i];
        c0 += G[0][k] * w;
        c1 += G[1][k] * w;
        c2 += G[2][k] * w;
    }
    C[((size_t)tr * 3 + 0) * H + i] = c0;
    C[((size_t)tr * 3 + 1) * H + i] = c1;
    C[((size_t)tr * 3 + 2) * H + i] = c2;
}

// K1b: CbT[o][k] = bf16(C[k][o]), k padded 48->64 with zeros. 128 blocks x 64.
__global__ void cbt_kernel(const float* __restrict__ C, unsigned short* __restrict__ CbT) {
    int o = blockIdx.x;
    int k = threadIdx.x;
    CbT[o * 64 + k] = (k < 48) ? f2bf(C[k * 128 + o]) : (unsigned short)0;
}

// ---------------------------------------------------------------------------
// K2: partition edges into 64-node dst buckets. Payload 8B:
//   .x = src | (local<<18) | (r<<24) | (t<<27); .y = bits(norm)
// ---------------------------------------------------------------------------
__global__ __launch_bounds__(1024) void partition_kernel(
        const int* __restrict__ src, const int* __restrict__ dst,
        const int* __restrict__ etype, const float* __restrict__ norm,
        const int* __restrict__ node_type, int* __restrict__ cursor,
        uint2* __restrict__ buck, int E) {
    __shared__ int lh[NBUCK];
    __shared__ int gb[NBUCK];
    int tid = threadIdx.x;
    for (int i = tid; i < NBUCK; i += 1024) lh[i] = 0;
    __syncthreads();
    int base = blockIdx.x * EPB;
    uint2 pl[8]; int bb[8]; int rk[8];
#pragma unroll
    for (int c = 0; c < 8; ++c) {
        int e = base + c * 1024 + tid;
        bb[c] = -1;
        if (e < E) {
            int s = src[e];
            int d = dst[e];
            int r = etype[e];
            float nm = norm[e];
            int t = node_type[s];
            int b = d >> 6;
            int local = d & 63;
            pl[c].x = (unsigned)s | ((unsigned)local << 18) | ((unsigned)r << 24) | ((unsigned)t << 27);
            pl[c].y = __float_as_uint(nm);
            bb[c] = b;
            rk[c] = atomicAdd(&lh[b], 1);
        }
    }
    __syncthreads();
    for (int i = tid; i < NBUCK; i += 1024) {
        if (lh[i] > 0) {
            int g = atomicAdd(&cursor[i], lh[i]);
            gb[i] = (g < 0) ? 0 : (g > BCAP ? BCAP : g);
        }
    }
    __syncthreads();
#pragma unroll
    for (int c = 0; c < 8; ++c) {
        if (bb[c] >= 0) {
            int pos = gb[bb[c]] + rk[c];
            if (pos < BCAP) buck[(size_t)bb[c] * BCAP + pos] = pl[c];
        }
    }
}

// ---------------------------------------------------------------------------
// K3: per-bucket replay (8-deep pipelined) -> S[64][68] fp32 LDS, then
// h = relu(S@C) via bf16 MFMA. Epilogue: hb bf16, pred, gsum partial.
// ---------------------------------------------------------------------------
__global__ __launch_bounds__(256) void bucket_node(
        const uint2* __restrict__ buck, const int* __restrict__ cursor,
        const float* __restrict__ ntc, const unsigned short* __restrict__ CbT,
        const float* __restrict__ fc2_w, const float* __restrict__ fc2_b,
        unsigned short* __restrict__ hb, float* __restrict__ pred,
        float* __restrict__ gpart, int N) {
    __shared__ float S[64 * 68];            // rows padded to 68 (bank spread)
    __shared__ unsigned short Cb[128 * 72]; // CbT rows padded to 72 shorts
    __shared__ float gloc[128];
    int tid = threadIdx.x;
    int bkt = blockIdx.x;
    for (int i = tid; i < 64 * 68; i += 256) S[i] = 0.0f;
    for (int g = tid; g < 1024; g += 256) {   // stage CbT: 1024 uint4
        int row = g >> 3, c = g & 7;
        uint4 v = ((const uint4*)CbT)[g];
        *(uint4*)(Cb + row * 72 + c * 8) = v;
    }
    if (tid < 128) gloc[tid] = 0.0f;
    __syncthreads();

    int cnt = cursor[bkt];
    if (cnt > BCAP) cnt = BCAP;
    if (cnt < 0) cnt = 0;
    const uint2* bp = buck + (size_t)bkt * BCAP;
    for (int base = 0; base < cnt; base += 2048) {
        uint2 pl[8]; float2 cc[8]; int ii[8];
#pragma unroll
        for (int j = 0; j < 8; ++j) {
            ii[j] = base + j * 256 + tid;
            pl[j] = (ii[j] < cnt) ? bp[ii[j]] : make_uint2(0u, 0u);
        }
#pragma unroll
        for (int j = 0; j < 8; ++j)
            cc[j] = (ii[j] < cnt) ? ((const float2*)ntc)[pl[j].x & 0x3FFFF]
                                  : make_float2(0.f, 0.f);
#pragma unroll
        for (int j = 0; j < 8; ++j) {
            if (ii[j] < cnt) {
                int local = (pl[j].x >> 18) & 63;
                int tr = ((pl[j].x >> 24) & 7) + (((pl[j].x >> 27) & 1) << 3);
                float nm = __uint_as_float(pl[j].y);
                float* p = &S[local * 68 + tr * 3];
                atomicAdd(p, nm * cc[j].x);
                atomicAdd(p + 1, nm * cc[j].y);
                atomicAdd(p + 2, nm);
            }
        }
    }
    __syncthreads();

    int lane = tid & 63, w = tid >> 6;
    int lrow = lane & 15, quad = lane >> 4;

    // A-frags: rows w*16+lrow of S (fp32 -> bf16)
    bf16x8 a[2];
#pragma unroll
    for (int ks = 0; ks < 2; ++ks) {
        const float* sp = S + (w * 16 + lrow) * 68 + ks * 32 + quad * 8;
        float4 f0 = *(const float4*)sp;
        float4 f1 = *(const float4*)(sp + 4);
        bf16x8 t;
        t[0] = (short)f2bf(f0.x); t[1] = (short)f2bf(f0.y);
        t[2] = (short)f2bf(f0.z); t[3] = (short)f2bf(f0.w);
        t[4] = (short)f2bf(f1.x); t[5] = (short)f2bf(f1.y);
        t[6] = (short)f2bf(f1.z); t[7] = (short)f2bf(f1.w);
        a[ks] = t;
    }

    f32x4 acc[8];
#pragma unroll
    for (int tn = 0; tn < 8; ++tn) acc[tn] = (f32x4){0.f, 0.f, 0.f, 0.f};
#pragma unroll
    for (int ks = 0; ks < 2; ++ks) {
#pragma unroll
        for (int tn = 0; tn < 8; ++tn) {
            bf16x8 b = *(const bf16x8*)(Cb + (tn * 16 + lrow) * 72 + ks * 32 + quad * 8);
            acc[tn] = __builtin_amdgcn_mfma_f32_16x16x32_bf16(a[ks], b, acc[tn], 0, 0, 0);
        }
    }

    // relu
#pragma unroll
    for (int tn = 0; tn < 8; ++tn)
#pragma unroll
        for (int r = 0; r < 4; ++r) acc[tn][r] = fmaxf(acc[tn][r], 0.f);

    int vbase = bkt * BNODES + w * 16 + quad * 4;
#pragma unroll
    for (int r = 0; r < 4; ++r) {
        unsigned short* hrow = hb + (size_t)(vbase + r) * H + lrow;
#pragma unroll
        for (int tn = 0; tn < 8; ++tn) hrow[tn * 16] = f2bf(acc[tn][r]);
    }
    // pred: dot over 128 cols = reduce over 16 lanes of the quad
    float pd[4];
#pragma unroll
    for (int r = 0; r < 4; ++r) {
        float s = 0.f;
#pragma unroll
        for (int tn = 0; tn < 8; ++tn) s += acc[tn][r] * fc2_w[tn * 16 + lrow];
        pd[r] = s;
    }
#pragma unroll
    for (int mask = 1; mask < 16; mask <<= 1)
#pragma unroll
        for (int r = 0; r < 4; ++r) pd[r] += __shfl_xor(pd[r], mask, 64);
    if (lrow == 0) {
#pragma unroll
        for (int r = 0; r < 4; ++r) {
            int v = vbase + r;
            if (v < N) {
                float z = pd[r] + fc2_b[0];
                pred[v] = fminf(fmaxf(fsig(z), 1e-7f), 1e10f);
            }
        }
    }
    // gsum partial: column sums over this wave's 16 rows
    float csum[8];
#pragma unroll
    for (int tn = 0; tn < 8; ++tn)
        csum[tn] = acc[tn][0] + acc[tn][1] + acc[tn][2] + acc[tn][3];
#pragma unroll
    for (int mask = 16; mask < 64; mask <<= 1)
#pragma unroll
        for (int tn = 0; tn < 8; ++tn) csum[tn] += __shfl_xor(csum[tn], mask, 64);
    if (lane < 16) {
#pragma unroll
        for (int tn = 0; tn < 8; ++tn) atomicAdd(&gloc[tn * 16 + lrow], csum[tn]);
    }
    __syncthreads();
    if (tid < 128) gpart[(size_t)bkt * 128 + tid] = gloc[tid];
}

// ---------------------------------------------------------------------------
// K4 (MEGA): all post-bucket_node independent work in ONE launch.
// blocks [0, 2*nb128): prob3 MFMA tile (y = blk/nb128)
// blocks [2*nb128, +nbuck): agg_outcost (8-deep pipelined)
// blocks next 2*MNUM: rowcol (rs then cs)
// blocks next 128: gsum dim-reduction from gpart
// MFMA-heavy and latency-heavy blocks co-schedule on the same CUs.
// ---------------------------------------------------------------------------
__global__ __launch_bounds__(256, 2) void mega_kernel(
        const unsigned short* __restrict__ hb, const unsigned short* __restrict__ wt,
        const float* __restrict__ biasws, float* __restrict__ psum, int nb128,
        const uint2* __restrict__ buck, const int* __restrict__ cursor,
        const float* __restrict__ pred, const float* __restrict__ sc,
        float* __restrict__ ocpart, int N,
        float* __restrict__ rs, float* __restrict__ cs,
        const float* __restrict__ gpart, float* __restrict__ gsum, int nbuck) {
    __shared__ unsigned short Bsh[128 * 136];
    __shared__ float red[8];
    int blk = blockIdx.x;
    int tid = threadIdx.x;
    int P1 = 2 * nb128;
    int P2 = P1 + nbuck;
    int P3 = P2 + 2 * MNUM;

    if (blk < P1) {
        // ---------------- prob3 path ----------------
        int by = blk / nb128, bx = blk - by * nb128;
        int n0 = bx * 128;
        int pt0 = by * 4;
        int lane = tid & 63, wid = tid >> 6;
        int wy = wid >> 1, wx = wid & 1;
        int lrow = lane & 15, quad = lane >> 4;

        bf16x8 a[4][4];
#pragma unroll
        for (int tm = 0; tm < 4; ++tm) {
            const unsigned short* arow = hb + (size_t)(n0 + wy * 64 + tm * 16 + lrow) * H + quad * 8;
#pragma unroll
            for (int ks = 0; ks < 4; ++ks)
                a[tm][ks] = *(const bf16x8*)(arow + ks * 32);
        }

        float lsum = 0.f;
        for (int pi = 0; pi < 4; ++pi) {
            int pt = pt0 + pi;
            __syncthreads();
            {
                int c = tid & 15;
                int r0 = tid >> 4;
#pragma unroll
                for (int it = 0; it < 8; ++it) {
                    int row = r0 + it * 16;
                    uint4 bv = *(const uint4*)(wt + (size_t)(pt * 128 + row) * H + c * 8);
                    *(uint4*)(Bsh + row * 136 + c * 8) = bv;
                }
            }
            __syncthreads();

            f32x4 acc[4][4];
#pragma unroll
            for (int tm = 0; tm < 4; ++tm)
#pragma unroll
                for (int tn = 0; tn < 4; ++tn)
                    acc[tm][tn] = (f32x4){0.f, 0.f, 0.f, 0.f};

            const unsigned short* Bbase = Bsh + (wx * 64 + lrow) * 136 + quad * 8;
#pragma unroll
            for (int ks = 0; ks < 4; ++ks) {
                bf16x8 b[4];
#pragma unroll
                for (int tn = 0; tn < 4; ++tn)
                    b[tn] = *(const bf16x8*)(Bbase + tn * 16 * 136 + ks * 32);
#pragma unroll
                for (int tm = 0; tm < 4; ++tm)
#pragma unroll
                    for (int tn = 0; tn < 4; ++tn)
                        acc[tm][tn] = __builtin_amdgcn_mfma_f32_16x16x32_bf16(a[tm][ks], b[tn], acc[tm][tn], 0, 0, 0);
            }

#pragma unroll
            for (int tn = 0; tn < 4; ++tn) {
                float bv = biasws[pt * 128 + wx * 64 + tn * 16 + lrow];
#pragma unroll
                for (int tm = 0; tm < 4; ++tm) {
#pragma unroll
                    for (int r = 0; r < 4; ++r)
                        lsum += fsig_fast(acc[tm][tn][r] + bv);
                }
            }
        }
        lsum = wave_reduce(lsum);
        if (lane == 0) red[wid] = lsum;
        __syncthreads();
        if (tid == 0)
            psum[by * nb128 + bx] = red[0] + red[1] + red[2] + red[3];
    } else if (blk < P2) {
        // ---------------- agg_outcost path ----------------
        int bkt = blk - P1;
        float* agg = (float*)Bsh;   // 64 floats carved from Bsh
        if (tid < BNODES) agg[tid] = 0.0f;
        __syncthreads();
        int cnt = cursor[bkt];
        if (cnt > BCAP) cnt = BCAP;
        if (cnt < 0) cnt = 0;
        const uint2* bp = buck + (size_t)bkt * BCAP;
        for (int base = 0; base < cnt; base += 2048) {
            unsigned x[8]; float pv[8]; int ii[8];
#pragma unroll
            for (int j = 0; j < 8; ++j) {
                ii[j] = base + j * 256 + tid;
                x[j] = (ii[j] < cnt) ? bp[ii[j]].x : 0u;
            }
#pragma unroll
            for (int j = 0; j < 8; ++j)
                pv[j] = (ii[j] < cnt) ? pred[x[j] & 0x3FFFF] : 0.f;
#pragma unroll
            for (int j = 0; j < 8; ++j)
                if (ii[j] < cnt) atomicAdd(&agg[(x[j] >> 18) & 63], pv[j]);
        }
        __syncthreads();
        if (tid < 64) {
            float v = 0.f;
            int node = bkt * BNODES + tid;
            if (node < N) {
                float d = agg[tid] - 1.0f;
                v = d * d * sc[node];
            }
            v = wave_reduce(v);
            if (tid == 0) ocpart[bkt] = v;
        }
    } else if (blk < P3) {
        // ---------------- rowcol path ----------------
        int rc = blk - P2;
        float p = 0.f;
        if (rc < MNUM) {
            if (tid < MNUM) p = pred[rc * MNUM + tid];
        } else {
            int j = rc - MNUM;
            if (tid < MNUM) p = pred[tid * MNUM + j];
        }
        p = wave_reduce(p);
        if ((tid & 63) == 0) red[tid >> 6] = p;
        __syncthreads();
        if (tid == 0) {
            float s = red[0] + red[1] + red[2] + red[3];
            if (rc < MNUM) rs[rc] = s; else cs[rc - MNUM] = s;
        }
    } else {
        // ---------------- gsum dim-reduction ----------------
        int dim = blk - P3;  // 0..127
        float s = 0.f;
        for (int b = tid; b < nbuck; b += 256) s += gpart[(size_t)b * 128 + dim];
        s = wave_reduce(s);
        if ((tid & 63) == 0) red[tid >> 6] = s;
        __syncthreads();
        if (tid == 0) gsum[dim] = red[0] + red[1] + red[2] + red[3];
    }
}

// K7: per-row ce/l2 plain stores (223 blocks).
__global__ void losses_kernel(const float* __restrict__ pred, const float* __restrict__ gt,
                              const float* __restrict__ rs, const float* __restrict__ cs,
                              float* __restrict__ lce, float* __restrict__ ll2) {
    __shared__ float redc[4], redl[4];
    int blk = blockIdx.x, tid = threadIdx.x;
    float ce = 0.f, l2 = 0.f;
    if (tid < MNUM) {
        float p = pred[blk * MNUM + tid];
        ce = -gt[blk * MNUM + tid] * __log2f(p);
        l2 = p * (rs[blk] + cs[tid] - 2.0f * p);
    }
    ce = wave_reduce(ce);
    l2 = wave_reduce(l2);
    if ((tid & 63) == 0) { redc[tid >> 6] = ce; redl[tid >> 6] = l2; }
    __syncthreads();
    if (tid == 0) {
        lce[blk] = redc[0] + redc[1] + redc[2] + redc[3];
        ll2[blk] = redl[0] + redl[1] + redl[2] + redl[3];
    }
}

// K8: single-block tail: all six outputs via plain stores.
__global__ void tail_kernel(const float* __restrict__ rs, const float* __restrict__ cs,
                            const float* __restrict__ lce, const float* __restrict__ ll2,
                            const float* __restrict__ psum, int npsum,
                            const float* __restrict__ ocpart, int nbuck,
                            const float* __restrict__ gsum, const float* __restrict__ fc3_w,
                            const float* __restrict__ fc3_b, const float* __restrict__ fl3_b,
                            float* __restrict__ out, int N, int padrows) {
    __shared__ float red[4];
    int tid = threadIdx.x;
    // sumone
    float v = 0.f;
    if (tid < MNUM) {
        float a = rs[tid] - 1.0f, b = cs[tid] - 1.0f;
        v = a * a + b * b;
    }
    v = wave_reduce(v);
    if ((tid & 63) == 0) red[tid >> 6] = v;
    __syncthreads();
    if (tid == 0) out[1] = red[0] + red[1] + red[2] + red[3];
    __syncthreads();
    // ce
    float ce = (tid < MNUM) ? lce[tid] : 0.f;
    ce = wave_reduce(ce);
    if ((tid & 63) == 0) red[tid >> 6] = ce;
    __syncthreads();
    if (tid == 0) out[3] = red[0] + red[1] + red[2] + red[3];
    __syncthreads();
    // loss2
    float l2 = (tid < MNUM) ? ll2[tid] : 0.f;
    l2 = wave_reduce(l2);
    if ((tid & 63) == 0) red[tid >> 6] = l2;
    __syncthreads();
    if (tid == 0) out[2] = red[0] + red[1] + red[2] + red[3];
    __syncthreads();
    // prob3_sum
    float ps = 0.f;
    for (int i = tid; i < npsum; i += 256) ps += psum[i];
    float ss = 0.f;
    for (int p = tid; p < PNUM; p += 256) ss += fsig_fast(fl3_b[p]);
    float comb = ps - (float)padrows * ss;
    comb = wave_reduce(comb);
    if ((tid & 63) == 0) red[tid >> 6] = comb;
    __syncthreads();
    if (tid == 0) out[5] = red[0] + red[1] + red[2] + red[3];
    __syncthreads();
    // out_cost
    float oc = 0.f;
    for (int b = tid; b < nbuck; b += 256) oc += ocpart[b];
    oc = wave_reduce(oc);
    if ((tid & 63) == 0) red[tid >> 6] = oc;
    __syncthreads();
    if (tid == 0) out[4] = red[0] + red[1] + red[2] + red[3];
    __syncthreads();
    // pred_obj
    float pv = 0.f;
    if (tid < 128) pv = gsum[tid] * (1.0f / (float)N) * fc3_w[tid];
    pv = wave_reduce(pv);
    if ((tid & 63) == 0) red[tid >> 6] = pv;
    __syncthreads();
    if (tid == 0) out[0] = red[0] + red[1] + fc3_b[0];
}

extern "C" void kernel_launch(void* const* d_in, const int* in_sizes, int n_in,
                              void* d_out, int out_size, void* d_ws, size_t ws_size,
                              hipStream_t stream) {
    const float* ntc   = (const float*)d_in[0];
    const float* norm  = (const float*)d_in[1];
    const float* sc    = (const float*)d_in[2];
    const float* gt    = (const float*)d_in[3];
    const float* fc_w  = (const float*)d_in[4];
    const float* fc_b  = (const float*)d_in[5];
    const float* w_nt  = (const float*)d_in[6];
    const float* w_rel = (const float*)d_in[7];
    const float* fc2_w = (const float*)d_in[8];
    const float* fc2_b = (const float*)d_in[9];
    const float* fc3_w = (const float*)d_in[10];
    const float* fc3_b = (const float*)d_in[11];
    const float* fl3_w = (const float*)d_in[12];
    const float* fl3_b = (const float*)d_in[13];
    const int* node_type = (const int*)d_in[14];
    const int* src   = (const int*)d_in[15];
    const int* dst   = (const int*)d_in[16];
    const int* etype = (const int*)d_in[17];
    int N = in_sizes[2];
    int E = in_sizes[1];
    int nb128 = (N + 127) / 128;             // 391
    int padN  = nb128 * 128;                 // 50048
    int nbuck = padN / BNODES;               // 782
    int npsum = nb128 * 2;                   // 782

    // ---- workspace layout (float offsets) ----
    float* ws   = (float*)d_ws;
    float* C    = ws;                        // 0..6144
    unsigned short* wt = (unsigned short*)(ws + 6144);   // ..71680
    float* biasws = ws + 71680;              // ..72704
    float* gsum = ws + 72704;                // ..72832
    float* rs   = ws + 72832;                // ..73088
    float* cs   = ws + 73088;                // ..73344
    int*  cursor = (int*)(ws + 73344);       // ..74128 (784 ints)
    float* psum = ws + 74128;                // ..75152
    float* lce  = ws + 75152;                // ..75408
    float* ll2  = ws + 75408;                // ..75664
    float* ocpart = ws + 75664;              // ..76688
    unsigned short* CbT = (unsigned short*)(ws + 76688); // 128*64 shorts = ..80784
    float* gpart  = ws + 80784;              // ..180880 (782*128)
    float* pred = ws + 180880;               // ..+N
    unsigned short* hb = (unsigned short*)(pred + N);    // padN*128 bf16
    uint2* buck = (uint2*)(hb + (size_t)padN * H);       // nbuck*BCAP*8B
    float* out  = (float*)d_out;

    hipMemsetAsync(d_out, 0, 6 * sizeof(float), stream);
    hipMemsetAsync(cursor, 0, 784 * sizeof(int), stream);

    setup_kernel<<<1040, 128, 0, stream>>>(fl3_w, fl3_b, wt, biasws,
                                           fc_w, fc_b, w_nt, w_rel, C);
    cbt_kernel<<<128, 64, 0, stream>>>(C, CbT);
    partition_kernel<<<(E + EPB - 1) / EPB, 1024, 0, stream>>>(src, dst, etype, norm,
                                                               node_type, cursor, buck, E);
    bucket_node<<<nbuck, 256, 0, stream>>>(buck, cursor, ntc, CbT, fc2_w, fc2_b,
                                           hb, pred, gpart, N);
    int megablocks = 2 * nb128 + nbuck + 2 * MNUM + 128;
    mega_kernel<<<megablocks, 256, 0, stream>>>(hb, wt, biasws, psum, nb128,
                                                buck, cursor, pred, sc, ocpart, N,
                                                rs, cs, gpart, gsum, nbuck);
    losses_kernel<<<MNUM, 256, 0, stream>>>(pred, gt, rs, cs, lce, ll2);
    tail_kernel<<<1, 256, 0, stream>>>(rs, cs, lce, ll2, psum, npsum, ocpart, nbuck,
                                       gsum, fc3_w, fc3_b, fl3_b, out, N, padN - N);
}

// Round 15
// 231.837 us; speedup vs baseline: 1.4517x; 1.0290x over previous
//
#include <hip/hip_runtime.h>

#define H 128
#define RNUM 8
#define TNUM 2
#define PNUM 1000
#define MNUM 223
#define BNODES 64           // nodes per dst-bucket (power of 2)
#define NBUCK 782           // padN / 64
#define BCAP 2304           // per-bucket capacity (mean 2048, +5.7 sigma)
#define EPB 8192            // edges per partition block

typedef __attribute__((ext_vector_type(8))) short bf16x8;
typedef __attribute__((ext_vector_type(4))) float f32x4;

__device__ __forceinline__ float fsig(float z) {
    return 1.0f / (1.0f + __expf(-z));
}
__device__ __forceinline__ float fsig_fast(float z) {
    return __builtin_amdgcn_rcpf(1.0f + __expf(-z));
}

__device__ __forceinline__ float wave_reduce(float v) {
#pragma unroll
    for (int off = 32; off > 0; off >>= 1) v += __shfl_down(v, off, 64);
    return v;
}

__device__ __forceinline__ unsigned short f2bf(float f) {
    unsigned int u = __float_as_uint(f);
    u += 0x7fffu + ((u >> 16) & 1u);   // RNE
    return (unsigned short)(u >> 16);
}

// ---------------------------------------------------------------------------
// K1 (fused setup): blocks 0..1023 -> wt/bias transpose+pad; blocks
// 1024..1039 -> CbT bf16 precompute written DIRECTLY (no fp32 C array):
// block tr, thread i computes C[tr*3+c][i] and stores CbT[i*64 + tr*3+c].
// Block 1024 also zeroes CbT pad columns k=48..63.
// ---------------------------------------------------------------------------
__global__ void setup_kernel(const float* __restrict__ fl3_w, const float* __restrict__ fl3_b,
                             unsigned short* __restrict__ wt, float* __restrict__ biasws,
                             const float* __restrict__ fc_w, const float* __restrict__ fc_b,
                             const float* __restrict__ w_nt, const float* __restrict__ w_rel,
                             unsigned short* __restrict__ CbT) {
    __shared__ float G[3][H];
    int blk = blockIdx.x;
    int i = threadIdx.x;
    if (blk < 1024) {
        int p = blk;
        float v = (p < PNUM) ? fl3_w[(size_t)i * PNUM + p] : 0.0f;
        wt[(size_t)p * H + i] = f2bf(v);
        if (i == 0) biasws[p] = (p < PNUM) ? fl3_b[p] : -1.0e4f;
        return;
    }
    int tr = blk - 1024;            // t*8+r
    int t = tr >> 3, r = tr & 7;
    float a0 = 0.f, a1 = 0.f, a2 = 0.f;
#pragma unroll 8
    for (int j = 0; j < H; ++j) {
        float w = w_nt[((size_t)t * H + j) * H + i];
        a0 += fc_w[j] * w;
        a1 += fc_w[H + j] * w;
        a2 += fc_b[j] * w;
    }
    G[0][i] = a0; G[1][i] = a1; G[2][i] = a2;
    __syncthreads();
    float c0 = 0.f, c1 = 0.f, c2 = 0.f;
#pragma unroll 8
    for (int k = 0; k < H; ++k) {
        float w = w_rel[((size_t)r * H + k) * H + i];
        c0 += G[0][k] * w;
        c1 += G[1][k] * w;
        c2 += G[2][k] * w;
    }
    CbT[i * 64 + tr * 3 + 0] = f2bf(c0);
    CbT[i * 64 + tr * 3 + 1] = f2bf(c1);
    CbT[i * 64 + tr * 3 + 2] = f2bf(c2);
    if (tr == 0) {
        // zero pad columns k=48..63 (16 shorts = 2 uint4, 16B-aligned)
        uint4 z = make_uint4(0u, 0u, 0u, 0u);
        *(uint4*)(CbT + i * 64 + 48) = z;
        *(uint4*)(CbT + i * 64 + 56) = z;
    }
}

// ---------------------------------------------------------------------------
// K2: partition edges into 64-node dst buckets. Payload 8B:
//   .x = src | (local<<18) | (r<<24) | (t<<27); .y = bits(norm)
// ---------------------------------------------------------------------------
__global__ __launch_bounds__(1024) void partition_kernel(
        const int* __restrict__ src, const int* __restrict__ dst,
        const int* __restrict__ etype, const float* __restrict__ norm,
        const int* __restrict__ node_type, int* __restrict__ cursor,
        uint2* __restrict__ buck, int E) {
    __shared__ int lh[NBUCK];
    __shared__ int gb[NBUCK];
    int tid = threadIdx.x;
    for (int i = tid; i < NBUCK; i += 1024) lh[i] = 0;
    __syncthreads();
    int base = blockIdx.x * EPB;
    uint2 pl[8]; int bb[8]; int rk[8];
#pragma unroll
    for (int c = 0; c < 8; ++c) {
        int e = base + c * 1024 + tid;
        bb[c] = -1;
        if (e < E) {
            int s = src[e];
            int d = dst[e];
            int r = etype[e];
            float nm = norm[e];
            int t = node_type[s];
            int b = d >> 6;
            int local = d & 63;
            pl[c].x = (unsigned)s | ((unsigned)local << 18) | ((unsigned)r << 24) | ((unsigned)t << 27);
            pl[c].y = __float_as_uint(nm);
            bb[c] = b;
            rk[c] = atomicAdd(&lh[b], 1);
        }
    }
    __syncthreads();
    for (int i = tid; i < NBUCK; i += 1024) {
        if (lh[i] > 0) {
            int g = atomicAdd(&cursor[i], lh[i]);
            gb[i] = (g < 0) ? 0 : (g > BCAP ? BCAP : g);
        }
    }
    __syncthreads();
#pragma unroll
    for (int c = 0; c < 8; ++c) {
        if (bb[c] >= 0) {
            int pos = gb[bb[c]] + rk[c];
            if (pos < BCAP) buck[(size_t)bb[c] * BCAP + pos] = pl[c];
        }
    }
}

// ---------------------------------------------------------------------------
// K3: per-bucket replay (4-deep pipelined) -> S[64][68] fp32 LDS, then
// h = relu(S@C) via bf16 MFMA. Epilogue: hb bf16, pred, gsum partial.
// ---------------------------------------------------------------------------
__global__ __launch_bounds__(256) void bucket_node(
        const uint2* __restrict__ buck, const int* __restrict__ cursor,
        const float* __restrict__ ntc, const unsigned short* __restrict__ CbT,
        const float* __restrict__ fc2_w, const float* __restrict__ fc2_b,
        unsigned short* __restrict__ hb, float* __restrict__ pred,
        float* __restrict__ gpart, int N) {
    __shared__ float S[64 * 68];            // rows padded to 68 (bank spread)
    __shared__ unsigned short Cb[128 * 72]; // CbT rows padded to 72 shorts
    __shared__ float gloc[128];
    int tid = threadIdx.x;
    int bkt = blockIdx.x;
    for (int i = tid; i < 64 * 68; i += 256) S[i] = 0.0f;
    for (int g = tid; g < 1024; g += 256) {   // stage CbT: 1024 uint4
        int row = g >> 3, c = g & 7;
        uint4 v = ((const uint4*)CbT)[g];
        *(uint4*)(Cb + row * 72 + c * 8) = v;
    }
    if (tid < 128) gloc[tid] = 0.0f;
    __syncthreads();

    int cnt = cursor[bkt];
    if (cnt > BCAP) cnt = BCAP;
    if (cnt < 0) cnt = 0;
    const uint2* bp = buck + (size_t)bkt * BCAP;
    for (int base = 0; base < cnt; base += 1024) {
        uint2 pl[4]; float2 cc[4]; int ii[4];
#pragma unroll
        for (int j = 0; j < 4; ++j) {
            ii[j] = base + j * 256 + tid;
            pl[j] = (ii[j] < cnt) ? bp[ii[j]] : make_uint2(0u, 0u);
        }
#pragma unroll
        for (int j = 0; j < 4; ++j)
            cc[j] = (ii[j] < cnt) ? ((const float2*)ntc)[pl[j].x & 0x3FFFF]
                                  : make_float2(0.f, 0.f);
#pragma unroll
        for (int j = 0; j < 4; ++j) {
            if (ii[j] < cnt) {
                int local = (pl[j].x >> 18) & 63;
                int tr = ((pl[j].x >> 24) & 7) + (((pl[j].x >> 27) & 1) << 3);
                float nm = __uint_as_float(pl[j].y);
                float* p = &S[local * 68 + tr * 3];
                atomicAdd(p, nm * cc[j].x);
                atomicAdd(p + 1, nm * cc[j].y);
                atomicAdd(p + 2, nm);
            }
        }
    }
    __syncthreads();

    int lane = tid & 63, w = tid >> 6;
    int lrow = lane & 15, quad = lane >> 4;

    // A-frags: rows w*16+lrow of S (fp32 -> bf16)
    bf16x8 a[2];
#pragma unroll
    for (int ks = 0; ks < 2; ++ks) {
        const float* sp = S + (w * 16 + lrow) * 68 + ks * 32 + quad * 8;
        float4 f0 = *(const float4*)sp;
        float4 f1 = *(const float4*)(sp + 4);
        bf16x8 t;
        t[0] = (short)f2bf(f0.x); t[1] = (short)f2bf(f0.y);
        t[2] = (short)f2bf(f0.z); t[3] = (short)f2bf(f0.w);
        t[4] = (short)f2bf(f1.x); t[5] = (short)f2bf(f1.y);
        t[6] = (short)f2bf(f1.z); t[7] = (short)f2bf(f1.w);
        a[ks] = t;
    }

    f32x4 acc[8];
#pragma unroll
    for (int tn = 0; tn < 8; ++tn) acc[tn] = (f32x4){0.f, 0.f, 0.f, 0.f};
#pragma unroll
    for (int ks = 0; ks < 2; ++ks) {
#pragma unroll
        for (int tn = 0; tn < 8; ++tn) {
            bf16x8 b = *(const bf16x8*)(Cb + (tn * 16 + lrow) * 72 + ks * 32 + quad * 8);
            acc[tn] = __builtin_amdgcn_mfma_f32_16x16x32_bf16(a[ks], b, acc[tn], 0, 0, 0);
        }
    }

    // relu
#pragma unroll
    for (int tn = 0; tn < 8; ++tn)
#pragma unroll
        for (int r = 0; r < 4; ++r) acc[tn][r] = fmaxf(acc[tn][r], 0.f);

    int vbase = bkt * BNODES + w * 16 + quad * 4;
#pragma unroll
    for (int r = 0; r < 4; ++r) {
        unsigned short* hrow = hb + (size_t)(vbase + r) * H + lrow;
#pragma unroll
        for (int tn = 0; tn < 8; ++tn) hrow[tn * 16] = f2bf(acc[tn][r]);
    }
    // pred: dot over 128 cols = reduce over 16 lanes of the quad
    float pd[4];
#pragma unroll
    for (int r = 0; r < 4; ++r) {
        float s = 0.f;
#pragma unroll
        for (int tn = 0; tn < 8; ++tn) s += acc[tn][r] * fc2_w[tn * 16 + lrow];
        pd[r] = s;
    }
#pragma unroll
    for (int mask = 1; mask < 16; mask <<= 1)
#pragma unroll
        for (int r = 0; r < 4; ++r) pd[r] += __shfl_xor(pd[r], mask, 64);
    if (lrow == 0) {
#pragma unroll
        for (int r = 0; r < 4; ++r) {
            int v = vbase + r;
            if (v < N) {
                float z = pd[r] + fc2_b[0];
                pred[v] = fminf(fmaxf(fsig(z), 1e-7f), 1e10f);
            }
        }
    }
    // gsum partial: column sums over this wave's 16 rows
    float csum[8];
#pragma unroll
    for (int tn = 0; tn < 8; ++tn)
        csum[tn] = acc[tn][0] + acc[tn][1] + acc[tn][2] + acc[tn][3];
#pragma unroll
    for (int mask = 16; mask < 64; mask <<= 1)
#pragma unroll
        for (int tn = 0; tn < 8; ++tn) csum[tn] += __shfl_xor(csum[tn], mask, 64);
    if (lane < 16) {
#pragma unroll
        for (int tn = 0; tn < 8; ++tn) atomicAdd(&gloc[tn * 16 + lrow], csum[tn]);
    }
    __syncthreads();
    if (tid < 128) gpart[(size_t)bkt * 128 + tid] = gloc[tid];
}

// ---------------------------------------------------------------------------
// K4 (MEGA): all post-bucket_node independent work in ONE launch.
// blocks [0, 2*nb128): prob3 MFMA tile (y = blk/nb128)
// blocks [P1, P1+nbuck): agg_outcost (8-deep pipelined)
// blocks [P2, P2+MNUM): row pass -> rs + cepart + sqpart
// blocks [P2+MNUM, P2+2*MNUM): col pass -> cs
// blocks last 128: gsum dim-reduction from gpart
// ---------------------------------------------------------------------------
__global__ __launch_bounds__(256, 2) void mega_kernel(
        const unsigned short* __restrict__ hb, const unsigned short* __restrict__ wt,
        const float* __restrict__ biasws, float* __restrict__ psum, int nb128,
        const uint2* __restrict__ buck, const int* __restrict__ cursor,
        const float* __restrict__ pred, const float* __restrict__ sc,
        const float* __restrict__ gt, float* __restrict__ ocpart, int N,
        float* __restrict__ rs, float* __restrict__ cs,
        float* __restrict__ cepart, float* __restrict__ sqpart,
        const float* __restrict__ gpart, float* __restrict__ gsum, int nbuck) {
    __shared__ unsigned short Bsh[128 * 136];
    __shared__ float red[12];
    int blk = blockIdx.x;
    int tid = threadIdx.x;
    int P1 = 2 * nb128;
    int P2 = P1 + nbuck;
    int P3 = P2 + 2 * MNUM;

    if (blk < P1) {
        // ---------------- prob3 path ----------------
        int by = blk / nb128, bx = blk - by * nb128;
        int n0 = bx * 128;
        int pt0 = by * 4;
        int lane = tid & 63, wid = tid >> 6;
        int wy = wid >> 1, wx = wid & 1;
        int lrow = lane & 15, quad = lane >> 4;

        bf16x8 a[4][4];
#pragma unroll
        for (int tm = 0; tm < 4; ++tm) {
            const unsigned short* arow = hb + (size_t)(n0 + wy * 64 + tm * 16 + lrow) * H + quad * 8;
#pragma unroll
            for (int ks = 0; ks < 4; ++ks)
                a[tm][ks] = *(const bf16x8*)(arow + ks * 32);
        }

        float lsum = 0.f;
        for (int pi = 0; pi < 4; ++pi) {
            int pt = pt0 + pi;
            __syncthreads();
            {
                int c = tid & 15;
                int r0 = tid >> 4;
#pragma unroll
                for (int it = 0; it < 8; ++it) {
                    int row = r0 + it * 16;
                    uint4 bv = *(const uint4*)(wt + (size_t)(pt * 128 + row) * H + c * 8);
                    *(uint4*)(Bsh + row * 136 + c * 8) = bv;
                }
            }
            __syncthreads();

            f32x4 acc[4][4];
#pragma unroll
            for (int tm = 0; tm < 4; ++tm)
#pragma unroll
                for (int tn = 0; tn < 4; ++tn)
                    acc[tm][tn] = (f32x4){0.f, 0.f, 0.f, 0.f};

            const unsigned short* Bbase = Bsh + (wx * 64 + lrow) * 136 + quad * 8;
#pragma unroll
            for (int ks = 0; ks < 4; ++ks) {
                bf16x8 b[4];
#pragma unroll
                for (int tn = 0; tn < 4; ++tn)
                    b[tn] = *(const bf16x8*)(Bbase + tn * 16 * 136 + ks * 32);
#pragma unroll
                for (int tm = 0; tm < 4; ++tm)
#pragma unroll
                    for (int tn = 0; tn < 4; ++tn)
                        acc[tm][tn] = __builtin_amdgcn_mfma_f32_16x16x32_bf16(a[tm][ks], b[tn], acc[tm][tn], 0, 0, 0);
            }

#pragma unroll
            for (int tn = 0; tn < 4; ++tn) {
                float bv = biasws[pt * 128 + wx * 64 + tn * 16 + lrow];
#pragma unroll
                for (int tm = 0; tm < 4; ++tm) {
#pragma unroll
                    for (int r = 0; r < 4; ++r)
                        lsum += fsig_fast(acc[tm][tn][r] + bv);
                }
            }
        }
        lsum = wave_reduce(lsum);
        if (lane == 0) red[wid] = lsum;
        __syncthreads();
        if (tid == 0)
            psum[by * nb128 + bx] = red[0] + red[1] + red[2] + red[3];
    } else if (blk < P2) {
        // ---------------- agg_outcost path ----------------
        int bkt = blk - P1;
        float* agg = (float*)Bsh;   // 64 floats carved from Bsh
        if (tid < BNODES) agg[tid] = 0.0f;
        __syncthreads();
        int cnt = cursor[bkt];
        if (cnt > BCAP) cnt = BCAP;
        if (cnt < 0) cnt = 0;
        const uint2* bp = buck + (size_t)bkt * BCAP;
        for (int base = 0; base < cnt; base += 2048) {
            unsigned x[8]; float pv[8]; int ii[8];
#pragma unroll
            for (int j = 0; j < 8; ++j) {
                ii[j] = base + j * 256 + tid;
                x[j] = (ii[j] < cnt) ? bp[ii[j]].x : 0u;
            }
#pragma unroll
            for (int j = 0; j < 8; ++j)
                pv[j] = (ii[j] < cnt) ? pred[x[j] & 0x3FFFF] : 0.f;
#pragma unroll
            for (int j = 0; j < 8; ++j)
                if (ii[j] < cnt) atomicAdd(&agg[(x[j] >> 18) & 63], pv[j]);
        }
        __syncthreads();
        if (tid < 64) {
            float v = 0.f;
            int node = bkt * BNODES + tid;
            if (node < N) {
                float d = agg[tid] - 1.0f;
                v = d * d * sc[node];
            }
            v = wave_reduce(v);
            if (tid == 0) ocpart[bkt] = v;
        }
    } else if (blk < P3) {
        // ---------------- rowcol path (+ce/sq on rows) ----------------
        int rc = blk - P2;
        if (rc < MNUM) {
            float p = 0.f, ce = 0.f, sq = 0.f;
            if (tid < MNUM) {
                p = pred[rc * MNUM + tid];
                ce = -gt[rc * MNUM + tid] * __log2f(p);
                sq = p * p;
            }
            p = wave_reduce(p);
            ce = wave_reduce(ce);
            sq = wave_reduce(sq);
            int wid = tid >> 6;
            if ((tid & 63) == 0) { red[wid] = p; red[4 + wid] = ce; red[8 + wid] = sq; }
            __syncthreads();
            if (tid == 0) {
                rs[rc] = red[0] + red[1] + red[2] + red[3];
                cepart[rc] = red[4] + red[5] + red[6] + red[7];
                sqpart[rc] = red[8] + red[9] + red[10] + red[11];
            }
        } else {
            int j = rc - MNUM;
            float p = 0.f;
            if (tid < MNUM) p = pred[tid * MNUM + j];
            p = wave_reduce(p);
            if ((tid & 63) == 0) red[tid >> 6] = p;
            __syncthreads();
            if (tid == 0) cs[j] = red[0] + red[1] + red[2] + red[3];
        }
    } else {
        // ---------------- gsum dim-reduction ----------------
        int dim = blk - P3;  // 0..127
        float s = 0.f;
        for (int b = tid; b < nbuck; b += 256) s += gpart[(size_t)b * 128 + dim];
        s = wave_reduce(s);
        if ((tid & 63) == 0) red[tid >> 6] = s;
        __syncthreads();
        if (tid == 0) gsum[dim] = red[0] + red[1] + red[2] + red[3];
    }
}

// K8: single-block tail: all six outputs via plain stores.
// loss2 = sum_i rs_i^2 + sum_j cs_j^2 - 2*sum p^2 (exact identity).
__global__ void tail_kernel(const float* __restrict__ rs, const float* __restrict__ cs,
                            const float* __restrict__ cepart, const float* __restrict__ sqpart,
                            const float* __restrict__ psum, int npsum,
                            const float* __restrict__ ocpart, int nbuck,
                            const float* __restrict__ gsum, const float* __restrict__ fc3_w,
                            const float* __restrict__ fc3_b, const float* __restrict__ fl3_b,
                            float* __restrict__ out, int N, int padrows) {
    __shared__ float red[4];
    int tid = threadIdx.x;
    // sumone
    float v = 0.f;
    if (tid < MNUM) {
        float a = rs[tid] - 1.0f, b = cs[tid] - 1.0f;
        v = a * a + b * b;
    }
    v = wave_reduce(v);
    if ((tid & 63) == 0) red[tid >> 6] = v;
    __syncthreads();
    if (tid == 0) out[1] = red[0] + red[1] + red[2] + red[3];
    __syncthreads();
    // ce
    float ce = (tid < MNUM) ? cepart[tid] : 0.f;
    ce = wave_reduce(ce);
    if ((tid & 63) == 0) red[tid >> 6] = ce;
    __syncthreads();
    if (tid == 0) out[3] = red[0] + red[1] + red[2] + red[3];
    __syncthreads();
    // loss2 = sum rs^2 + sum cs^2 - 2 sum p^2
    float l2 = 0.f;
    if (tid < MNUM)
        l2 = rs[tid] * rs[tid] + cs[tid] * cs[tid] - 2.0f * sqpart[tid];
    l2 = wave_reduce(l2);
    if ((tid & 63) == 0) red[tid >> 6] = l2;
    __syncthreads();
    if (tid == 0) out[2] = red[0] + red[1] + red[2] + red[3];
    __syncthreads();
    // prob3_sum
    float ps = 0.f;
    for (int i = tid; i < npsum; i += 256) ps += psum[i];
    float ss = 0.f;
    for (int p = tid; p < PNUM; p += 256) ss += fsig_fast(fl3_b[p]);
    float comb = ps - (float)padrows * ss;
    comb = wave_reduce(comb);
    if ((tid & 63) == 0) red[tid >> 6] = comb;
    __syncthreads();
    if (tid == 0) out[5] = red[0] + red[1] + red[2] + red[3];
    __syncthreads();
    // out_cost
    float oc = 0.f;
    for (int b = tid; b < nbuck; b += 256) oc += ocpart[b];
    oc = wave_reduce(oc);
    if ((tid & 63) == 0) red[tid >> 6] = oc;
    __syncthreads();
    if (tid == 0) out[4] = red[0] + red[1] + red[2] + red[3];
    __syncthreads();
    // pred_obj
    float pv = 0.f;
    if (tid < 128) pv = gsum[tid] * (1.0f / (float)N) * fc3_w[tid];
    pv = wave_reduce(pv);
    if ((tid & 63) == 0) red[tid >> 6] = pv;
    __syncthreads();
    if (tid == 0) out[0] = red[0] + red[1] + fc3_b[0];
}

extern "C" void kernel_launch(void* const* d_in, const int* in_sizes, int n_in,
                              void* d_out, int out_size, void* d_ws, size_t ws_size,
                              hipStream_t stream) {
    const float* ntc   = (const float*)d_in[0];
    const float* norm  = (const float*)d_in[1];
    const float* sc    = (const float*)d_in[2];
    const float* gt    = (const float*)d_in[3];
    const float* fc_w  = (const float*)d_in[4];
    const float* fc_b  = (const float*)d_in[5];
    const float* w_nt  = (const float*)d_in[6];
    const float* w_rel = (const float*)d_in[7];
    const float* fc2_w = (const float*)d_in[8];
    const float* fc2_b = (const float*)d_in[9];
    const float* fc3_w = (const float*)d_in[10];
    const float* fc3_b = (const float*)d_in[11];
    const float* fl3_w = (const float*)d_in[12];
    const float* fl3_b = (const float*)d_in[13];
    const int* node_type = (const int*)d_in[14];
    const int* src   = (const int*)d_in[15];
    const int* dst   = (const int*)d_in[16];
    const int* etype = (const int*)d_in[17];
    int N = in_sizes[2];
    int E = in_sizes[1];
    int nb128 = (N + 127) / 128;             // 391
    int padN  = nb128 * 128;                 // 50048
    int nbuck = padN / BNODES;               // 782
    int npsum = nb128 * 2;                   // 782

    // ---- workspace layout (float offsets) ----
    float* ws   = (float*)d_ws;
    unsigned short* wt = (unsigned short*)ws;            // 0..65536 (131072 shorts)
    float* biasws = ws + 65536;              // ..66560
    float* gsum = ws + 66560;                // ..66688
    float* rs   = ws + 66688;                // ..66944
    float* cs   = ws + 66944;                // ..67200
    int*  cursor = (int*)(ws + 67200);       // ..67984 (784 ints)
    float* psum = ws + 67984;                // ..69008
    float* cepart = ws + 69008;              // ..69264
    float* sqpart = ws + 69264;              // ..69520
    float* ocpart = ws + 69520;              // ..70544
    unsigned short* CbT = (unsigned short*)(ws + 70544); // 8192 shorts -> ..74640
    float* gpart  = ws + 74640;              // ..174736 (782*128)
    float* pred = ws + 174736;               // ..+N
    unsigned short* hb = (unsigned short*)(pred + N);    // padN*128 bf16
    uint2* buck = (uint2*)(hb + (size_t)padN * H);       // nbuck*BCAP*8B
    float* out  = (float*)d_out;

    hipMemsetAsync(d_out, 0, 6 * sizeof(float), stream);
    hipMemsetAsync(cursor, 0, 784 * sizeof(int), stream);

    setup_kernel<<<1040, 128, 0, stream>>>(fl3_w, fl3_b, wt, biasws,
                                           fc_w, fc_b, w_nt, w_rel, CbT);
    partition_kernel<<<(E + EPB - 1) / EPB, 1024, 0, stream>>>(src, dst, etype, norm,
                                                               node_type, cursor, buck, E);
    bucket_node<<<nbuck, 256, 0, stream>>>(buck, cursor, ntc, CbT, fc2_w, fc2_b,
                                           hb, pred, gpart, N);
    int megablocks = 2 * nb128 + nbuck + 2 * MNUM + 128;
    mega_kernel<<<megablocks, 256, 0, stream>>>(hb, wt, biasws, psum, nb128,
                                                buck, cursor, pred, sc, gt, ocpart, N,
                                                rs, cs, cepart, sqpart, gpart, gsum, nbuck);
    tail_kernel<<<1, 256, 0, stream>>>(rs, cs, cepart, sqpart, psum, npsum, ocpart, nbuck,
                                       gsum, fc3_w, fc3_b, fl3_b, out, N, padN - N);
}

// Round 16
// 212.027 us; speedup vs baseline: 1.5874x; 1.0934x over previous
//
#include <hip/hip_runtime.h>

#define H 128
#define RNUM 8
#define TNUM 2
#define PNUM 1000
#define MNUM 223
#define BNODES 64           // nodes per dst-bucket (power of 2)
#define NBUCK 782           // padN / 64
#define BCAP 2304           // per-bucket capacity (mean 2048, +5.7 sigma)
#define EPB 8192            // edges per partition block

typedef __attribute__((ext_vector_type(8))) short bf16x8;
typedef __attribute__((ext_vector_type(4))) float f32x4;

__device__ __forceinline__ float fsig(float z) {
    return 1.0f / (1.0f + __expf(-z));
}
__device__ __forceinline__ float fsig_fast(float z) {
    return __builtin_amdgcn_rcpf(1.0f + __expf(-z));
}

__device__ __forceinline__ float wave_reduce(float v) {
#pragma unroll
    for (int off = 32; off > 0; off >>= 1) v += __shfl_down(v, off, 64);
    return v;
}

__device__ __forceinline__ unsigned short f2bf(float f) {
    unsigned int u = __float_as_uint(f);
    u += 0x7fffu + ((u >> 16) & 1u);   // RNE
    return (unsigned short)(u >> 16);
}

// ---------------------------------------------------------------------------
// K1 (partition + setup fused, 1024 threads):
//  blocks [0, NP):        edge partition into 64-node dst buckets
//  blocks [NP, NP+128):   wt/bias transpose+pad (8 p's per block)
//  blocks [NP+128, +2):   CbT bf16 precompute (8 tr per block)
// Payload 8B: .x = src | (local<<18) | (r<<24) | (t<<27); .y = bits(norm)
// ---------------------------------------------------------------------------
__global__ __launch_bounds__(1024) void partition_setup(
        const int* __restrict__ src, const int* __restrict__ dst,
        const int* __restrict__ etype, const float* __restrict__ norm,
        const int* __restrict__ node_type, int* __restrict__ cursor,
        uint2* __restrict__ buck, int E, int NP,
        const float* __restrict__ fl3_w, const float* __restrict__ fl3_b,
        unsigned short* __restrict__ wt, float* __restrict__ biasws,
        const float* __restrict__ fc_w, const float* __restrict__ fc_b,
        const float* __restrict__ w_nt, const float* __restrict__ w_rel,
        unsigned short* __restrict__ CbT) {
    int blk = blockIdx.x;
    int tid = threadIdx.x;
    if (blk < NP) {
        // ------------- partition path -------------
        __shared__ int lh[NBUCK];
        __shared__ int gb[NBUCK];
        for (int i = tid; i < NBUCK; i += 1024) lh[i] = 0;
        __syncthreads();
        int base = blk * EPB;
        uint2 pl[8]; int bb[8]; int rk[8];
#pragma unroll
        for (int c = 0; c < 8; ++c) {
            int e = base + c * 1024 + tid;
            bb[c] = -1;
            if (e < E) {
                int s = src[e];
                int d = dst[e];
                int r = etype[e];
                float nm = norm[e];
                int t = node_type[s];
                int b = d >> 6;
                int local = d & 63;
                pl[c].x = (unsigned)s | ((unsigned)local << 18) | ((unsigned)r << 24) | ((unsigned)t << 27);
                pl[c].y = __float_as_uint(nm);
                bb[c] = b;
                rk[c] = atomicAdd(&lh[b], 1);
            }
        }
        __syncthreads();
        for (int i = tid; i < NBUCK; i += 1024) {
            if (lh[i] > 0) {
                int g = atomicAdd(&cursor[i], lh[i]);
                gb[i] = (g < 0) ? 0 : (g > BCAP ? BCAP : g);
            }
        }
        __syncthreads();
#pragma unroll
        for (int c = 0; c < 8; ++c) {
            if (bb[c] >= 0) {
                int pos = gb[bb[c]] + rk[c];
                if (pos < BCAP) buck[(size_t)bb[c] * BCAP + pos] = pl[c];
            }
        }
    } else if (blk < NP + 128) {
        // ------------- wt transpose path (8 p's per block) -------------
        int p = (blk - NP) * 8 + (tid >> 7);   // 0..1023
        int k = tid & 127;
        float v = (p < PNUM) ? fl3_w[(size_t)k * PNUM + p] : 0.0f;
        wt[(size_t)p * H + k] = f2bf(v);
        if (k == 0) biasws[p] = (p < PNUM) ? fl3_b[p] : -1.0e4f;
    } else {
        // ------------- CbT path (8 tr per block) -------------
        __shared__ float G[8][3][H];
        int g = tid >> 7;                       // group 0..7
        int tr = (blk - NP - 128) * 8 + g;      // 0..15
        int t = tr >> 3, r = tr & 7;
        int i = tid & 127;
        float a0 = 0.f, a1 = 0.f, a2 = 0.f;
#pragma unroll 8
        for (int j = 0; j < H; ++j) {
            float w = w_nt[((size_t)t * H + j) * H + i];
            a0 += fc_w[j] * w;
            a1 += fc_w[H + j] * w;
            a2 += fc_b[j] * w;
        }
        G[g][0][i] = a0; G[g][1][i] = a1; G[g][2][i] = a2;
        __syncthreads();
        float c0 = 0.f, c1 = 0.f, c2 = 0.f;
#pragma unroll 8
        for (int k = 0; k < H; ++k) {
            float w = w_rel[((size_t)r * H + k) * H + i];
            c0 += G[g][0][k] * w;
            c1 += G[g][1][k] * w;
            c2 += G[g][2][k] * w;
        }
        CbT[i * 64 + tr * 3 + 0] = f2bf(c0);
        CbT[i * 64 + tr * 3 + 1] = f2bf(c1);
        CbT[i * 64 + tr * 3 + 2] = f2bf(c2);
        if (tr == 0) {
            uint4 z = make_uint4(0u, 0u, 0u, 0u);
            *(uint4*)(CbT + i * 64 + 48) = z;
            *(uint4*)(CbT + i * 64 + 56) = z;
        }
    }
}

// ---------------------------------------------------------------------------
// K3: per-bucket replay with PACKED LDS atomics (2 per edge instead of 3):
// (nm*c0, nm*c1) as 2^12 fixed-point halves of one u64 atomic (non-negative,
// worst-bucket sum 2304*5.5*4096 = 5.2e7 < 2^31 -> no cross-carry), nm as
// exact f32. P/F alias the S buffer; register-staged unpack rebuilds
// S[64][68] (pad cols zeroed) before the verified bf16-MFMA node phase.
// ---------------------------------------------------------------------------
__global__ __launch_bounds__(256) void bucket_node(
        const uint2* __restrict__ buck, const int* __restrict__ cursor,
        const float* __restrict__ ntc, const unsigned short* __restrict__ CbT,
        const float* __restrict__ fc2_w, const float* __restrict__ fc2_b,
        unsigned short* __restrict__ hb, float* __restrict__ pred,
        float* __restrict__ gpart, int N) {
    __shared__ float S[64 * 68];            // union: replay P/F, then S
    __shared__ unsigned short Cb[128 * 72]; // CbT rows padded to 72 shorts
    __shared__ float gloc[128];
    unsigned long long* P = (unsigned long long*)S;   // 64*16 u64 = first 2048 floats
    float* F = S + 2048;                              // 64*17 f32 (padded rows)
    int tid = threadIdx.x;
    int bkt = blockIdx.x;
    for (int i = tid; i < 3136; i += 256) S[i] = 0.0f;   // zero P+F region
    for (int g = tid; g < 1024; g += 256) {   // stage CbT: 1024 uint4
        int row = g >> 3, c = g & 7;
        uint4 v = ((const uint4*)CbT)[g];
        *(uint4*)(Cb + row * 72 + c * 8) = v;
    }
    if (tid < 128) gloc[tid] = 0.0f;
    __syncthreads();

    int cnt = cursor[bkt];
    if (cnt > BCAP) cnt = BCAP;
    if (cnt < 0) cnt = 0;
    const uint2* bp = buck + (size_t)bkt * BCAP;
    const float fxs = 4096.0f;
    for (int base = 0; base < cnt; base += 1024) {
        uint2 pl[4]; float2 cc[4]; int ii[4];
#pragma unroll
        for (int j = 0; j < 4; ++j) {
            ii[j] = base + j * 256 + tid;
            pl[j] = (ii[j] < cnt) ? bp[ii[j]] : make_uint2(0u, 0u);
        }
#pragma unroll
        for (int j = 0; j < 4; ++j)
            cc[j] = (ii[j] < cnt) ? ((const float2*)ntc)[pl[j].x & 0x3FFFF]
                                  : make_float2(0.f, 0.f);
#pragma unroll
        for (int j = 0; j < 4; ++j) {
            if (ii[j] < cnt) {
                int local = (pl[j].x >> 18) & 63;
                int tr = ((pl[j].x >> 24) & 7) + (((pl[j].x >> 27) & 1) << 3);
                float nm = __uint_as_float(pl[j].y);
                unsigned lo = __float2uint_rn(nm * cc[j].x * fxs);
                unsigned hi = __float2uint_rn(nm * cc[j].y * fxs);
                unsigned long long pk = ((unsigned long long)hi << 32) | lo;
                atomicAdd(&P[local * 16 + tr], pk);
                atomicAdd(&F[local * 17 + tr], nm);
            }
        }
    }
    __syncthreads();

    // unpack P/F -> registers (1024 pairs, 4 per thread), then rebuild S
    unsigned long long rpk[4]; float rf[4];
#pragma unroll
    for (int u = 0; u < 4; ++u) {
        int idx = tid * 4 + u;                 // = local*16 + tr
        rpk[u] = P[idx];
        rf[u] = F[(idx >> 4) * 17 + (idx & 15)];
    }
    __syncthreads();
    const float inv = 1.0f / 4096.0f;
#pragma unroll
    for (int u = 0; u < 4; ++u) {
        int idx = tid * 4 + u;
        int local = idx >> 4, tr = idx & 15;
        float* p = S + local * 68 + tr * 3;
        p[0] = (float)(unsigned)(rpk[u] & 0xFFFFFFFFull) * inv;
        p[1] = (float)(unsigned)(rpk[u] >> 32) * inv;
        p[2] = rf[u];
    }
    for (int idx = tid; idx < 1024; idx += 256) {   // zero pad cols 48..63
        int row = idx >> 4, c = idx & 15;
        S[row * 68 + 48 + c] = 0.0f;
    }
    __syncthreads();

    int lane = tid & 63, w = tid >> 6;
    int lrow = lane & 15, quad = lane >> 4;

    // A-frags: rows w*16+lrow of S (fp32 -> bf16)
    bf16x8 a[2];
#pragma unroll
    for (int ks = 0; ks < 2; ++ks) {
        const float* sp = S + (w * 16 + lrow) * 68 + ks * 32 + quad * 8;
        float4 f0 = *(const float4*)sp;
        float4 f1 = *(const float4*)(sp + 4);
        bf16x8 t;
        t[0] = (short)f2bf(f0.x); t[1] = (short)f2bf(f0.y);
        t[2] = (short)f2bf(f0.z); t[3] = (short)f2bf(f0.w);
        t[4] = (short)f2bf(f1.x); t[5] = (short)f2bf(f1.y);
        t[6] = (short)f2bf(f1.z); t[7] = (short)f2bf(f1.w);
        a[ks] = t;
    }

    f32x4 acc[8];
#pragma unroll
    for (int tn = 0; tn < 8; ++tn) acc[tn] = (f32x4){0.f, 0.f, 0.f, 0.f};
#pragma unroll
    for (int ks = 0; ks < 2; ++ks) {
#pragma unroll
        for (int tn = 0; tn < 8; ++tn) {
            bf16x8 b = *(const bf16x8*)(Cb + (tn * 16 + lrow) * 72 + ks * 32 + quad * 8);
            acc[tn] = __builtin_amdgcn_mfma_f32_16x16x32_bf16(a[ks], b, acc[tn], 0, 0, 0);
        }
    }

    // relu
#pragma unroll
    for (int tn = 0; tn < 8; ++tn)
#pragma unroll
        for (int r = 0; r < 4; ++r) acc[tn][r] = fmaxf(acc[tn][r], 0.f);

    int vbase = bkt * BNODES + w * 16 + quad * 4;
#pragma unroll
    for (int r = 0; r < 4; ++r) {
        unsigned short* hrow = hb + (size_t)(vbase + r) * H + lrow;
#pragma unroll
        for (int tn = 0; tn < 8; ++tn) hrow[tn * 16] = f2bf(acc[tn][r]);
    }
    // pred: dot over 128 cols = reduce over 16 lanes of the quad
    float pd[4];
#pragma unroll
    for (int r = 0; r < 4; ++r) {
        float s = 0.f;
#pragma unroll
        for (int tn = 0; tn < 8; ++tn) s += acc[tn][r] * fc2_w[tn * 16 + lrow];
        pd[r] = s;
    }
#pragma unroll
    for (int mask = 1; mask < 16; mask <<= 1)
#pragma unroll
        for (int r = 0; r < 4; ++r) pd[r] += __shfl_xor(pd[r], mask, 64);
    if (lrow == 0) {
#pragma unroll
        for (int r = 0; r < 4; ++r) {
            int v = vbase + r;
            if (v < N) {
                float z = pd[r] + fc2_b[0];
                pred[v] = fminf(fmaxf(fsig(z), 1e-7f), 1e10f);
            }
        }
    }
    // gsum partial: column sums over this wave's 16 rows
    float csum[8];
#pragma unroll
    for (int tn = 0; tn < 8; ++tn)
        csum[tn] = acc[tn][0] + acc[tn][1] + acc[tn][2] + acc[tn][3];
#pragma unroll
    for (int mask = 16; mask < 64; mask <<= 1)
#pragma unroll
        for (int tn = 0; tn < 8; ++tn) csum[tn] += __shfl_xor(csum[tn], mask, 64);
    if (lane < 16) {
#pragma unroll
        for (int tn = 0; tn < 8; ++tn) atomicAdd(&gloc[tn * 16 + lrow], csum[tn]);
    }
    __syncthreads();
    if (tid < 128) gpart[(size_t)bkt * 128 + tid] = gloc[tid];
}

// ---------------------------------------------------------------------------
// K4 (MEGA): all post-bucket_node independent work in ONE launch.
// ---------------------------------------------------------------------------
__global__ __launch_bounds__(256, 2) void mega_kernel(
        const unsigned short* __restrict__ hb, const unsigned short* __restrict__ wt,
        const float* __restrict__ biasws, float* __restrict__ psum, int nb128,
        const uint2* __restrict__ buck, const int* __restrict__ cursor,
        const float* __restrict__ pred, const float* __restrict__ sc,
        const float* __restrict__ gt, float* __restrict__ ocpart, int N,
        float* __restrict__ rs, float* __restrict__ cs,
        float* __restrict__ cepart, float* __restrict__ sqpart,
        const float* __restrict__ gpart, float* __restrict__ gsum, int nbuck) {
    __shared__ unsigned short Bsh[128 * 136];
    __shared__ float red[12];
    int blk = blockIdx.x;
    int tid = threadIdx.x;
    int P1 = 2 * nb128;
    int P2 = P1 + nbuck;
    int P3 = P2 + 2 * MNUM;

    if (blk < P1) {
        // ---------------- prob3 path ----------------
        int by = blk / nb128, bx = blk - by * nb128;
        int n0 = bx * 128;
        int pt0 = by * 4;
        int lane = tid & 63, wid = tid >> 6;
        int wy = wid >> 1, wx = wid & 1;
        int lrow = lane & 15, quad = lane >> 4;

        bf16x8 a[4][4];
#pragma unroll
        for (int tm = 0; tm < 4; ++tm) {
            const unsigned short* arow = hb + (size_t)(n0 + wy * 64 + tm * 16 + lrow) * H + quad * 8;
#pragma unroll
            for (int ks = 0; ks < 4; ++ks)
                a[tm][ks] = *(const bf16x8*)(arow + ks * 32);
        }

        float lsum = 0.f;
        for (int pi = 0; pi < 4; ++pi) {
            int pt = pt0 + pi;
            __syncthreads();
            {
                int c = tid & 15;
                int r0 = tid >> 4;
#pragma unroll
                for (int it = 0; it < 8; ++it) {
                    int row = r0 + it * 16;
                    uint4 bv = *(const uint4*)(wt + (size_t)(pt * 128 + row) * H + c * 8);
                    *(uint4*)(Bsh + row * 136 + c * 8) = bv;
                }
            }
            __syncthreads();

            f32x4 acc[4][4];
#pragma unroll
            for (int tm = 0; tm < 4; ++tm)
#pragma unroll
                for (int tn = 0; tn < 4; ++tn)
                    acc[tm][tn] = (f32x4){0.f, 0.f, 0.f, 0.f};

            const unsigned short* Bbase = Bsh + (wx * 64 + lrow) * 136 + quad * 8;
#pragma unroll
            for (int ks = 0; ks < 4; ++ks) {
                bf16x8 b[4];
#pragma unroll
                for (int tn = 0; tn < 4; ++tn)
                    b[tn] = *(const bf16x8*)(Bbase + tn * 16 * 136 + ks * 32);
#pragma unroll
                for (int tm = 0; tm < 4; ++tm)
#pragma unroll
                    for (int tn = 0; tn < 4; ++tn)
                        acc[tm][tn] = __builtin_amdgcn_mfma_f32_16x16x32_bf16(a[tm][ks], b[tn], acc[tm][tn], 0, 0, 0);
            }

#pragma unroll
            for (int tn = 0; tn < 4; ++tn) {
                float bv = biasws[pt * 128 + wx * 64 + tn * 16 + lrow];
#pragma unroll
                for (int tm = 0; tm < 4; ++tm) {
#pragma unroll
                    for (int r = 0; r < 4; ++r)
                        lsum += fsig_fast(acc[tm][tn][r] + bv);
                }
            }
        }
        lsum = wave_reduce(lsum);
        if (lane == 0) red[wid] = lsum;
        __syncthreads();
        if (tid == 0)
            psum[by * nb128 + bx] = red[0] + red[1] + red[2] + red[3];
    } else if (blk < P2) {
        // ---------------- agg_outcost path ----------------
        int bkt = blk - P1;
        float* agg = (float*)Bsh;   // 64 floats carved from Bsh
        if (tid < BNODES) agg[tid] = 0.0f;
        __syncthreads();
        int cnt = cursor[bkt];
        if (cnt > BCAP) cnt = BCAP;
        if (cnt < 0) cnt = 0;
        const uint2* bp = buck + (size_t)bkt * BCAP;
        for (int base = 0; base < cnt; base += 2048) {
            unsigned x[8]; float pv[8]; int ii[8];
#pragma unroll
            for (int j = 0; j < 8; ++j) {
                ii[j] = base + j * 256 + tid;
                x[j] = (ii[j] < cnt) ? bp[ii[j]].x : 0u;
            }
#pragma unroll
            for (int j = 0; j < 8; ++j)
                pv[j] = (ii[j] < cnt) ? pred[x[j] & 0x3FFFF] : 0.f;
#pragma unroll
            for (int j = 0; j < 8; ++j)
                if (ii[j] < cnt) atomicAdd(&agg[(x[j] >> 18) & 63], pv[j]);
        }
        __syncthreads();
        if (tid < 64) {
            float v = 0.f;
            int node = bkt * BNODES + tid;
            if (node < N) {
                float d = agg[tid] - 1.0f;
                v = d * d * sc[node];
            }
            v = wave_reduce(v);
            if (tid == 0) ocpart[bkt] = v;
        }
    } else if (blk < P3) {
        // ---------------- rowcol path (+ce/sq on rows) ----------------
        int rc = blk - P2;
        if (rc < MNUM) {
            float p = 0.f, ce = 0.f, sq = 0.f;
            if (tid < MNUM) {
                p = pred[rc * MNUM + tid];
                ce = -gt[rc * MNUM + tid] * __log2f(p);
                sq = p * p;
            }
            p = wave_reduce(p);
            ce = wave_reduce(ce);
            sq = wave_reduce(sq);
            int wid = tid >> 6;
            if ((tid & 63) == 0) { red[wid] = p; red[4 + wid] = ce; red[8 + wid] = sq; }
            __syncthreads();
            if (tid == 0) {
                rs[rc] = red[0] + red[1] + red[2] + red[3];
                cepart[rc] = red[4] + red[5] + red[6] + red[7];
                sqpart[rc] = red[8] + red[9] + red[10] + red[11];
            }
        } else {
            int j = rc - MNUM;
            float p = 0.f;
            if (tid < MNUM) p = pred[tid * MNUM + j];
            p = wave_reduce(p);
            if ((tid & 63) == 0) red[tid >> 6] = p;
            __syncthreads();
            if (tid == 0) cs[j] = red[0] + red[1] + red[2] + red[3];
        }
    } else {
        // ---------------- gsum dim-reduction ----------------
        int dim = blk - P3;  // 0..127
        float s = 0.f;
        for (int b = tid; b < nbuck; b += 256) s += gpart[(size_t)b * 128 + dim];
        s = wave_reduce(s);
        if ((tid & 63) == 0) red[tid >> 6] = s;
        __syncthreads();
        if (tid == 0) gsum[dim] = red[0] + red[1] + red[2] + red[3];
    }
}

// K8: single-block tail: all six outputs via plain stores.
// loss2 = sum_i rs_i^2 + sum_j cs_j^2 - 2*sum p^2 (exact identity).
__global__ void tail_kernel(const float* __restrict__ rs, const float* __restrict__ cs,
                            const float* __restrict__ cepart, const float* __restrict__ sqpart,
                            const float* __restrict__ psum, int npsum,
                            const float* __restrict__ ocpart, int nbuck,
                            const float* __restrict__ gsum, const float* __restrict__ fc3_w,
                            const float* __restrict__ fc3_b, const float* __restrict__ fl3_b,
                            float* __restrict__ out, int N, int padrows) {
    __shared__ float red[4];
    int tid = threadIdx.x;
    // sumone
    float v = 0.f;
    if (tid < MNUM) {
        float a = rs[tid] - 1.0f, b = cs[tid] - 1.0f;
        v = a * a + b * b;
    }
    v = wave_reduce(v);
    if ((tid & 63) == 0) red[tid >> 6] = v;
    __syncthreads();
    if (tid == 0) out[1] = red[0] + red[1] + red[2] + red[3];
    __syncthreads();
    // ce
    float ce = (tid < MNUM) ? cepart[tid] : 0.f;
    ce = wave_reduce(ce);
    if ((tid & 63) == 0) red[tid >> 6] = ce;
    __syncthreads();
    if (tid == 0) out[3] = red[0] + red[1] + red[2] + red[3];
    __syncthreads();
    // loss2 = sum rs^2 + sum cs^2 - 2 sum p^2
    float l2 = 0.f;
    if (tid < MNUM)
        l2 = rs[tid] * rs[tid] + cs[tid] * cs[tid] - 2.0f * sqpart[tid];
    l2 = wave_reduce(l2);
    if ((tid & 63) == 0) red[tid >> 6] = l2;
    __syncthreads();
    if (tid == 0) out[2] = red[0] + red[1] + red[2] + red[3];
    __syncthreads();
    // prob3_sum
    float ps = 0.f;
    for (int i = tid; i < npsum; i += 256) ps += psum[i];
    float ss = 0.f;
    for (int p = tid; p < PNUM; p += 256) ss += fsig_fast(fl3_b[p]);
    float comb = ps - (float)padrows * ss;
    comb = wave_reduce(comb);
    if ((tid & 63) == 0) red[tid >> 6] = comb;
    __syncthreads();
    if (tid == 0) out[5] = red[0] + red[1] + red[2] + red[3];
    __syncthreads();
    // out_cost
    float oc = 0.f;
    for (int b = tid; b < nbuck; b += 256) oc += ocpart[b];
    oc = wave_reduce(oc);
    if ((tid & 63) == 0) red[tid >> 6] = oc;
    __syncthreads();
    if (tid == 0) out[4] = red[0] + red[1] + red[2] + red[3];
    __syncthreads();
    // pred_obj
    float pv = 0.f;
    if (tid < 128) pv = gsum[tid] * (1.0f / (float)N) * fc3_w[tid];
    pv = wave_reduce(pv);
    if ((tid & 63) == 0) red[tid >> 6] = pv;
    __syncthreads();
    if (tid == 0) out[0] = red[0] + red[1] + fc3_b[0];
}

extern "C" void kernel_launch(void* const* d_in, const int* in_sizes, int n_in,
                              void* d_out, int out_size, void* d_ws, size_t ws_size,
                              hipStream_t stream) {
    const float* ntc   = (const float*)d_in[0];
    const float* norm  = (const float*)d_in[1];
    const float* sc    = (const float*)d_in[2];
    const float* gt    = (const float*)d_in[3];
    const float* fc_w  = (const float*)d_in[4];
    const float* fc_b  = (const float*)d_in[5];
    const float* w_nt  = (const float*)d_in[6];
    const float* w_rel = (const float*)d_in[7];
    const float* fc2_w = (const float*)d_in[8];
    const float* fc2_b = (const float*)d_in[9];
    const float* fc3_w = (const float*)d_in[10];
    const float* fc3_b = (const float*)d_in[11];
    const float* fl3_w = (const float*)d_in[12];
    const float* fl3_b = (const float*)d_in[13];
    const int* node_type = (const int*)d_in[14];
    const int* src   = (const int*)d_in[15];
    const int* dst   = (const int*)d_in[16];
    const int* etype = (const int*)d_in[17];
    int N = in_sizes[2];
    int E = in_sizes[1];
    int nb128 = (N + 127) / 128;             // 391
    int padN  = nb128 * 128;                 // 50048
    int nbuck = padN / BNODES;               // 782
    int npsum = nb128 * 2;                   // 782
    int NP = (E + EPB - 1) / EPB;            // 196

    // ---- workspace layout (float offsets) ----
    float* ws   = (float*)d_ws;
    unsigned short* wt = (unsigned short*)ws;            // 0..65536 (131072 shorts)
    float* biasws = ws + 65536;              // ..66560
    float* gsum = ws + 66560;                // ..66688
    float* rs   = ws + 66688;                // ..66944
    float* cs   = ws + 66944;                // ..67200
    int*  cursor = (int*)(ws + 67200);       // ..67984 (784 ints)
    float* psum = ws + 67984;                // ..69008
    float* cepart = ws + 69008;              // ..69264
    float* sqpart = ws + 69264;              // ..69520
    float* ocpart = ws + 69520;              // ..70544
    unsigned short* CbT = (unsigned short*)(ws + 70544); // 8192 shorts -> ..74640
    float* gpart  = ws + 74640;              // ..174736 (782*128)
    float* pred = ws + 174736;               // ..+N
    unsigned short* hb = (unsigned short*)(pred + N);    // padN*128 bf16
    uint2* buck = (uint2*)(hb + (size_t)padN * H);       // nbuck*BCAP*8B
    float* out  = (float*)d_out;

    hipMemsetAsync(d_out, 0, 6 * sizeof(float), stream);
    hipMemsetAsync(cursor, 0, 784 * sizeof(int), stream);

    partition_setup<<<NP + 130, 1024, 0, stream>>>(src, dst, etype, norm, node_type,
                                                   cursor, buck, E, NP,
                                                   fl3_w, fl3_b, wt, biasws,
                                                   fc_w, fc_b, w_nt, w_rel, CbT);
    bucket_node<<<nbuck, 256, 0, stream>>>(buck, cursor, ntc, CbT, fc2_w, fc2_b,
                                           hb, pred, gpart, N);
    int megablocks = 2 * nb128 + nbuck + 2 * MNUM + 128;
    mega_kernel<<<megablocks, 256, 0, stream>>>(hb, wt, biasws, psum, nb128,
                                                buck, cursor, pred, sc, gt, ocpart, N,
                                                rs, cs, cepart, sqpart, gpart, gsum, nbuck);
    tail_kernel<<<1, 256, 0, stream>>>(rs, cs, cepart, sqpart, psum, npsum, ocpart, nbuck,
                                       gsum, fc3_w, fc3_b, fl3_b, out, N, padN - N);
}

// Round 17
// 202.797 us; speedup vs baseline: 1.6596x; 1.0455x over previous
//
#include <hip/hip_runtime.h>

#define H 128
#define RNUM 8
#define TNUM 2
#define PNUM 1000
#define MNUM 223
#define BNODES 64           // nodes per dst-bucket (power of 2)
#define NBUCK 782           // padN / 64
#define BCAP 2304           // per-bucket capacity (mean 2048, +5.7 sigma)
#define EPB 4096            // edges per partition block (512 thr x 8)

typedef __attribute__((ext_vector_type(8))) short bf16x8;
typedef __attribute__((ext_vector_type(4))) float f32x4;

__device__ __forceinline__ float fsig(float z) {
    return 1.0f / (1.0f + __expf(-z));
}
__device__ __forceinline__ float fsig_fast(float z) {
    return __builtin_amdgcn_rcpf(1.0f + __expf(-z));
}

__device__ __forceinline__ float wave_reduce(float v) {
#pragma unroll
    for (int off = 32; off > 0; off >>= 1) v += __shfl_down(v, off, 64);
    return v;
}

__device__ __forceinline__ unsigned short f2bf(float f) {
    unsigned int u = __float_as_uint(f);
    u += 0x7fffu + ((u >> 16) & 1u);   // RNE
    return (unsigned short)(u >> 16);
}

// ---------------------------------------------------------------------------
// K1 (partition + setup fused, 512 threads):
//  blocks [0, NP):         edge partition (8 edges/thread, 8-deep ILP)
//  blocks [NP, NP+256):    wt/bias transpose+pad (4 p's per block)
//  blocks [NP+256, +4):    CbT bf16 precompute (4 tr per block)
// Payload 8B: .x = src | (local<<18) | (r<<24) | (t<<27); .y = bits(norm)
// ---------------------------------------------------------------------------
__global__ __launch_bounds__(512) void partition_setup(
        const int* __restrict__ src, const int* __restrict__ dst,
        const int* __restrict__ etype, const float* __restrict__ norm,
        const int* __restrict__ node_type, int* __restrict__ cursor,
        uint2* __restrict__ buck, int E, int NP,
        const float* __restrict__ fl3_w, const float* __restrict__ fl3_b,
        unsigned short* __restrict__ wt, float* __restrict__ biasws,
        const float* __restrict__ fc_w, const float* __restrict__ fc_b,
        const float* __restrict__ w_nt, const float* __restrict__ w_rel,
        unsigned short* __restrict__ CbT) {
    int blk = blockIdx.x;
    int tid = threadIdx.x;
    if (blk < NP) {
        // ------------- partition path -------------
        __shared__ int lh[NBUCK];
        __shared__ int gb[NBUCK];
        for (int i = tid; i < NBUCK; i += 512) lh[i] = 0;
        __syncthreads();
        int base = blk * EPB;
        uint2 pl[8]; int bb[8]; int rk[8];
#pragma unroll
        for (int c = 0; c < 8; ++c) {
            int e = base + c * 512 + tid;
            bb[c] = -1;
            if (e < E) {
                int s = src[e];
                int d = dst[e];
                int r = etype[e];
                float nm = norm[e];
                int t = node_type[s];
                int b = d >> 6;
                int local = d & 63;
                pl[c].x = (unsigned)s | ((unsigned)local << 18) | ((unsigned)r << 24) | ((unsigned)t << 27);
                pl[c].y = __float_as_uint(nm);
                bb[c] = b;
                rk[c] = atomicAdd(&lh[b], 1);
            }
        }
        __syncthreads();
        for (int i = tid; i < NBUCK; i += 512) {
            if (lh[i] > 0) {
                int g = atomicAdd(&cursor[i], lh[i]);
                gb[i] = (g < 0) ? 0 : (g > BCAP ? BCAP : g);
            }
        }
        __syncthreads();
#pragma unroll
        for (int c = 0; c < 8; ++c) {
            if (bb[c] >= 0) {
                int pos = gb[bb[c]] + rk[c];
                if (pos < BCAP) buck[(size_t)bb[c] * BCAP + pos] = pl[c];
            }
        }
    } else if (blk < NP + 256) {
        // ------------- wt transpose path (4 p's per block) -------------
        int p = (blk - NP) * 4 + (tid >> 7);   // 0..1023
        int k = tid & 127;
        float v = (p < PNUM) ? fl3_w[(size_t)k * PNUM + p] : 0.0f;
        wt[(size_t)p * H + k] = f2bf(v);
        if (k == 0) biasws[p] = (p < PNUM) ? fl3_b[p] : -1.0e4f;
    } else {
        // ------------- CbT path (4 tr per block) -------------
        __shared__ float G[4][3][H];
        int g = tid >> 7;                       // group 0..3
        int tr = (blk - NP - 256) * 4 + g;      // 0..15
        int t = tr >> 3, r = tr & 7;
        int i = tid & 127;
        float a0 = 0.f, a1 = 0.f, a2 = 0.f;
#pragma unroll 8
        for (int j = 0; j < H; ++j) {
            float w = w_nt[((size_t)t * H + j) * H + i];
            a0 += fc_w[j] * w;
            a1 += fc_w[H + j] * w;
            a2 += fc_b[j] * w;
        }
        G[g][0][i] = a0; G[g][1][i] = a1; G[g][2][i] = a2;
        __syncthreads();
        float c0 = 0.f, c1 = 0.f, c2 = 0.f;
#pragma unroll 8
        for (int k = 0; k < H; ++k) {
            float w = w_rel[((size_t)r * H + k) * H + i];
            c0 += G[g][0][k] * w;
            c1 += G[g][1][k] * w;
            c2 += G[g][2][k] * w;
        }
        CbT[i * 64 + tr * 3 + 0] = f2bf(c0);
        CbT[i * 64 + tr * 3 + 1] = f2bf(c1);
        CbT[i * 64 + tr * 3 + 2] = f2bf(c2);
        if (tr == 0) {
            uint4 z = make_uint4(0u, 0u, 0u, 0u);
            *(uint4*)(CbT + i * 64 + 48) = z;
            *(uint4*)(CbT + i * 64 + 56) = z;
        }
    }
}

// ---------------------------------------------------------------------------
// K3: per-bucket replay with PACKED LDS atomics (2 per edge):
// (nm*c0, nm*c1) as 2^12 fixed-point halves of one u64 atomic, nm exact f32.
// Then h = relu(S@C) via bf16 MFMA; hb bf16, pred, gsum partial.
// ---------------------------------------------------------------------------
__global__ __launch_bounds__(256) void bucket_node(
        const uint2* __restrict__ buck, const int* __restrict__ cursor,
        const float* __restrict__ ntc, const unsigned short* __restrict__ CbT,
        const float* __restrict__ fc2_w, const float* __restrict__ fc2_b,
        unsigned short* __restrict__ hb, float* __restrict__ pred,
        float* __restrict__ gpart, int N) {
    __shared__ float S[64 * 68];            // union: replay P/F, then S
    __shared__ unsigned short Cb[128 * 72]; // CbT rows padded to 72 shorts
    __shared__ float gloc[128];
    unsigned long long* P = (unsigned long long*)S;   // 64*16 u64 = first 2048 floats
    float* F = S + 2048;                              // 64*17 f32 (padded rows)
    int tid = threadIdx.x;
    int bkt = blockIdx.x;
    for (int i = tid; i < 3136; i += 256) S[i] = 0.0f;   // zero P+F region
    for (int g = tid; g < 1024; g += 256) {   // stage CbT: 1024 uint4
        int row = g >> 3, c = g & 7;
        uint4 v = ((const uint4*)CbT)[g];
        *(uint4*)(Cb + row * 72 + c * 8) = v;
    }
    if (tid < 128) gloc[tid] = 0.0f;
    __syncthreads();

    int cnt = cursor[bkt];
    if (cnt > BCAP) cnt = BCAP;
    if (cnt < 0) cnt = 0;
    const uint2* bp = buck + (size_t)bkt * BCAP;
    const float fxs = 4096.0f;
    for (int base = 0; base < cnt; base += 1024) {
        uint2 pl[4]; float2 cc[4]; int ii[4];
#pragma unroll
        for (int j = 0; j < 4; ++j) {
            ii[j] = base + j * 256 + tid;
            pl[j] = (ii[j] < cnt) ? bp[ii[j]] : make_uint2(0u, 0u);
        }
#pragma unroll
        for (int j = 0; j < 4; ++j)
            cc[j] = (ii[j] < cnt) ? ((const float2*)ntc)[pl[j].x & 0x3FFFF]
                                  : make_float2(0.f, 0.f);
#pragma unroll
        for (int j = 0; j < 4; ++j) {
            if (ii[j] < cnt) {
                int local = (pl[j].x >> 18) & 63;
                int tr = ((pl[j].x >> 24) & 7) + (((pl[j].x >> 27) & 1) << 3);
                float nm = __uint_as_float(pl[j].y);
                unsigned lo = __float2uint_rn(nm * cc[j].x * fxs);
                unsigned hi = __float2uint_rn(nm * cc[j].y * fxs);
                unsigned long long pk = ((unsigned long long)hi << 32) | lo;
                atomicAdd(&P[local * 16 + tr], pk);
                atomicAdd(&F[local * 17 + tr], nm);
            }
        }
    }
    __syncthreads();

    // unpack P/F -> registers (1024 pairs, 4 per thread), then rebuild S
    unsigned long long rpk[4]; float rf[4];
#pragma unroll
    for (int u = 0; u < 4; ++u) {
        int idx = tid * 4 + u;                 // = local*16 + tr
        rpk[u] = P[idx];
        rf[u] = F[(idx >> 4) * 17 + (idx & 15)];
    }
    __syncthreads();
    const float inv = 1.0f / 4096.0f;
#pragma unroll
    for (int u = 0; u < 4; ++u) {
        int idx = tid * 4 + u;
        int local = idx >> 4, tr = idx & 15;
        float* p = S + local * 68 + tr * 3;
        p[0] = (float)(unsigned)(rpk[u] & 0xFFFFFFFFull) * inv;
        p[1] = (float)(unsigned)(rpk[u] >> 32) * inv;
        p[2] = rf[u];
    }
    for (int idx = tid; idx < 1024; idx += 256) {   // zero pad cols 48..63
        int row = idx >> 4, c = idx & 15;
        S[row * 68 + 48 + c] = 0.0f;
    }
    __syncthreads();

    int lane = tid & 63, w = tid >> 6;
    int lrow = lane & 15, quad = lane >> 4;

    // A-frags: rows w*16+lrow of S (fp32 -> bf16)
    bf16x8 a[2];
#pragma unroll
    for (int ks = 0; ks < 2; ++ks) {
        const float* sp = S + (w * 16 + lrow) * 68 + ks * 32 + quad * 8;
        float4 f0 = *(const float4*)sp;
        float4 f1 = *(const float4*)(sp + 4);
        bf16x8 t;
        t[0] = (short)f2bf(f0.x); t[1] = (short)f2bf(f0.y);
        t[2] = (short)f2bf(f0.z); t[3] = (short)f2bf(f0.w);
        t[4] = (short)f2bf(f1.x); t[5] = (short)f2bf(f1.y);
        t[6] = (short)f2bf(f1.z); t[7] = (short)f2bf(f1.w);
        a[ks] = t;
    }

    f32x4 acc[8];
#pragma unroll
    for (int tn = 0; tn < 8; ++tn) acc[tn] = (f32x4){0.f, 0.f, 0.f, 0.f};
#pragma unroll
    for (int ks = 0; ks < 2; ++ks) {
#pragma unroll
        for (int tn = 0; tn < 8; ++tn) {
            bf16x8 b = *(const bf16x8*)(Cb + (tn * 16 + lrow) * 72 + ks * 32 + quad * 8);
            acc[tn] = __builtin_amdgcn_mfma_f32_16x16x32_bf16(a[ks], b, acc[tn], 0, 0, 0);
        }
    }

    // relu
#pragma unroll
    for (int tn = 0; tn < 8; ++tn)
#pragma unroll
        for (int r = 0; r < 4; ++r) acc[tn][r] = fmaxf(acc[tn][r], 0.f);

    int vbase = bkt * BNODES + w * 16 + quad * 4;
#pragma unroll
    for (int r = 0; r < 4; ++r) {
        unsigned short* hrow = hb + (size_t)(vbase + r) * H + lrow;
#pragma unroll
        for (int tn = 0; tn < 8; ++tn) hrow[tn * 16] = f2bf(acc[tn][r]);
    }
    // pred: dot over 128 cols = reduce over 16 lanes of the quad
    float pd[4];
#pragma unroll
    for (int r = 0; r < 4; ++r) {
        float s = 0.f;
#pragma unroll
        for (int tn = 0; tn < 8; ++tn) s += acc[tn][r] * fc2_w[tn * 16 + lrow];
        pd[r] = s;
    }
#pragma unroll
    for (int mask = 1; mask < 16; mask <<= 1)
#pragma unroll
        for (int r = 0; r < 4; ++r) pd[r] += __shfl_xor(pd[r], mask, 64);
    if (lrow == 0) {
#pragma unroll
        for (int r = 0; r < 4; ++r) {
            int v = vbase + r;
            if (v < N) {
                float z = pd[r] + fc2_b[0];
                pred[v] = fminf(fmaxf(fsig(z), 1e-7f), 1e10f);
            }
        }
    }
    // gsum partial: column sums over this wave's 16 rows
    float csum[8];
#pragma unroll
    for (int tn = 0; tn < 8; ++tn)
        csum[tn] = acc[tn][0] + acc[tn][1] + acc[tn][2] + acc[tn][3];
#pragma unroll
    for (int mask = 16; mask < 64; mask <<= 1)
#pragma unroll
        for (int tn = 0; tn < 8; ++tn) csum[tn] += __shfl_xor(csum[tn], mask, 64);
    if (lane < 16) {
#pragma unroll
        for (int tn = 0; tn < 8; ++tn) atomicAdd(&gloc[tn * 16 + lrow], csum[tn]);
    }
    __syncthreads();
    if (tid < 128) gpart[(size_t)bkt * 128 + tid] = gloc[tid];
}

// ---------------------------------------------------------------------------
// K4 (MEGA): all post-bucket_node independent work in ONE launch.
// ---------------------------------------------------------------------------
__global__ __launch_bounds__(256, 2) void mega_kernel(
        const unsigned short* __restrict__ hb, const unsigned short* __restrict__ wt,
        const float* __restrict__ biasws, float* __restrict__ psum, int nb128,
        const uint2* __restrict__ buck, const int* __restrict__ cursor,
        const float* __restrict__ pred, const float* __restrict__ sc,
        const float* __restrict__ gt, float* __restrict__ ocpart, int N,
        float* __restrict__ rs, float* __restrict__ cs,
        float* __restrict__ cepart, float* __restrict__ sqpart,
        const float* __restrict__ gpart, float* __restrict__ gsum, int nbuck) {
    __shared__ unsigned short Bsh[128 * 136];
    __shared__ float red[12];
    int blk = blockIdx.x;
    int tid = threadIdx.x;
    int P1 = 2 * nb128;
    int P2 = P1 + nbuck;
    int P3 = P2 + 2 * MNUM;

    if (blk < P1) {
        // ---------------- prob3 path ----------------
        int by = blk / nb128, bx = blk - by * nb128;
        int n0 = bx * 128;
        int pt0 = by * 4;
        int lane = tid & 63, wid = tid >> 6;
        int wy = wid >> 1, wx = wid & 1;
        int lrow = lane & 15, quad = lane >> 4;

        bf16x8 a[4][4];
#pragma unroll
        for (int tm = 0; tm < 4; ++tm) {
            const unsigned short* arow = hb + (size_t)(n0 + wy * 64 + tm * 16 + lrow) * H + quad * 8;
#pragma unroll
            for (int ks = 0; ks < 4; ++ks)
                a[tm][ks] = *(const bf16x8*)(arow + ks * 32);
        }

        float lsum = 0.f;
        for (int pi = 0; pi < 4; ++pi) {
            int pt = pt0 + pi;
            __syncthreads();
            {
                int c = tid & 15;
                int r0 = tid >> 4;
#pragma unroll
                for (int it = 0; it < 8; ++it) {
                    int row = r0 + it * 16;
                    uint4 bv = *(const uint4*)(wt + (size_t)(pt * 128 + row) * H + c * 8);
                    *(uint4*)(Bsh + row * 136 + c * 8) = bv;
                }
            }
            __syncthreads();

            f32x4 acc[4][4];
#pragma unroll
            for (int tm = 0; tm < 4; ++tm)
#pragma unroll
                for (int tn = 0; tn < 4; ++tn)
                    acc[tm][tn] = (f32x4){0.f, 0.f, 0.f, 0.f};

            const unsigned short* Bbase = Bsh + (wx * 64 + lrow) * 136 + quad * 8;
#pragma unroll
            for (int ks = 0; ks < 4; ++ks) {
                bf16x8 b[4];
#pragma unroll
                for (int tn = 0; tn < 4; ++tn)
                    b[tn] = *(const bf16x8*)(Bbase + tn * 16 * 136 + ks * 32);
#pragma unroll
                for (int tm = 0; tm < 4; ++tm)
#pragma unroll
                    for (int tn = 0; tn < 4; ++tn)
                        acc[tm][tn] = __builtin_amdgcn_mfma_f32_16x16x32_bf16(a[tm][ks], b[tn], acc[tm][tn], 0, 0, 0);
            }

#pragma unroll
            for (int tn = 0; tn < 4; ++tn) {
                float bv = biasws[pt * 128 + wx * 64 + tn * 16 + lrow];
#pragma unroll
                for (int tm = 0; tm < 4; ++tm) {
#pragma unroll
                    for (int r = 0; r < 4; ++r)
                        lsum += fsig_fast(acc[tm][tn][r] + bv);
                }
            }
        }
        lsum = wave_reduce(lsum);
        if (lane == 0) red[wid] = lsum;
        __syncthreads();
        if (tid == 0)
            psum[by * nb128 + bx] = red[0] + red[1] + red[2] + red[3];
    } else if (blk < P2) {
        // ---------------- agg_outcost path ----------------
        int bkt = blk - P1;
        float* agg = (float*)Bsh;   // 64 floats carved from Bsh
        if (tid < BNODES) agg[tid] = 0.0f;
        __syncthreads();
        int cnt = cursor[bkt];
        if (cnt > BCAP) cnt = BCAP;
        if (cnt < 0) cnt = 0;
        const uint2* bp = buck + (size_t)bkt * BCAP;
        for (int base = 0; base < cnt; base += 2048) {
            unsigned x[8]; float pv[8]; int ii[8];
#pragma unroll
            for (int j = 0; j < 8; ++j) {
                ii[j] = base + j * 256 + tid;
                x[j] = (ii[j] < cnt) ? bp[ii[j]].x : 0u;
            }
#pragma unroll
            for (int j = 0; j < 8; ++j)
                pv[j] = (ii[j] < cnt) ? pred[x[j] & 0x3FFFF] : 0.f;
#pragma unroll
            for (int j = 0; j < 8; ++j)
                if (ii[j] < cnt) atomicAdd(&agg[(x[j] >> 18) & 63], pv[j]);
        }
        __syncthreads();
        if (tid < 64) {
            float v = 0.f;
            int node = bkt * BNODES + tid;
            if (node < N) {
                float d = agg[tid] - 1.0f;
                v = d * d * sc[node];
            }
            v = wave_reduce(v);
            if (tid == 0) ocpart[bkt] = v;
        }
    } else if (blk < P3) {
        // ---------------- rowcol path (+ce/sq on rows) ----------------
        int rc = blk - P2;
        if (rc < MNUM) {
            float p = 0.f, ce = 0.f, sq = 0.f;
            if (tid < MNUM) {
                p = pred[rc * MNUM + tid];
                ce = -gt[rc * MNUM + tid] * __log2f(p);
                sq = p * p;
            }
            p = wave_reduce(p);
            ce = wave_reduce(ce);
            sq = wave_reduce(sq);
            int wid = tid >> 6;
            if ((tid & 63) == 0) { red[wid] = p; red[4 + wid] = ce; red[8 + wid] = sq; }
            __syncthreads();
            if (tid == 0) {
                rs[rc] = red[0] + red[1] + red[2] + red[3];
                cepart[rc] = red[4] + red[5] + red[6] + red[7];
                sqpart[rc] = red[8] + red[9] + red[10] + red[11];
            }
        } else {
            int j = rc - MNUM;
            float p = 0.f;
            if (tid < MNUM) p = pred[tid * MNUM + j];
            p = wave_reduce(p);
            if ((tid & 63) == 0) red[tid >> 6] = p;
            __syncthreads();
            if (tid == 0) cs[j] = red[0] + red[1] + red[2] + red[3];
        }
    } else {
        // ---------------- gsum dim-reduction ----------------
        int dim = blk - P3;  // 0..127
        float s = 0.f;
        for (int b = tid; b < nbuck; b += 256) s += gpart[(size_t)b * 128 + dim];
        s = wave_reduce(s);
        if ((tid & 63) == 0) red[tid >> 6] = s;
        __syncthreads();
        if (tid == 0) gsum[dim] = red[0] + red[1] + red[2] + red[3];
    }
}

// K8: single-block tail: all six outputs via plain stores (no d_out memset
// needed — every slot is written unconditionally).
__global__ void tail_kernel(const float* __restrict__ rs, const float* __restrict__ cs,
                            const float* __restrict__ cepart, const float* __restrict__ sqpart,
                            const float* __restrict__ psum, int npsum,
                            const float* __restrict__ ocpart, int nbuck,
                            const float* __restrict__ gsum, const float* __restrict__ fc3_w,
                            const float* __restrict__ fc3_b, const float* __restrict__ fl3_b,
                            float* __restrict__ out, int N, int padrows) {
    __shared__ float red[4];
    int tid = threadIdx.x;
    // sumone
    float v = 0.f;
    if (tid < MNUM) {
        float a = rs[tid] - 1.0f, b = cs[tid] - 1.0f;
        v = a * a + b * b;
    }
    v = wave_reduce(v);
    if ((tid & 63) == 0) red[tid >> 6] = v;
    __syncthreads();
    if (tid == 0) out[1] = red[0] + red[1] + red[2] + red[3];
    __syncthreads();
    // ce
    float ce = (tid < MNUM) ? cepart[tid] : 0.f;
    ce = wave_reduce(ce);
    if ((tid & 63) == 0) red[tid >> 6] = ce;
    __syncthreads();
    if (tid == 0) out[3] = red[0] + red[1] + red[2] + red[3];
    __syncthreads();
    // loss2 = sum rs^2 + sum cs^2 - 2 sum p^2
    float l2 = 0.f;
    if (tid < MNUM)
        l2 = rs[tid] * rs[tid] + cs[tid] * cs[tid] - 2.0f * sqpart[tid];
    l2 = wave_reduce(l2);
    if ((tid & 63) == 0) red[tid >> 6] = l2;
    __syncthreads();
    if (tid == 0) out[2] = red[0] + red[1] + red[2] + red[3];
    __syncthreads();
    // prob3_sum
    float ps = 0.f;
    for (int i = tid; i < npsum; i += 256) ps += psum[i];
    float ss = 0.f;
    for (int p = tid; p < PNUM; p += 256) ss += fsig_fast(fl3_b[p]);
    float comb = ps - (float)padrows * ss;
    comb = wave_reduce(comb);
    if ((tid & 63) == 0) red[tid >> 6] = comb;
    __syncthreads();
    if (tid == 0) out[5] = red[0] + red[1] + red[2] + red[3];
    __syncthreads();
    // out_cost
    float oc = 0.f;
    for (int b = tid; b < nbuck; b += 256) oc += ocpart[b];
    oc = wave_reduce(oc);
    if ((tid & 63) == 0) red[tid >> 6] = oc;
    __syncthreads();
    if (tid == 0) out[4] = red[0] + red[1] + red[2] + red[3];
    __syncthreads();
    // pred_obj
    float pv = 0.f;
    if (tid < 128) pv = gsum[tid] * (1.0f / (float)N) * fc3_w[tid];
    pv = wave_reduce(pv);
    if ((tid & 63) == 0) red[tid >> 6] = pv;
    __syncthreads();
    if (tid == 0) out[0] = red[0] + red[1] + fc3_b[0];
}

extern "C" void kernel_launch(void* const* d_in, const int* in_sizes, int n_in,
                              void* d_out, int out_size, void* d_ws, size_t ws_size,
                              hipStream_t stream) {
    const float* ntc   = (const float*)d_in[0];
    const float* norm  = (const float*)d_in[1];
    const float* sc    = (const float*)d_in[2];
    const float* gt    = (const float*)d_in[3];
    const float* fc_w  = (const float*)d_in[4];
    const float* fc_b  = (const float*)d_in[5];
    const float* w_nt  = (const float*)d_in[6];
    const float* w_rel = (const float*)d_in[7];
    const float* fc2_w = (const float*)d_in[8];
    const float* fc2_b = (const float*)d_in[9];
    const float* fc3_w = (const float*)d_in[10];
    const float* fc3_b = (const float*)d_in[11];
    const float* fl3_w = (const float*)d_in[12];
    const float* fl3_b = (const float*)d_in[13];
    const int* node_type = (const int*)d_in[14];
    const int* src   = (const int*)d_in[15];
    const int* dst   = (const int*)d_in[16];
    const int* etype = (const int*)d_in[17];
    int N = in_sizes[2];
    int E = in_sizes[1];
    int nb128 = (N + 127) / 128;             // 391
    int padN  = nb128 * 128;                 // 50048
    int nbuck = padN / BNODES;               // 782
    int npsum = nb128 * 2;                   // 782
    int NP = (E + EPB - 1) / EPB;            // 391

    // ---- workspace layout (float offsets) ----
    float* ws   = (float*)d_ws;
    unsigned short* wt = (unsigned short*)ws;            // 0..65536 (131072 shorts)
    float* biasws = ws + 65536;              // ..66560
    float* gsum = ws + 66560;                // ..66688
    float* rs   = ws + 66688;                // ..66944
    float* cs   = ws + 66944;                // ..67200
    int*  cursor = (int*)(ws + 67200);       // ..67984 (784 ints)
    float* psum = ws + 67984;                // ..69008
    float* cepart = ws + 69008;              // ..69264
    float* sqpart = ws + 69264;              // ..69520
    float* ocpart = ws + 69520;              // ..70544
    unsigned short* CbT = (unsigned short*)(ws + 70544); // 8192 shorts -> ..74640
    float* gpart  = ws + 74640;              // ..174736 (782*128)
    float* pred = ws + 174736;               // ..+N
    unsigned short* hb = (unsigned short*)(pred + N);    // padN*128 bf16
    uint2* buck = (uint2*)(hb + (size_t)padN * H);       // nbuck*BCAP*8B
    float* out  = (float*)d_out;

    hipMemsetAsync(cursor, 0, 784 * sizeof(int), stream);

    partition_setup<<<NP + 260, 512, 0, stream>>>(src, dst, etype, norm, node_type,
                                                  cursor, buck, E, NP,
                                                  fl3_w, fl3_b, wt, biasws,
                                                  fc_w, fc_b, w_nt, w_rel, CbT);
    bucket_node<<<nbuck, 256, 0, stream>>>(buck, cursor, ntc, CbT, fc2_w, fc2_b,
                                           hb, pred, gpart, N);
    int megablocks = 2 * nb128 + nbuck + 2 * MNUM + 128;
    mega_kernel<<<megablocks, 256, 0, stream>>>(hb, wt, biasws, psum, nb128,
                                                buck, cursor, pred, sc, gt, ocpart, N,
                                                rs, cs, cepart, sqpart, gpart, gsum, nbuck);
    tail_kernel<<<1, 256, 0, stream>>>(rs, cs, cepart, sqpart, psum, npsum, ocpart, nbuck,
                                       gsum, fc3_w, fc3_b, fl3_b, out, N, padN - N);
}

// Round 18
// 200.597 us; speedup vs baseline: 1.6778x; 1.0110x over previous
//
#include <hip/hip_runtime.h>

#define H 128
#define RNUM 8
#define TNUM 2
#define PNUM 1000
#define MNUM 223
#define BNODES 64           // nodes per dst-bucket (power of 2)
#define NBUCK 782           // padN / 64
#define BCAP 2304           // per-bucket capacity (mean 2048, +5.7 sigma)
#define EPB 4096            // edges per partition block (512 thr x 8)

typedef __attribute__((ext_vector_type(8))) short bf16x8;
typedef __attribute__((ext_vector_type(4))) float f32x4;

__device__ __forceinline__ float fsig(float z) {
    return 1.0f / (1.0f + __expf(-z));
}
__device__ __forceinline__ float fsig_fast(float z) {
    return __builtin_amdgcn_rcpf(1.0f + __expf(-z));
}

__device__ __forceinline__ float wave_reduce(float v) {
#pragma unroll
    for (int off = 32; off > 0; off >>= 1) v += __shfl_down(v, off, 64);
    return v;
}

__device__ __forceinline__ unsigned short f2bf(float f) {
    unsigned int u = __float_as_uint(f);
    u += 0x7fffu + ((u >> 16) & 1u);   // RNE
    return (unsigned short)(u >> 16);
}

// ---------------------------------------------------------------------------
// K1 (partition + setup fused, 512 threads):
//  blocks [0, NP):         edge partition (8 edges/thread, 8-deep ILP)
//  blocks [NP, NP+256):    wt/bias transpose+pad (4 p's per block)
//  blocks [NP+256, +4):    CbT bf16 precompute (4 tr per block)
// Payload 8B: .x = src | (local<<18) | (r<<24) | (t<<27); .y = bits(norm)
// ---------------------------------------------------------------------------
__global__ __launch_bounds__(512) void partition_setup(
        const int* __restrict__ src, const int* __restrict__ dst,
        const int* __restrict__ etype, const float* __restrict__ norm,
        const int* __restrict__ node_type, int* __restrict__ cursor,
        uint2* __restrict__ buck, int E, int NP,
        const float* __restrict__ fl3_w, const float* __restrict__ fl3_b,
        unsigned short* __restrict__ wt, float* __restrict__ biasws,
        const float* __restrict__ fc_w, const float* __restrict__ fc_b,
        const float* __restrict__ w_nt, const float* __restrict__ w_rel,
        unsigned short* __restrict__ CbT) {
    int blk = blockIdx.x;
    int tid = threadIdx.x;
    if (blk < NP) {
        // ------------- partition path -------------
        __shared__ int lh[NBUCK];
        __shared__ int gb[NBUCK];
        for (int i = tid; i < NBUCK; i += 512) lh[i] = 0;
        __syncthreads();
        int base = blk * EPB;
        uint2 pl[8]; int bb[8]; int rk[8];
#pragma unroll
        for (int c = 0; c < 8; ++c) {
            int e = base + c * 512 + tid;
            bb[c] = -1;
            if (e < E) {
                int s = src[e];
                int d = dst[e];
                int r = etype[e];
                float nm = norm[e];
                int t = node_type[s];
                int b = d >> 6;
                int local = d & 63;
                pl[c].x = (unsigned)s | ((unsigned)local << 18) | ((unsigned)r << 24) | ((unsigned)t << 27);
                pl[c].y = __float_as_uint(nm);
                bb[c] = b;
                rk[c] = atomicAdd(&lh[b], 1);
            }
        }
        __syncthreads();
        for (int i = tid; i < NBUCK; i += 512) {
            if (lh[i] > 0) {
                int g = atomicAdd(&cursor[i], lh[i]);
                gb[i] = (g < 0) ? 0 : (g > BCAP ? BCAP : g);
            }
        }
        __syncthreads();
#pragma unroll
        for (int c = 0; c < 8; ++c) {
            if (bb[c] >= 0) {
                int pos = gb[bb[c]] + rk[c];
                if (pos < BCAP) buck[(size_t)bb[c] * BCAP + pos] = pl[c];
            }
        }
    } else if (blk < NP + 256) {
        // ------------- wt transpose path (4 p's per block) -------------
        int p = (blk - NP) * 4 + (tid >> 7);   // 0..1023
        int k = tid & 127;
        float v = (p < PNUM) ? fl3_w[(size_t)k * PNUM + p] : 0.0f;
        wt[(size_t)p * H + k] = f2bf(v);
        if (k == 0) biasws[p] = (p < PNUM) ? fl3_b[p] : -1.0e4f;
    } else {
        // ------------- CbT path (4 tr per block) -------------
        __shared__ float G[4][3][H];
        int g = tid >> 7;                       // group 0..3
        int tr = (blk - NP - 256) * 4 + g;      // 0..15
        int t = tr >> 3, r = tr & 7;
        int i = tid & 127;
        float a0 = 0.f, a1 = 0.f, a2 = 0.f;
#pragma unroll 8
        for (int j = 0; j < H; ++j) {
            float w = w_nt[((size_t)t * H + j) * H + i];
            a0 += fc_w[j] * w;
            a1 += fc_w[H + j] * w;
            a2 += fc_b[j] * w;
        }
        G[g][0][i] = a0; G[g][1][i] = a1; G[g][2][i] = a2;
        __syncthreads();
        float c0 = 0.f, c1 = 0.f, c2 = 0.f;
#pragma unroll 8
        for (int k = 0; k < H; ++k) {
            float w = w_rel[((size_t)r * H + k) * H + i];
            c0 += G[g][0][k] * w;
            c1 += G[g][1][k] * w;
            c2 += G[g][2][k] * w;
        }
        CbT[i * 64 + tr * 3 + 0] = f2bf(c0);
        CbT[i * 64 + tr * 3 + 1] = f2bf(c1);
        CbT[i * 64 + tr * 3 + 2] = f2bf(c2);
        if (tr == 0) {
            uint4 z = make_uint4(0u, 0u, 0u, 0u);
            *(uint4*)(CbT + i * 64 + 48) = z;
            *(uint4*)(CbT + i * 64 + 56) = z;
        }
    }
}

// ---------------------------------------------------------------------------
// K3: per-bucket replay with ONE packed u64 LDS atomic per edge:
// fields [0:21) nm*c0 @2^-7, [21:42) nm*c1 @2^-7, [42:63) nm @2^-9.
// Worst-bucket sums: 2304*5.5*128=1.62M and 2304*1.1*512=1.30M, both < 2^21
// -> no cross-field carry (all addends non-negative). Quantization sigma
// ~1e-4 relative, below the bf16 rounding already in the MFMA path.
// Then h = relu(S@C) via bf16 MFMA; hb bf16, pred, gsum partial.
// ---------------------------------------------------------------------------
__global__ __launch_bounds__(256) void bucket_node(
        const uint2* __restrict__ buck, const int* __restrict__ cursor,
        const float* __restrict__ ntc, const unsigned short* __restrict__ CbT,
        const float* __restrict__ fc2_w, const float* __restrict__ fc2_b,
        unsigned short* __restrict__ hb, float* __restrict__ pred,
        float* __restrict__ gpart, int N) {
    __shared__ float S[64 * 68];            // union: replay P, then S
    __shared__ unsigned short Cb[128 * 72]; // CbT rows padded to 72 shorts
    __shared__ float gloc[128];
    unsigned long long* P = (unsigned long long*)S;   // 64*16 u64 = first 2048 floats
    int tid = threadIdx.x;
    int bkt = blockIdx.x;
    for (int i = tid; i < 2048; i += 256) S[i] = 0.0f;   // zero P region
    for (int g = tid; g < 1024; g += 256) {   // stage CbT: 1024 uint4
        int row = g >> 3, c = g & 7;
        uint4 v = ((const uint4*)CbT)[g];
        *(uint4*)(Cb + row * 72 + c * 8) = v;
    }
    if (tid < 128) gloc[tid] = 0.0f;
    __syncthreads();

    int cnt = cursor[bkt];
    if (cnt > BCAP) cnt = BCAP;
    if (cnt < 0) cnt = 0;
    const uint2* bp = buck + (size_t)bkt * BCAP;
    for (int base = 0; base < cnt; base += 1024) {
        uint2 pl[4]; float2 cc[4]; int ii[4];
#pragma unroll
        for (int j = 0; j < 4; ++j) {
            ii[j] = base + j * 256 + tid;
            pl[j] = (ii[j] < cnt) ? bp[ii[j]] : make_uint2(0u, 0u);
        }
#pragma unroll
        for (int j = 0; j < 4; ++j)
            cc[j] = (ii[j] < cnt) ? ((const float2*)ntc)[pl[j].x & 0x3FFFF]
                                  : make_float2(0.f, 0.f);
#pragma unroll
        for (int j = 0; j < 4; ++j) {
            if (ii[j] < cnt) {
                int local = (pl[j].x >> 18) & 63;
                int tr = ((pl[j].x >> 24) & 7) + (((pl[j].x >> 27) & 1) << 3);
                float nm = __uint_as_float(pl[j].y);
                unsigned f0 = __float2uint_rn(nm * cc[j].x * 128.0f);
                unsigned f1 = __float2uint_rn(nm * cc[j].y * 128.0f);
                unsigned f2 = __float2uint_rn(nm * 512.0f);
                unsigned long long pk = (unsigned long long)f0
                                      | ((unsigned long long)f1 << 21)
                                      | ((unsigned long long)f2 << 42);
                atomicAdd(&P[local * 16 + tr], pk);
            }
        }
    }
    __syncthreads();

    // unpack P -> registers (1024 u64, 4 per thread), then rebuild S
    unsigned long long rpk[4];
#pragma unroll
    for (int u = 0; u < 4; ++u) rpk[u] = P[tid * 4 + u];
    __syncthreads();
#pragma unroll
    for (int u = 0; u < 4; ++u) {
        int idx = tid * 4 + u;
        int local = idx >> 4, tr = idx & 15;
        float* p = S + local * 68 + tr * 3;
        p[0] = (float)(unsigned)(rpk[u] & 0x1FFFFFull) * (1.0f / 128.0f);
        p[1] = (float)(unsigned)((rpk[u] >> 21) & 0x1FFFFFull) * (1.0f / 128.0f);
        p[2] = (float)(unsigned)(rpk[u] >> 42) * (1.0f / 512.0f);
    }
    for (int idx = tid; idx < 1024; idx += 256) {   // zero pad cols 48..63
        int row = idx >> 4, c = idx & 15;
        S[row * 68 + 48 + c] = 0.0f;
    }
    __syncthreads();

    int lane = tid & 63, w = tid >> 6;
    int lrow = lane & 15, quad = lane >> 4;

    // A-frags: rows w*16+lrow of S (fp32 -> bf16)
    bf16x8 a[2];
#pragma unroll
    for (int ks = 0; ks < 2; ++ks) {
        const float* sp = S + (w * 16 + lrow) * 68 + ks * 32 + quad * 8;
        float4 f0 = *(const float4*)sp;
        float4 f1 = *(const float4*)(sp + 4);
        bf16x8 t;
        t[0] = (short)f2bf(f0.x); t[1] = (short)f2bf(f0.y);
        t[2] = (short)f2bf(f0.z); t[3] = (short)f2bf(f0.w);
        t[4] = (short)f2bf(f1.x); t[5] = (short)f2bf(f1.y);
        t[6] = (short)f2bf(f1.z); t[7] = (short)f2bf(f1.w);
        a[ks] = t;
    }

    f32x4 acc[8];
#pragma unroll
    for (int tn = 0; tn < 8; ++tn) acc[tn] = (f32x4){0.f, 0.f, 0.f, 0.f};
#pragma unroll
    for (int ks = 0; ks < 2; ++ks) {
#pragma unroll
        for (int tn = 0; tn < 8; ++tn) {
            bf16x8 b = *(const bf16x8*)(Cb + (tn * 16 + lrow) * 72 + ks * 32 + quad * 8);
            acc[tn] = __builtin_amdgcn_mfma_f32_16x16x32_bf16(a[ks], b, acc[tn], 0, 0, 0);
        }
    }

    // relu
#pragma unroll
    for (int tn = 0; tn < 8; ++tn)
#pragma unroll
        for (int r = 0; r < 4; ++r) acc[tn][r] = fmaxf(acc[tn][r], 0.f);

    int vbase = bkt * BNODES + w * 16 + quad * 4;
#pragma unroll
    for (int r = 0; r < 4; ++r) {
        unsigned short* hrow = hb + (size_t)(vbase + r) * H + lrow;
#pragma unroll
        for (int tn = 0; tn < 8; ++tn) hrow[tn * 16] = f2bf(acc[tn][r]);
    }
    // pred: dot over 128 cols = reduce over 16 lanes of the quad
    float pd[4];
#pragma unroll
    for (int r = 0; r < 4; ++r) {
        float s = 0.f;
#pragma unroll
        for (int tn = 0; tn < 8; ++tn) s += acc[tn][r] * fc2_w[tn * 16 + lrow];
        pd[r] = s;
    }
#pragma unroll
    for (int mask = 1; mask < 16; mask <<= 1)
#pragma unroll
        for (int r = 0; r < 4; ++r) pd[r] += __shfl_xor(pd[r], mask, 64);
    if (lrow == 0) {
#pragma unroll
        for (int r = 0; r < 4; ++r) {
            int v = vbase + r;
            if (v < N) {
                float z = pd[r] + fc2_b[0];
                pred[v] = fminf(fmaxf(fsig(z), 1e-7f), 1e10f);
            }
        }
    }
    // gsum partial: column sums over this wave's 16 rows
    float csum[8];
#pragma unroll
    for (int tn = 0; tn < 8; ++tn)
        csum[tn] = acc[tn][0] + acc[tn][1] + acc[tn][2] + acc[tn][3];
#pragma unroll
    for (int mask = 16; mask < 64; mask <<= 1)
#pragma unroll
        for (int tn = 0; tn < 8; ++tn) csum[tn] += __shfl_xor(csum[tn], mask, 64);
    if (lane < 16) {
#pragma unroll
        for (int tn = 0; tn < 8; ++tn) atomicAdd(&gloc[tn * 16 + lrow], csum[tn]);
    }
    __syncthreads();
    if (tid < 128) gpart[(size_t)bkt * 128 + tid] = gloc[tid];
}

// ---------------------------------------------------------------------------
// K4 (MEGA): all post-bucket_node independent work in ONE launch.
// ---------------------------------------------------------------------------
__global__ __launch_bounds__(256, 2) void mega_kernel(
        const unsigned short* __restrict__ hb, const unsigned short* __restrict__ wt,
        const float* __restrict__ biasws, float* __restrict__ psum, int nb128,
        const uint2* __restrict__ buck, const int* __restrict__ cursor,
        const float* __restrict__ pred, const float* __restrict__ sc,
        const float* __restrict__ gt, float* __restrict__ ocpart, int N,
        float* __restrict__ rs, float* __restrict__ cs,
        float* __restrict__ cepart, float* __restrict__ sqpart,
        const float* __restrict__ gpart, float* __restrict__ gsum, int nbuck) {
    __shared__ unsigned short Bsh[128 * 136];
    __shared__ float red[12];
    int blk = blockIdx.x;
    int tid = threadIdx.x;
    int P1 = 2 * nb128;
    int P2 = P1 + nbuck;
    int P3 = P2 + 2 * MNUM;

    if (blk < P1) {
        // ---------------- prob3 path ----------------
        int by = blk / nb128, bx = blk - by * nb128;
        int n0 = bx * 128;
        int pt0 = by * 4;
        int lane = tid & 63, wid = tid >> 6;
        int wy = wid >> 1, wx = wid & 1;
        int lrow = lane & 15, quad = lane >> 4;

        bf16x8 a[4][4];
#pragma unroll
        for (int tm = 0; tm < 4; ++tm) {
            const unsigned short* arow = hb + (size_t)(n0 + wy * 64 + tm * 16 + lrow) * H + quad * 8;
#pragma unroll
            for (int ks = 0; ks < 4; ++ks)
                a[tm][ks] = *(const bf16x8*)(arow + ks * 32);
        }

        float lsum = 0.f;
        for (int pi = 0; pi < 4; ++pi) {
            int pt = pt0 + pi;
            __syncthreads();
            {
                int c = tid & 15;
                int r0 = tid >> 4;
#pragma unroll
                for (int it = 0; it < 8; ++it) {
                    int row = r0 + it * 16;
                    uint4 bv = *(const uint4*)(wt + (size_t)(pt * 128 + row) * H + c * 8);
                    *(uint4*)(Bsh + row * 136 + c * 8) = bv;
                }
            }
            __syncthreads();

            f32x4 acc[4][4];
#pragma unroll
            for (int tm = 0; tm < 4; ++tm)
#pragma unroll
                for (int tn = 0; tn < 4; ++tn)
                    acc[tm][tn] = (f32x4){0.f, 0.f, 0.f, 0.f};

            const unsigned short* Bbase = Bsh + (wx * 64 + lrow) * 136 + quad * 8;
#pragma unroll
            for (int ks = 0; ks < 4; ++ks) {
                bf16x8 b[4];
#pragma unroll
                for (int tn = 0; tn < 4; ++tn)
                    b[tn] = *(const bf16x8*)(Bbase + tn * 16 * 136 + ks * 32);
#pragma unroll
                for (int tm = 0; tm < 4; ++tm)
#pragma unroll
                    for (int tn = 0; tn < 4; ++tn)
                        acc[tm][tn] = __builtin_amdgcn_mfma_f32_16x16x32_bf16(a[tm][ks], b[tn], acc[tm][tn], 0, 0, 0);
            }

#pragma unroll
            for (int tn = 0; tn < 4; ++tn) {
                float bv = biasws[pt * 128 + wx * 64 + tn * 16 + lrow];
#pragma unroll
                for (int tm = 0; tm < 4; ++tm) {
#pragma unroll
                    for (int r = 0; r < 4; ++r)
                        lsum += fsig_fast(acc[tm][tn][r] + bv);
                }
            }
        }
        lsum = wave_reduce(lsum);
        if (lane == 0) red[wid] = lsum;
        __syncthreads();
        if (tid == 0)
            psum[by * nb128 + bx] = red[0] + red[1] + red[2] + red[3];
    } else if (blk < P2) {
        // ---------------- agg_outcost path ----------------
        int bkt = blk - P1;
        float* agg = (float*)Bsh;   // 64 floats carved from Bsh
        if (tid < BNODES) agg[tid] = 0.0f;
        __syncthreads();
        int cnt = cursor[bkt];
        if (cnt > BCAP) cnt = BCAP;
        if (cnt < 0) cnt = 0;
        const uint2* bp = buck + (size_t)bkt * BCAP;
        for (int base = 0; base < cnt; base += 2048) {
            unsigned x[8]; float pv[8]; int ii[8];
#pragma unroll
            for (int j = 0; j < 8; ++j) {
                ii[j] = base + j * 256 + tid;
                x[j] = (ii[j] < cnt) ? bp[ii[j]].x : 0u;
            }
#pragma unroll
            for (int j = 0; j < 8; ++j)
                pv[j] = (ii[j] < cnt) ? pred[x[j] & 0x3FFFF] : 0.f;
#pragma unroll
            for (int j = 0; j < 8; ++j)
                if (ii[j] < cnt) atomicAdd(&agg[(x[j] >> 18) & 63], pv[j]);
        }
        __syncthreads();
        if (tid < 64) {
            float v = 0.f;
            int node = bkt * BNODES + tid;
            if (node < N) {
                float d = agg[tid] - 1.0f;
                v = d * d * sc[node];
            }
            v = wave_reduce(v);
            if (tid == 0) ocpart[bkt] = v;
        }
    } else if (blk < P3) {
        // ---------------- rowcol path (+ce/sq on rows) ----------------
        int rc = blk - P2;
        if (rc < MNUM) {
            float p = 0.f, ce = 0.f, sq = 0.f;
            if (tid < MNUM) {
                p = pred[rc * MNUM + tid];
                ce = -gt[rc * MNUM + tid] * __log2f(p);
                sq = p * p;
            }
            p = wave_reduce(p);
            ce = wave_reduce(ce);
            sq = wave_reduce(sq);
            int wid = tid >> 6;
            if ((tid & 63) == 0) { red[wid] = p; red[4 + wid] = ce; red[8 + wid] = sq; }
            __syncthreads();
            if (tid == 0) {
                rs[rc] = red[0] + red[1] + red[2] + red[3];
                cepart[rc] = red[4] + red[5] + red[6] + red[7];
                sqpart[rc] = red[8] + red[9] + red[10] + red[11];
            }
        } else {
            int j = rc - MNUM;
            float p = 0.f;
            if (tid < MNUM) p = pred[tid * MNUM + j];
            p = wave_reduce(p);
            if ((tid & 63) == 0) red[tid >> 6] = p;
            __syncthreads();
            if (tid == 0) cs[j] = red[0] + red[1] + red[2] + red[3];
        }
    } else {
        // ---------------- gsum dim-reduction ----------------
        int dim = blk - P3;  // 0..127
        float s = 0.f;
        for (int b = tid; b < nbuck; b += 256) s += gpart[(size_t)b * 128 + dim];
        s = wave_reduce(s);
        if ((tid & 63) == 0) red[tid >> 6] = s;
        __syncthreads();
        if (tid == 0) gsum[dim] = red[0] + red[1] + red[2] + red[3];
    }
}

// K8: single-block tail: all six outputs via plain stores.
__global__ void tail_kernel(const float* __restrict__ rs, const float* __restrict__ cs,
                            const float* __restrict__ cepart, const float* __restrict__ sqpart,
                            const float* __restrict__ psum, int npsum,
                            const float* __restrict__ ocpart, int nbuck,
                            const float* __restrict__ gsum, const float* __restrict__ fc3_w,
                            const float* __restrict__ fc3_b, const float* __restrict__ fl3_b,
                            float* __restrict__ out, int N, int padrows) {
    __shared__ float red[4];
    int tid = threadIdx.x;
    // sumone
    float v = 0.f;
    if (tid < MNUM) {
        float a = rs[tid] - 1.0f, b = cs[tid] - 1.0f;
        v = a * a + b * b;
    }
    v = wave_reduce(v);
    if ((tid & 63) == 0) red[tid >> 6] = v;
    __syncthreads();
    if (tid == 0) out[1] = red[0] + red[1] + red[2] + red[3];
    __syncthreads();
    // ce
    float ce = (tid < MNUM) ? cepart[tid] : 0.f;
    ce = wave_reduce(ce);
    if ((tid & 63) == 0) red[tid >> 6] = ce;
    __syncthreads();
    if (tid == 0) out[3] = red[0] + red[1] + red[2] + red[3];
    __syncthreads();
    // loss2 = sum rs^2 + sum cs^2 - 2 sum p^2
    float l2 = 0.f;
    if (tid < MNUM)
        l2 = rs[tid] * rs[tid] + cs[tid] * cs[tid] - 2.0f * sqpart[tid];
    l2 = wave_reduce(l2);
    if ((tid & 63) == 0) red[tid >> 6] = l2;
    __syncthreads();
    if (tid == 0) out[2] = red[0] + red[1] + red[2] + red[3];
    __syncthreads();
    // prob3_sum
    float ps = 0.f;
    for (int i = tid; i < npsum; i += 256) ps += psum[i];
    float ss = 0.f;
    for (int p = tid; p < PNUM; p += 256) ss += fsig_fast(fl3_b[p]);
    float comb = ps - (float)padrows * ss;
    comb = wave_reduce(comb);
    if ((tid & 63) == 0) red[tid >> 6] = comb;
    __syncthreads();
    if (tid == 0) out[5] = red[0] + red[1] + red[2] + red[3];
    __syncthreads();
    // out_cost
    float oc = 0.f;
    for (int b = tid; b < nbuck; b += 256) oc += ocpart[b];
    oc = wave_reduce(oc);
    if ((tid & 63) == 0) red[tid >> 6] = oc;
    __syncthreads();
    if (tid == 0) out[4] = red[0] + red[1] + red[2] + red[3];
    __syncthreads();
    // pred_obj
    float pv = 0.f;
    if (tid < 128) pv = gsum[tid] * (1.0f / (float)N) * fc3_w[tid];
    pv = wave_reduce(pv);
    if ((tid & 63) == 0) red[tid >> 6] = pv;
    __syncthreads();
    if (tid == 0) out[0] = red[0] + red[1] + fc3_b[0];
}

extern "C" void kernel_launch(void* const* d_in, const int* in_sizes, int n_in,
                              void* d_out, int out_size, void* d_ws, size_t ws_size,
                              hipStream_t stream) {
    const float* ntc   = (const float*)d_in[0];
    const float* norm  = (const float*)d_in[1];
    const float* sc    = (const float*)d_in[2];
    const float* gt    = (const float*)d_in[3];
    const float* fc_w  = (const float*)d_in[4];
    const float* fc_b  = (const float*)d_in[5];
    const float* w_nt  = (const float*)d_in[6];
    const float* w_rel = (const float*)d_in[7];
    const float* fc2_w = (const float*)d_in[8];
    const float* fc2_b = (const float*)d_in[9];
    const float* fc3_w = (const float*)d_in[10];
    const float* fc3_b = (const float*)d_in[11];
    const float* fl3_w = (const float*)d_in[12];
    const float* fl3_b = (const float*)d_in[13];
    const int* node_type = (const int*)d_in[14];
    const int* src   = (const int*)d_in[15];
    const int* dst   = (const int*)d_in[16];
    const int* etype = (const int*)d_in[17];
    int N = in_sizes[2];
    int E = in_sizes[1];
    int nb128 = (N + 127) / 128;             // 391
    int padN  = nb128 * 128;                 // 50048
    int nbuck = padN / BNODES;               // 782
    int npsum = nb128 * 2;                   // 782
    int NP = (E + EPB - 1) / EPB;            // 391

    // ---- workspace layout (float offsets) ----
    float* ws   = (float*)d_ws;
    unsigned short* wt = (unsigned short*)ws;            // 0..65536 (131072 shorts)
    float* biasws = ws + 65536;              // ..66560
    float* gsum = ws + 66560;                // ..66688
    float* rs   = ws + 66688;                // ..66944
    float* cs   = ws + 66944;                // ..67200
    int*  cursor = (int*)(ws + 67200);       // ..67984 (784 ints)
    float* psum = ws + 67984;                // ..69008
    float* cepart = ws + 69008;              // ..69264
    float* sqpart = ws + 69264;              // ..69520
    float* ocpart = ws + 69520;              // ..70544
    unsigned short* CbT = (unsigned short*)(ws + 70544); // 8192 shorts -> ..74640
    float* gpart  = ws + 74640;              // ..174736 (782*128)
    float* pred = ws + 174736;               // ..+N
    unsigned short* hb = (unsigned short*)(pred + N);    // padN*128 bf16
    uint2* buck = (uint2*)(hb + (size_t)padN * H);       // nbuck*BCAP*8B
    float* out  = (float*)d_out;

    hipMemsetAsync(cursor, 0, 784 * sizeof(int), stream);

    partition_setup<<<NP + 260, 512, 0, stream>>>(src, dst, etype, norm, node_type,
                                                  cursor, buck, E, NP,
                                                  fl3_w, fl3_b, wt, biasws,
                                                  fc_w, fc_b, w_nt, w_rel, CbT);
    bucket_node<<<nbuck, 256, 0, stream>>>(buck, cursor, ntc, CbT, fc2_w, fc2_b,
                                           hb, pred, gpart, N);
    int megablocks = 2 * nb128 + nbuck + 2 * MNUM + 128;
    mega_kernel<<<megablocks, 256, 0, stream>>>(hb, wt, biasws, psum, nb128,
                                                buck, cursor, pred, sc, gt, ocpart, N,
                                                rs, cs, cepart, sqpart, gpart, gsum, nbuck);
    tail_kernel<<<1, 256, 0, stream>>>(rs, cs, cepart, sqpart, psum, npsum, ocpart, nbuck,
                                       gsum, fc3_w, fc3_b, fl3_b, out, N, padN - N);
}